// Round 1
// baseline (1233.393 us; speedup 1.0000x reference)
//
#include <hip/hip_runtime.h>
#include <hip/hip_bf16.h>

typedef __hip_bfloat16 bf16;
typedef unsigned int uint32;

// Problem constants
#define N_NODES 50000
#define N_EDGES 800000
#define ETOT    (N_EDGES + N_NODES)   // 850000 (with self loops)
#define F_INN   78
#define H1      10
#define D1      780                   // H1 * F_INN
#define OUT2    128
#define NGRAPH  512
#define NEG_SLOPE 0.2f

__device__ __forceinline__ float lrelu(float v) { return v > 0.f ? v : NEG_SLOPE * v; }
__device__ __forceinline__ float bl(uint32 u) { return __uint_as_float(u << 16); }          // low bf16 -> f32
__device__ __forceinline__ float bh(uint32 u) { return __uint_as_float(u & 0xffff0000u); }  // high bf16 -> f32
__device__ __forceinline__ unsigned short f2bfbits(float f) {
    return __bfloat16_as_ushort(__float2bfloat16(f));
}
__device__ __forceinline__ uint32 packbf(float lo, float hi) {
    return (uint32)f2bfbits(lo) | ((uint32)f2bfbits(hi) << 16);
}
__device__ __forceinline__ int esrc(const int* ei, int e) { return e < N_EDGES ? ei[e] : e - N_EDGES; }
__device__ __forceinline__ int edst(const int* ei, int e) { return e < N_EDGES ? ei[N_EDGES + e] : e - N_EDGES; }

// ---------------- GEMM1: x[50000x78] @ W1[78x780] -> h1 bf16 ----------------
__global__ __launch_bounds__(256) void gemm1_kernel(const float* __restrict__ x,
                                                    const float* __restrict__ W1,
                                                    bf16* __restrict__ h1) {
    __shared__ float As[64 * 80];   // [row][k], k padded 78->80
    __shared__ float Bs[78 * 64];   // [k][col]
    int bx = blockIdx.x, by = blockIdx.y;
    int tid = threadIdx.x;
    int tx = tid & 15, ty = tid >> 4;
    int row0 = by * 64, col0 = bx * 64;

    for (int idx = tid; idx < 64 * 78; idx += 256) {
        int r = idx / 78, c = idx - r * 78;
        int gr = row0 + r;
        As[r * 80 + c] = (gr < N_NODES) ? x[gr * F_INN + c] : 0.f;
    }
    for (int idx = tid; idx < 78 * 64; idx += 256) {
        int r = idx >> 6, c = idx & 63;
        int gc = col0 + c;
        Bs[r * 64 + c] = (gc < D1) ? W1[r * D1 + gc] : 0.f;
    }
    __syncthreads();

    float acc[4][4] = {};
    for (int k = 0; k < 78; ++k) {
        float a[4], b[4];
#pragma unroll
        for (int i = 0; i < 4; ++i) a[i] = As[(ty * 4 + i) * 80 + k];
#pragma unroll
        for (int j = 0; j < 4; ++j) b[j] = Bs[k * 64 + tx + j * 16];
#pragma unroll
        for (int i = 0; i < 4; ++i)
#pragma unroll
            for (int j = 0; j < 4; ++j) acc[i][j] = fmaf(a[i], b[j], acc[i][j]);
    }
    for (int i = 0; i < 4; ++i) {
        int gr = row0 + ty * 4 + i;
        if (gr >= N_NODES) continue;
        for (int j = 0; j < 4; ++j) {
            int gc = col0 + tx + j * 16;
            if (gc < D1) h1[(long)gr * D1 + gc] = __float2bfloat16(acc[i][j]);
        }
    }
}

// ---------------- alpha projections layer 1: [N,10] src/dst ----------------
__global__ __launch_bounds__(256) void alphas1_kernel(const bf16* __restrict__ h1,
                                                      const float* __restrict__ a_src1,
                                                      const float* __restrict__ a_dst1,
                                                      float* __restrict__ as1,
                                                      float* __restrict__ ad1) {
    int id = blockIdx.x * 256 + threadIdx.x;
    if (id >= N_NODES * H1) return;
    int n = id / H1, h = id - n * H1;
    const uint32* hp = (const uint32*)(h1 + (long)n * D1 + h * F_INN);
    const float2* ps = (const float2*)(a_src1 + h * F_INN);
    const float2* pd = (const float2*)(a_dst1 + h * F_INN);
    float s = 0.f, d = 0.f;
#pragma unroll 13
    for (int q = 0; q < 39; ++q) {
        uint32 u = hp[q];
        float v0 = bl(u), v1 = bh(u);
        float2 sv = ps[q], dv = pd[q];
        s = fmaf(v0, sv.x, fmaf(v1, sv.y, s));
        d = fmaf(v0, dv.x, fmaf(v1, dv.y, d));
    }
    as1[id] = s;
    ad1[id] = d;
}

// ---------------- CSR build ----------------
__global__ void hist_kernel(const int* __restrict__ ei, int* __restrict__ deg) {
    int e = blockIdx.x * 256 + threadIdx.x;
    if (e < ETOT) atomicAdd(&deg[edst(ei, e)], 1);
}

__global__ __launch_bounds__(1024) void scan_kernel(const int* __restrict__ deg,
                                                    int* __restrict__ row_ptr,
                                                    int* __restrict__ cursor) {
    __shared__ int buf[1024];
    __shared__ int carry_sh;
    int tid = threadIdx.x;
    if (tid == 0) carry_sh = 0;
    __syncthreads();
    for (int base = 0; base < N_NODES; base += 1024) {
        int i = base + tid;
        int v = (i < N_NODES) ? deg[i] : 0;
        buf[tid] = v;
        __syncthreads();
        int carry = carry_sh;
        for (int off = 1; off < 1024; off <<= 1) {
            int t = (tid >= off) ? buf[tid - off] : 0;
            __syncthreads();
            buf[tid] += t;
            __syncthreads();
        }
        if (i < N_NODES) {
            int excl = carry + buf[tid] - v;
            row_ptr[i] = excl;
            cursor[i] = excl;
        }
        if (tid == 1023) carry_sh = carry + buf[1023];
        __syncthreads();
    }
    if (tid == 0) row_ptr[N_NODES] = carry_sh;
}

__global__ void scatter_kernel(const int* __restrict__ ei, int* __restrict__ cursor,
                               int* __restrict__ eid_arr) {
    int e = blockIdx.x * 256 + threadIdx.x;
    if (e < ETOT) {
        int pos = atomicAdd(&cursor[edst(ei, e)], 1);
        eid_arr[pos] = e;
    }
}

// ---------------- layer-1 attention aggregation (block per dst node) ----------------
__global__ __launch_bounds__(256) void agg1_kernel(const int* __restrict__ ei,
                                                   const int* __restrict__ row_ptr,
                                                   const int* __restrict__ eid_arr,
                                                   const float* __restrict__ as1,
                                                   const float* __restrict__ ad1,
                                                   const bf16* __restrict__ h1,
                                                   const float* __restrict__ b1,
                                                   bf16* __restrict__ out1) {
    int i = blockIdx.x;
    int tid = threadIdx.x;
    __shared__ float adst_sh[H1], m_sh[H1], rden_sh[H1];
    __shared__ float red[4][H1];
    __shared__ int src_sh[256];
    __shared__ float w_sh[256 * H1];

    int rs = row_ptr[i], deg = row_ptr[i + 1] - rs;
    if (tid < H1) adst_sh[tid] = ad1[i * H1 + tid];
    __syncthreads();

    // phase A: per-head max of leaky_relu(logit)
    float lm[H1];
#pragma unroll
    for (int h = 0; h < H1; ++h) lm[h] = -1e30f;
    for (int eix = tid; eix < deg; eix += 256) {
        int e = eid_arr[rs + eix];
        int s = esrc(ei, e);
#pragma unroll
        for (int h = 0; h < H1; ++h)
            lm[h] = fmaxf(lm[h], lrelu(as1[s * H1 + h] + adst_sh[h]));
    }
    int lane = tid & 63, wv = tid >> 6;
#pragma unroll
    for (int h = 0; h < H1; ++h) {
        float v = lm[h];
        for (int off = 32; off; off >>= 1) v = fmaxf(v, __shfl_xor(v, off, 64));
        if (lane == 0) red[wv][h] = v;
    }
    __syncthreads();
    if (tid < H1)
        m_sh[tid] = fmaxf(fmaxf(red[0][tid], red[1][tid]), fmaxf(red[2][tid], red[3][tid]));
    __syncthreads();

    // phase A2: per-head sum of exp
    float ls[H1];
#pragma unroll
    for (int h = 0; h < H1; ++h) ls[h] = 0.f;
    for (int eix = tid; eix < deg; eix += 256) {
        int e = eid_arr[rs + eix];
        int s = esrc(ei, e);
#pragma unroll
        for (int h = 0; h < H1; ++h)
            ls[h] += __expf(lrelu(as1[s * H1 + h] + adst_sh[h]) - m_sh[h]);
    }
#pragma unroll
    for (int h = 0; h < H1; ++h) {
        float v = ls[h];
        for (int off = 32; off; off >>= 1) v += __shfl_xor(v, off, 64);
        if (lane == 0) red[wv][h] = v;
    }
    __syncthreads();
    if (tid < H1)
        rden_sh[tid] = 1.f / (red[0][tid] + red[1][tid] + red[2][tid] + red[3][tid] + 1e-16f);
    __syncthreads();

    // phase B: weighted gather. thread covers uint (bf16-pair) indices u0=tid, u1=tid+256
    const int NU = D1 / 2;  // 390
    int u0 = tid, u1 = tid + 256;
    int hh0 = u0 / 39;
    int hh1 = (u1 < NU) ? (u1 / 39) : 0;
    float a0x = 0.f, a0y = 0.f, a1x = 0.f, a1y = 0.f;

    for (int base = 0; base < deg; base += 256) {
        int cnt = min(deg - base, 256);
        if (tid < cnt) src_sh[tid] = esrc(ei, eid_arr[rs + base + tid]);
        __syncthreads();
        for (int idx = tid; idx < cnt * H1; idx += 256) {
            int eix = idx / H1, h = idx - eix * H1;
            float v = lrelu(as1[src_sh[eix] * H1 + h] + adst_sh[h]);
            w_sh[eix * H1 + h] = __expf(v - m_sh[h]) * rden_sh[h];
        }
        __syncthreads();
        for (int eix = 0; eix < cnt; ++eix) {
            int s = src_sh[eix];
            const uint32* hp = (const uint32*)(h1 + (long)s * D1);
            uint32 uv0 = hp[u0];
            float w0 = w_sh[eix * H1 + hh0];
            a0x = fmaf(w0, bl(uv0), a0x);
            a0y = fmaf(w0, bh(uv0), a0y);
            if (u1 < NU) {
                uint32 uv1 = hp[u1];
                float w1 = w_sh[eix * H1 + hh1];
                a1x = fmaf(w1, bl(uv1), a1x);
                a1y = fmaf(w1, bh(uv1), a1y);
            }
        }
        __syncthreads();
    }

    uint32* op = (uint32*)out1 + (long)i * NU;
    const float2* bp = (const float2*)b1;
    float2 bv0 = bp[u0];
    op[u0] = packbf(fmaxf(a0x + bv0.x, 0.f), fmaxf(a0y + bv0.y, 0.f));
    if (u1 < NU) {
        float2 bv1 = bp[u1];
        op[u1] = packbf(fmaxf(a1x + bv1.x, 0.f), fmaxf(a1y + bv1.y, 0.f));
    }
}

// ---------------- GEMM2: out1[50000x780] bf16 @ W2[780x128] -> h2 bf16 ----------------
__global__ __launch_bounds__(256) void gemm2_kernel(const bf16* __restrict__ out1,
                                                    const float* __restrict__ W2,
                                                    bf16* __restrict__ h2) {
    __shared__ float As[64 * 64];    // [r][k]
    __shared__ float Bs[64 * 128];   // [k][c]
    int by = blockIdx.x;
    int tid = threadIdx.x;
    int tx = tid & 15, ty = tid >> 4;
    int row0 = by * 64;
    float acc[4][8] = {};

    for (int k0 = 0; k0 < D1; k0 += 64) {
        for (int idx = tid; idx < 64 * 32; idx += 256) {
            int r = idx >> 5, c2 = idx & 31;
            int gr = row0 + r, gk = k0 + c2 * 2;
            uint32 u = 0;
            if (gr < N_NODES && gk < D1)
                u = *((const uint32*)(out1 + (long)gr * D1 + gk));
            As[r * 64 + c2 * 2] = bl(u);
            As[r * 64 + c2 * 2 + 1] = bh(u);
        }
        for (int idx = tid; idx < 64 * 32; idx += 256) {
            int r = idx >> 5, c4 = idx & 31;
            int gk = k0 + r;
            float4 v = make_float4(0.f, 0.f, 0.f, 0.f);
            if (gk < D1) v = ((const float4*)(W2 + (long)gk * OUT2))[c4];
            ((float4*)(Bs + r * 128))[c4] = v;
        }
        __syncthreads();
        for (int kk = 0; kk < 64; ++kk) {
            float a[4], b[8];
#pragma unroll
            for (int i = 0; i < 4; ++i) a[i] = As[(ty * 4 + i) * 64 + kk];
#pragma unroll
            for (int j = 0; j < 8; ++j) b[j] = Bs[kk * 128 + tx + j * 16];
#pragma unroll
            for (int i = 0; i < 4; ++i)
#pragma unroll
                for (int j = 0; j < 8; ++j) acc[i][j] = fmaf(a[i], b[j], acc[i][j]);
        }
        __syncthreads();
    }
    for (int i = 0; i < 4; ++i) {
        int gr = row0 + ty * 4 + i;
        if (gr >= N_NODES) continue;
        for (int j = 0; j < 8; ++j)
            h2[(long)gr * OUT2 + tx + j * 16] = __float2bfloat16(acc[i][j]);
    }
}

// ---------------- alpha projections layer 2 (block per node, 128 threads) ----------------
__global__ __launch_bounds__(128) void alphas2_kernel(const bf16* __restrict__ h2,
                                                      const float* __restrict__ a_src2,
                                                      const float* __restrict__ a_dst2,
                                                      float* __restrict__ as2,
                                                      float* __restrict__ ad2) {
    int n = blockIdx.x, tid = threadIdx.x;
    __shared__ float red[2][2];
    float v = __bfloat162float(h2[(long)n * OUT2 + tid]);
    float s = v * a_src2[tid];
    float d = v * a_dst2[tid];
    for (int off = 32; off; off >>= 1) {
        s += __shfl_xor(s, off, 64);
        d += __shfl_xor(d, off, 64);
    }
    if ((tid & 63) == 0) { red[tid >> 6][0] = s; red[tid >> 6][1] = d; }
    __syncthreads();
    if (tid == 0) {
        as2[n] = red[0][0] + red[1][0];
        ad2[n] = red[0][1] + red[1][1];
    }
}

// ---------------- layer-2 aggregation + fused global max pool ----------------
__global__ __launch_bounds__(128) void agg2_kernel(const int* __restrict__ ei,
                                                   const int* __restrict__ row_ptr,
                                                   const int* __restrict__ eid_arr,
                                                   const float* __restrict__ as2,
                                                   const float* __restrict__ ad2,
                                                   const bf16* __restrict__ h2,
                                                   const float* __restrict__ b2,
                                                   const int* __restrict__ batch,
                                                   float* __restrict__ pooled) {
    int i = blockIdx.x, tid = threadIdx.x;
    __shared__ float red[2];
    __shared__ int src_sh[128];
    __shared__ float w_sh[128];
    int rs = row_ptr[i], deg = row_ptr[i + 1] - rs;
    float adst = ad2[i];

    float lm = -1e30f;
    for (int eix = tid; eix < deg; eix += 128)
        lm = fmaxf(lm, lrelu(as2[esrc(ei, eid_arr[rs + eix])] + adst));
    for (int off = 32; off; off >>= 1) lm = fmaxf(lm, __shfl_xor(lm, off, 64));
    if ((tid & 63) == 0) red[tid >> 6] = lm;
    __syncthreads();
    float m = fmaxf(red[0], red[1]);
    __syncthreads();

    float lsum = 0.f;
    for (int eix = tid; eix < deg; eix += 128)
        lsum += __expf(lrelu(as2[esrc(ei, eid_arr[rs + eix])] + adst) - m);
    for (int off = 32; off; off >>= 1) lsum += __shfl_xor(lsum, off, 64);
    if ((tid & 63) == 0) red[tid >> 6] = lsum;
    __syncthreads();
    float rden = 1.f / (red[0] + red[1] + 1e-16f);

    float acc = 0.f;
    for (int base = 0; base < deg; base += 128) {
        int cnt = min(deg - base, 128);
        __syncthreads();
        if (tid < cnt) {
            int s = esrc(ei, eid_arr[rs + base + tid]);
            src_sh[tid] = s;
            w_sh[tid] = __expf(lrelu(as2[s] + adst) - m) * rden;
        }
        __syncthreads();
        for (int eix = 0; eix < cnt; ++eix)
            acc = fmaf(w_sh[eix], __bfloat162float(h2[(long)src_sh[eix] * OUT2 + tid]), acc);
    }
    float val = fmaxf(acc + b2[tid], 0.f);
    int g = batch[i];
    atomicMax((int*)&pooled[g * OUT2 + tid], __float_as_int(val));
}

// ---------------- final FC + relu ----------------
__global__ __launch_bounds__(128) void fc_kernel(const float* __restrict__ pooled,
                                                 const float* __restrict__ fcW,
                                                 const float* __restrict__ fcb,
                                                 float* __restrict__ out) {
    int g = blockIdx.x, tid = threadIdx.x;
    __shared__ float p[128];
    p[tid] = pooled[g * OUT2 + tid];
    __syncthreads();
    float acc = fcb[tid];
    for (int k = 0; k < 128; ++k) acc = fmaf(p[k], fcW[k * OUT2 + tid], acc);
    out[g * OUT2 + tid] = fmaxf(acc, 0.f);
}

extern "C" void kernel_launch(void* const* d_in, const int* in_sizes, int n_in,
                              void* d_out, int out_size, void* d_ws, size_t ws_size,
                              hipStream_t stream) {
    const float* x      = (const float*)d_in[0];
    const int*   ei     = (const int*)d_in[1];
    const int*   batch  = (const int*)d_in[2];
    const float* W1     = (const float*)d_in[4];
    const float* a_src1 = (const float*)d_in[5];
    const float* a_dst1 = (const float*)d_in[6];
    const float* b1     = (const float*)d_in[7];
    const float* W2     = (const float*)d_in[8];
    const float* a_src2 = (const float*)d_in[9];
    const float* a_dst2 = (const float*)d_in[10];
    const float* b2     = (const float*)d_in[11];
    const float* fcW    = (const float*)d_in[12];
    const float* fcb    = (const float*)d_in[13];
    float* out = (float*)d_out;

    // workspace layout
    size_t off = 0;
    char* base = (char*)d_ws;
    auto alloc = [&](size_t bytes) -> void* {
        void* p = base + off;
        off += (bytes + 255) & ~(size_t)255;
        return p;
    };
    bf16* h1    = (bf16*)alloc((size_t)N_NODES * D1 * 2);
    bf16* out1  = (bf16*)alloc((size_t)N_NODES * D1 * 2);
    bf16* h2    = (bf16*)alloc((size_t)N_NODES * OUT2 * 2);
    float* as1  = (float*)alloc((size_t)N_NODES * H1 * 4);
    float* ad1  = (float*)alloc((size_t)N_NODES * H1 * 4);
    float* as2  = (float*)alloc((size_t)N_NODES * 4);
    float* ad2  = (float*)alloc((size_t)N_NODES * 4);
    float* pooled = (float*)alloc((size_t)NGRAPH * OUT2 * 4);
    int* deg     = (int*)alloc((size_t)N_NODES * 4);
    int* row_ptr = (int*)alloc((size_t)(N_NODES + 1) * 4);
    int* cursor  = (int*)alloc((size_t)N_NODES * 4);
    int* eid_arr = (int*)alloc((size_t)ETOT * 4);

    hipMemsetAsync(deg, 0, (size_t)N_NODES * 4, stream);
    hipMemsetAsync(pooled, 0, (size_t)NGRAPH * OUT2 * 4, stream);

    gemm1_kernel<<<dim3(13, 782), 256, 0, stream>>>(x, W1, h1);
    alphas1_kernel<<<(N_NODES * H1 + 255) / 256, 256, 0, stream>>>(h1, a_src1, a_dst1, as1, ad1);
    hist_kernel<<<(ETOT + 255) / 256, 256, 0, stream>>>(ei, deg);
    scan_kernel<<<1, 1024, 0, stream>>>(deg, row_ptr, cursor);
    scatter_kernel<<<(ETOT + 255) / 256, 256, 0, stream>>>(ei, cursor, eid_arr);
    agg1_kernel<<<N_NODES, 256, 0, stream>>>(ei, row_ptr, eid_arr, as1, ad1, h1, b1, out1);
    gemm2_kernel<<<(N_NODES + 63) / 64, 256, 0, stream>>>(out1, W2, h2);
    alphas2_kernel<<<N_NODES, 128, 0, stream>>>(h2, a_src2, a_dst2, as2, ad2);
    agg2_kernel<<<N_NODES, 128, 0, stream>>>(ei, row_ptr, eid_arr, as2, ad2, h2, b2, batch, pooled);
    fc_kernel<<<NGRAPH, 128, 0, stream>>>(pooled, fcW, fcb, out);
}

// Round 2
// 781.238 us; speedup vs baseline: 1.5788x; 1.5788x over previous
//
#include <hip/hip_runtime.h>
#include <hip/hip_bf16.h>
#include <stdint.h>

typedef unsigned int uint32;
typedef unsigned short u16;
typedef __attribute__((ext_vector_type(8))) short bf16x8;
typedef __attribute__((ext_vector_type(4))) float f32x4;

// Problem constants
#define N_NODES 50000
#define N_EDGES 800000
#define ETOT    (N_EDGES + N_NODES)   // 850000
#define F_INN   78
#define H1      10
#define D1      780
#define OUT2    128
#define NGRAPH  512
#define NEG_SLOPE 0.2f

#define NX  (N_NODES * F_INN)   // 3,900,000
#define NW1 (D1 * F_INN)        // 60,840
#define NW2 (OUT2 * D1)         // 99,840

__device__ __forceinline__ float lrelu(float v) { return v > 0.f ? v : NEG_SLOPE * v; }
__device__ __forceinline__ float bl(uint32 u) { return __uint_as_float(u << 16); }
__device__ __forceinline__ float bh(uint32 u) { return __uint_as_float(u & 0xffff0000u); }
__device__ __forceinline__ u16 f2bfbits(float f) {
    return __bfloat16_as_ushort(__float2bfloat16(f));
}
__device__ __forceinline__ uint32 packbf(float lo, float hi) {
    return (uint32)f2bfbits(lo) | ((uint32)f2bfbits(hi) << 16);
}
__device__ __forceinline__ int esrc(const int* ei, int e) { return e < N_EDGES ? ei[e] : e - N_EDGES; }
__device__ __forceinline__ int edst(const int* ei, int e) { return e < N_EDGES ? ei[N_EDGES + e] : e - N_EDGES; }

// ---------------- prep: x->bf16, W1->W1T bf16 [n][k], W2->W2T bf16 [n][k] ----------------
__global__ __launch_bounds__(256) void prep_kernel(const float* __restrict__ x,
                                                   const float* __restrict__ W1,
                                                   const float* __restrict__ W2,
                                                   u16* __restrict__ xb,
                                                   u16* __restrict__ W1T,
                                                   u16* __restrict__ W2T) {
    const int total = NX + NW1 + NW2;
    for (int id = blockIdx.x * 256 + threadIdx.x; id < total; id += gridDim.x * 256) {
        if (id < NX) {
            xb[id] = f2bfbits(x[id]);
        } else if (id < NX + NW1) {
            int t = id - NX;
            int n = t / F_INN, k = t - n * F_INN;
            W1T[t] = f2bfbits(W1[k * D1 + n]);
        } else {
            int t = id - NX - NW1;
            int n = t / D1, k = t - n * D1;
            W2T[t] = f2bfbits(W2[k * OUT2 + n]);
        }
    }
}

// ---------------- GEMM1 (MFMA): xb[50000x78] @ W1[78x780] -> h1 bf16 ----------------
// tile 128(M) x 64(N), K padded 78->96, LDS stride 104 u16 (52 uints)
#define G1S 52
__global__ __launch_bounds__(256) void gemm1_mfma(const u16* __restrict__ xb,
                                                  const u16* __restrict__ W1T,
                                                  u16* __restrict__ h1) {
    __shared__ uint32 As[128 * G1S];
    __shared__ uint32 Bs[64 * G1S];
    int tid = threadIdx.x;
    int col0 = blockIdx.x * 64, row0 = blockIdx.y * 128;
    const uint32* xbu = (const uint32*)xb;
    const uint32* w1u = (const uint32*)W1T;

    for (int idx = tid; idx < 128 * 39; idx += 256) {
        int r = idx / 39, c = idx - r * 39;
        int gr = row0 + r;
        As[r * G1S + c] = (gr < N_NODES) ? xbu[gr * 39 + c] : 0u;
    }
    for (int idx = tid; idx < 128 * 9; idx += 256) {
        int r = idx / 9, c = 39 + (idx - r * 9);
        As[r * G1S + c] = 0u;
    }
    for (int idx = tid; idx < 64 * 39; idx += 256) {
        int n = idx / 39, c = idx - n * 39;
        int gn = col0 + n;
        Bs[n * G1S + c] = (gn < D1) ? w1u[gn * 39 + c] : 0u;
    }
    for (int idx = tid; idx < 64 * 9; idx += 256) {
        int n = idx / 9, c = 39 + (idx - n * 9);
        Bs[n * G1S + c] = 0u;
    }
    __syncthreads();

    int lane = tid & 63, wv = tid >> 6;
    int wm = wv >> 1, wn = wv & 1;
    int l15 = lane & 15, quad = lane >> 4;
    const u16* Asu = (const u16*)As;
    const u16* Bsu = (const u16*)Bs;

    f32x4 acc[4][2];
#pragma unroll
    for (int mi = 0; mi < 4; ++mi)
#pragma unroll
        for (int nj = 0; nj < 2; ++nj) acc[mi][nj] = (f32x4){0.f, 0.f, 0.f, 0.f};

    int abase[4], bbase[2];
#pragma unroll
    for (int mi = 0; mi < 4; ++mi) abase[mi] = (wm * 64 + mi * 16 + l15) * 104 + quad * 8;
#pragma unroll
    for (int nj = 0; nj < 2; ++nj) bbase[nj] = (wn * 32 + nj * 16 + l15) * 104 + quad * 8;

#pragma unroll
    for (int ks = 0; ks < 96; ks += 32) {
        bf16x8 a[4], b[2];
#pragma unroll
        for (int mi = 0; mi < 4; ++mi) a[mi] = *(const bf16x8*)(Asu + abase[mi] + ks);
#pragma unroll
        for (int nj = 0; nj < 2; ++nj) b[nj] = *(const bf16x8*)(Bsu + bbase[nj] + ks);
#pragma unroll
        for (int mi = 0; mi < 4; ++mi)
#pragma unroll
            for (int nj = 0; nj < 2; ++nj)
                acc[mi][nj] = __builtin_amdgcn_mfma_f32_16x16x32_bf16(a[mi], b[nj], acc[mi][nj], 0, 0, 0);
    }

#pragma unroll
    for (int mi = 0; mi < 4; ++mi)
#pragma unroll
        for (int nj = 0; nj < 2; ++nj)
#pragma unroll
            for (int reg = 0; reg < 4; ++reg) {
                int row = row0 + wm * 64 + mi * 16 + quad * 4 + reg;
                int col = col0 + wn * 32 + nj * 16 + l15;
                if (row < N_NODES && col < D1)
                    h1[(size_t)row * D1 + col] = f2bfbits(acc[mi][nj][reg]);
            }
}

// ---------------- GEMM2 (MFMA): out1[50000x780] bf16 @ W2[780x128] -> h2 bf16 ----------------
// tile 128(M) x 128(N), K staged 64 at a time (13 stages), LDS stride 72 u16 (36 uints)
#define G2S 36
__global__ __launch_bounds__(256) void gemm2_mfma(const u16* __restrict__ out1,
                                                  const u16* __restrict__ W2T,
                                                  u16* __restrict__ h2) {
    __shared__ uint32 As[128 * G2S];
    __shared__ uint32 Bs[128 * G2S];
    int tid = threadIdx.x;
    int row0 = blockIdx.x * 128;
    const uint32* o1u = (const uint32*)out1;
    const uint32* w2u = (const uint32*)W2T;

    int lane = tid & 63, wv = tid >> 6;
    int wm = wv >> 1, wn = wv & 1;
    int l15 = lane & 15, quad = lane >> 4;
    const u16* Asu = (const u16*)As;
    const u16* Bsu = (const u16*)Bs;

    f32x4 acc[4][4];
#pragma unroll
    for (int mi = 0; mi < 4; ++mi)
#pragma unroll
        for (int nj = 0; nj < 4; ++nj) acc[mi][nj] = (f32x4){0.f, 0.f, 0.f, 0.f};

    int abase[4], bbase[4];
#pragma unroll
    for (int mi = 0; mi < 4; ++mi) abase[mi] = (wm * 64 + mi * 16 + l15) * 72 + quad * 8;
#pragma unroll
    for (int nj = 0; nj < 4; ++nj) bbase[nj] = (wn * 64 + nj * 16 + l15) * 72 + quad * 8;

    for (int s = 0; s < 13; ++s) {
        int k0h = s * 32;  // uint offset into a 390-uint row
        for (int idx = tid; idx < 128 * 32; idx += 256) {
            int r = idx >> 5, c = idx & 31;
            int gr = row0 + r;
            As[r * G2S + c] = (gr < N_NODES && (k0h + c) < 390) ? o1u[(size_t)gr * 390 + k0h + c] : 0u;
        }
        for (int idx = tid; idx < 128 * 32; idx += 256) {
            int n = idx >> 5, c = idx & 31;
            Bs[n * G2S + c] = ((k0h + c) < 390) ? w2u[(size_t)n * 390 + k0h + c] : 0u;
        }
        __syncthreads();
#pragma unroll
        for (int ks = 0; ks < 64; ks += 32) {
            bf16x8 a[4], b[4];
#pragma unroll
            for (int mi = 0; mi < 4; ++mi) a[mi] = *(const bf16x8*)(Asu + abase[mi] + ks);
#pragma unroll
            for (int nj = 0; nj < 4; ++nj) b[nj] = *(const bf16x8*)(Bsu + bbase[nj] + ks);
#pragma unroll
            for (int mi = 0; mi < 4; ++mi)
#pragma unroll
                for (int nj = 0; nj < 4; ++nj)
                    acc[mi][nj] = __builtin_amdgcn_mfma_f32_16x16x32_bf16(a[mi], b[nj], acc[mi][nj], 0, 0, 0);
        }
        __syncthreads();
    }

#pragma unroll
    for (int mi = 0; mi < 4; ++mi)
#pragma unroll
        for (int nj = 0; nj < 4; ++nj)
#pragma unroll
            for (int reg = 0; reg < 4; ++reg) {
                int row = row0 + wm * 64 + mi * 16 + quad * 4 + reg;
                int col = wn * 64 + nj * 16 + l15;
                if (row < N_NODES)
                    h2[(size_t)row * OUT2 + col] = f2bfbits(acc[mi][nj][reg]);
            }
}

// ---------------- alpha projections layer 1 ----------------
__global__ __launch_bounds__(256) void alphas1_kernel(const u16* __restrict__ h1,
                                                      const float* __restrict__ a_src1,
                                                      const float* __restrict__ a_dst1,
                                                      float* __restrict__ as1,
                                                      float* __restrict__ ad1) {
    int id = blockIdx.x * 256 + threadIdx.x;
    if (id >= N_NODES * H1) return;
    int n = id / H1, h = id - n * H1;
    const uint32* hp = (const uint32*)(h1 + (size_t)n * D1 + h * F_INN);
    const float2* ps = (const float2*)(a_src1 + h * F_INN);
    const float2* pd = (const float2*)(a_dst1 + h * F_INN);
    float s = 0.f, d = 0.f;
#pragma unroll 13
    for (int q = 0; q < 39; ++q) {
        uint32 u = hp[q];
        float v0 = bl(u), v1 = bh(u);
        float2 sv = ps[q], dv = pd[q];
        s = fmaf(v0, sv.x, fmaf(v1, sv.y, s));
        d = fmaf(v0, dv.x, fmaf(v1, dv.y, d));
    }
    as1[id] = s;
    ad1[id] = d;
}

// ---------------- CSR build ----------------
__global__ void hist_kernel(const int* __restrict__ ei, int* __restrict__ deg) {
    int e = blockIdx.x * 256 + threadIdx.x;
    if (e < ETOT) atomicAdd(&deg[edst(ei, e)], 1);
}

__global__ __launch_bounds__(256) void scan1_kernel(const int* __restrict__ deg,
                                                    int* __restrict__ row_ptr,
                                                    int* __restrict__ bsum) {
    __shared__ int buf[256];
    int tid = threadIdx.x;
    int i = blockIdx.x * 256 + tid;
    int v = (i < N_NODES) ? deg[i] : 0;
    buf[tid] = v;
    __syncthreads();
    for (int off = 1; off < 256; off <<= 1) {
        int t = (tid >= off) ? buf[tid - off] : 0;
        __syncthreads();
        buf[tid] += t;
        __syncthreads();
    }
    if (i < N_NODES) row_ptr[i] = buf[tid] - v;
    if (tid == 255) bsum[blockIdx.x] = buf[255];
}

__global__ __launch_bounds__(256) void scan2_kernel(const int* __restrict__ bsum,
                                                    int* __restrict__ boff) {
    __shared__ int buf[256];
    int tid = threadIdx.x;
    int v = (tid < 196) ? bsum[tid] : 0;
    buf[tid] = v;
    __syncthreads();
    for (int off = 1; off < 256; off <<= 1) {
        int t = (tid >= off) ? buf[tid - off] : 0;
        __syncthreads();
        buf[tid] += t;
        __syncthreads();
    }
    if (tid < 196) boff[tid] = buf[tid] - v;
}

__global__ __launch_bounds__(256) void scan3_kernel(int* __restrict__ row_ptr,
                                                    const int* __restrict__ boff,
                                                    int* __restrict__ cursor) {
    int i = blockIdx.x * 256 + threadIdx.x;
    if (i < N_NODES) {
        int r = row_ptr[i] + boff[blockIdx.x];
        row_ptr[i] = r;
        cursor[i] = r;
    }
    if (i == 0) row_ptr[N_NODES] = ETOT;
}

__global__ void scatter_kernel(const int* __restrict__ ei, int* __restrict__ cursor,
                               int* __restrict__ eid_arr) {
    int e = blockIdx.x * 256 + threadIdx.x;
    if (e < ETOT) {
        int pos = atomicAdd(&cursor[edst(ei, e)], 1);
        eid_arr[pos] = e;
    }
}

// ---------------- layer-1 aggregation: one WAVE per dst node ----------------
__global__ __launch_bounds__(256) void agg1_kernel(const int* __restrict__ ei,
                                                   const int* __restrict__ row_ptr,
                                                   const int* __restrict__ eid_arr,
                                                   const float* __restrict__ as1,
                                                   const float* __restrict__ ad1,
                                                   const uint32* __restrict__ h1u,
                                                   const float* __restrict__ b1,
                                                   uint32* __restrict__ out1u) {
    __shared__ float w_sh[4][64 * H1];
    __shared__ int src_sh[4][64];
    int tid = threadIdx.x, lane = tid & 63, wv = tid >> 6;
    int i = blockIdx.x * 4 + wv;
    int rs = row_ptr[i], deg = row_ptr[i + 1] - rs;

    float adst[H1];
    const float2* adp = (const float2*)(ad1 + i * H1);
#pragma unroll
    for (int h2 = 0; h2 < 5; ++h2) {
        float2 t = adp[h2];
        adst[2 * h2] = t.x;
        adst[2 * h2 + 1] = t.y;
    }

    // online softmax (single pass over edges)
    float m[H1], ss[H1];
#pragma unroll
    for (int h = 0; h < H1; ++h) { m[h] = -1e30f; ss[h] = 0.f; }
    for (int eix = lane; eix < deg; eix += 64) {
        int e = eid_arr[rs + eix];
        int sn = esrc(ei, e);
        const float2* ap = (const float2*)(as1 + sn * H1);
#pragma unroll
        for (int h2 = 0; h2 < 5; ++h2) {
            float2 t = ap[h2];
            int h = 2 * h2;
            float v0 = lrelu(t.x + adst[h]);
            float nm0 = fmaxf(m[h], v0);
            ss[h] = ss[h] * __expf(m[h] - nm0) + __expf(v0 - nm0);
            m[h] = nm0;
            float v1 = lrelu(t.y + adst[h + 1]);
            float nm1 = fmaxf(m[h + 1], v1);
            ss[h + 1] = ss[h + 1] * __expf(m[h + 1] - nm1) + __expf(v1 - nm1);
            m[h + 1] = nm1;
        }
    }
#pragma unroll
    for (int off = 1; off < 64; off <<= 1) {
#pragma unroll
        for (int h = 0; h < H1; ++h) {
            float mo = __shfl_xor(m[h], off, 64);
            float so = __shfl_xor(ss[h], off, 64);
            float nm = fmaxf(m[h], mo);
            ss[h] = ss[h] * __expf(m[h] - nm) + so * __expf(mo - nm);
            m[h] = nm;
        }
    }
    float rden[H1];
#pragma unroll
    for (int h = 0; h < H1; ++h) rden[h] = 1.f / (ss[h] + 1e-16f);

    // weighted gather: lane covers row uints {lane + 64q}
    float acc[14];
#pragma unroll
    for (int q = 0; q < 14; ++q) acc[q] = 0.f;
    int hq[7];
#pragma unroll
    for (int q = 0; q < 7; ++q) {
        int u = lane + 64 * q;
        hq[q] = (u < 390) ? (u / 39) : 0;
    }

    for (int base = 0; base < deg; base += 64) {
        int cnt = min(deg - base, 64);
        if (lane < cnt) {
            int e = eid_arr[rs + base + lane];
            int sn = esrc(ei, e);
            src_sh[wv][lane] = sn;
            const float2* ap = (const float2*)(as1 + sn * H1);
#pragma unroll
            for (int h2 = 0; h2 < 5; ++h2) {
                float2 t = ap[h2];
                int h = 2 * h2;
                w_sh[wv][lane * H1 + h] = __expf(lrelu(t.x + adst[h]) - m[h]) * rden[h];
                w_sh[wv][lane * H1 + h + 1] = __expf(lrelu(t.y + adst[h + 1]) - m[h + 1]) * rden[h + 1];
            }
        }
        __builtin_amdgcn_wave_barrier();
#pragma unroll 2
        for (int eix = 0; eix < cnt; ++eix) {
            int sn = src_sh[wv][eix];
            const uint32* rowp = h1u + (size_t)sn * 390;
            const float* wrow = &w_sh[wv][eix * H1];
#pragma unroll
            for (int q = 0; q < 6; ++q) {
                float w = wrow[hq[q]];
                uint32 uv = rowp[lane + 64 * q];
                acc[2 * q] = fmaf(w, bl(uv), acc[2 * q]);
                acc[2 * q + 1] = fmaf(w, bh(uv), acc[2 * q + 1]);
            }
            if (lane < 6) {
                float w = wrow[hq[6]];
                uint32 uv = rowp[384 + lane];
                acc[12] = fmaf(w, bl(uv), acc[12]);
                acc[13] = fmaf(w, bh(uv), acc[13]);
            }
        }
        __builtin_amdgcn_wave_barrier();
    }

    uint32* orow = out1u + (size_t)i * 390;
    const float2* bp = (const float2*)b1;
#pragma unroll
    for (int q = 0; q < 7; ++q) {
        int u = lane + 64 * q;
        if (u < 390) {
            float2 bv = bp[u];
            orow[u] = packbf(fmaxf(acc[2 * q] + bv.x, 0.f), fmaxf(acc[2 * q + 1] + bv.y, 0.f));
        }
    }
}

// ---------------- alpha projections layer 2 ----------------
__global__ __launch_bounds__(128) void alphas2_kernel(const u16* __restrict__ h2,
                                                      const float* __restrict__ a_src2,
                                                      const float* __restrict__ a_dst2,
                                                      float* __restrict__ as2,
                                                      float* __restrict__ ad2) {
    int n = blockIdx.x, tid = threadIdx.x;
    __shared__ float red[2][2];
    float v = __uint_as_float(((uint32)h2[(size_t)n * OUT2 + tid]) << 16);
    float s = v * a_src2[tid];
    float d = v * a_dst2[tid];
    for (int off = 32; off; off >>= 1) {
        s += __shfl_xor(s, off, 64);
        d += __shfl_xor(d, off, 64);
    }
    if ((tid & 63) == 0) { red[tid >> 6][0] = s; red[tid >> 6][1] = d; }
    __syncthreads();
    if (tid == 0) {
        as2[n] = red[0][0] + red[1][0];
        ad2[n] = red[0][1] + red[1][1];
    }
}

// ---------------- layer-2 aggregation + pool: one WAVE per dst node ----------------
__global__ __launch_bounds__(256) void agg2_kernel(const int* __restrict__ ei,
                                                   const int* __restrict__ row_ptr,
                                                   const int* __restrict__ eid_arr,
                                                   const float* __restrict__ as2,
                                                   const float* __restrict__ ad2,
                                                   const uint32* __restrict__ h2u,
                                                   const float* __restrict__ b2,
                                                   const int* __restrict__ batch,
                                                   float* __restrict__ pooled) {
    __shared__ float w_sh[4][64];
    __shared__ int src_sh[4][64];
    int tid = threadIdx.x, lane = tid & 63, wv = tid >> 6;
    int i = blockIdx.x * 4 + wv;
    int rs = row_ptr[i], deg = row_ptr[i + 1] - rs;
    float adst = ad2[i];

    float m = -1e30f, ss = 0.f;
    for (int eix = lane; eix < deg; eix += 64) {
        int sn = esrc(ei, eid_arr[rs + eix]);
        float v = lrelu(as2[sn] + adst);
        float nm = fmaxf(m, v);
        ss = ss * __expf(m - nm) + __expf(v - nm);
        m = nm;
    }
#pragma unroll
    for (int off = 1; off < 64; off <<= 1) {
        float mo = __shfl_xor(m, off, 64);
        float so = __shfl_xor(ss, off, 64);
        float nm = fmaxf(m, mo);
        ss = ss * __expf(m - nm) + so * __expf(mo - nm);
        m = nm;
    }
    float rden = 1.f / (ss + 1e-16f);

    float a0 = 0.f, a1 = 0.f;
    for (int base = 0; base < deg; base += 64) {
        int cnt = min(deg - base, 64);
        if (lane < cnt) {
            int sn = esrc(ei, eid_arr[rs + base + lane]);
            src_sh[wv][lane] = sn;
            w_sh[wv][lane] = __expf(lrelu(as2[sn] + adst) - m) * rden;
        }
        __builtin_amdgcn_wave_barrier();
#pragma unroll 2
        for (int eix = 0; eix < cnt; ++eix) {
            int sn = src_sh[wv][eix];
            float w = w_sh[wv][eix];
            uint32 uv = h2u[(size_t)sn * 64 + lane];
            a0 = fmaf(w, bl(uv), a0);
            a1 = fmaf(w, bh(uv), a1);
        }
        __builtin_amdgcn_wave_barrier();
    }
    float2 bv = ((const float2*)b2)[lane];
    float v0 = fmaxf(a0 + bv.x, 0.f);
    float v1 = fmaxf(a1 + bv.y, 0.f);
    int g = batch[i];
    atomicMax((int*)&pooled[g * OUT2 + 2 * lane], __float_as_int(v0));
    atomicMax((int*)&pooled[g * OUT2 + 2 * lane + 1], __float_as_int(v1));
}

// ---------------- final FC + relu ----------------
__global__ __launch_bounds__(128) void fc_kernel(const float* __restrict__ pooled,
                                                 const float* __restrict__ fcW,
                                                 const float* __restrict__ fcb,
                                                 float* __restrict__ out) {
    int g = blockIdx.x, tid = threadIdx.x;
    __shared__ float p[128];
    p[tid] = pooled[g * OUT2 + tid];
    __syncthreads();
    float acc = fcb[tid];
    for (int k = 0; k < 128; ++k) acc = fmaf(p[k], fcW[k * OUT2 + tid], acc);
    out[g * OUT2 + tid] = fmaxf(acc, 0.f);
}

extern "C" void kernel_launch(void* const* d_in, const int* in_sizes, int n_in,
                              void* d_out, int out_size, void* d_ws, size_t ws_size,
                              hipStream_t stream) {
    const float* x      = (const float*)d_in[0];
    const int*   ei     = (const int*)d_in[1];
    const int*   batch  = (const int*)d_in[2];
    const float* W1     = (const float*)d_in[4];
    const float* a_src1 = (const float*)d_in[5];
    const float* a_dst1 = (const float*)d_in[6];
    const float* b1     = (const float*)d_in[7];
    const float* W2     = (const float*)d_in[8];
    const float* a_src2 = (const float*)d_in[9];
    const float* a_dst2 = (const float*)d_in[10];
    const float* b2     = (const float*)d_in[11];
    const float* fcW    = (const float*)d_in[12];
    const float* fcb    = (const float*)d_in[13];
    float* out = (float*)d_out;

    size_t off = 0;
    char* base = (char*)d_ws;
    auto alloc = [&](size_t bytes) -> void* {
        void* p = base + off;
        off += (bytes + 255) & ~(size_t)255;
        return p;
    };
    u16* h1     = (u16*)alloc((size_t)N_NODES * D1 * 2);
    u16* out1   = (u16*)alloc((size_t)N_NODES * D1 * 2);
    u16* h2     = (u16*)alloc((size_t)N_NODES * OUT2 * 2);  // also hosts xb early
    u16* xb     = h2;   // xb dead before gemm2 writes h2
    float* as1  = (float*)alloc((size_t)N_NODES * H1 * 4);
    float* ad1  = (float*)alloc((size_t)N_NODES * H1 * 4);
    float* as2  = (float*)alloc((size_t)N_NODES * 4);
    float* ad2  = (float*)alloc((size_t)N_NODES * 4);
    u16* W1T    = (u16*)alloc((size_t)NW1 * 2);
    u16* W2T    = (u16*)alloc((size_t)NW2 * 2);
    float* pooled = (float*)alloc((size_t)NGRAPH * OUT2 * 4);
    int* deg     = (int*)alloc((size_t)N_NODES * 4);
    int* row_ptr = (int*)alloc((size_t)(N_NODES + 1) * 4);
    int* cursor  = (int*)alloc((size_t)N_NODES * 4);
    int* eid_arr = (int*)alloc((size_t)ETOT * 4);
    int* bsum    = (int*)alloc(196 * 4);
    int* boff    = (int*)alloc(196 * 4);

    hipMemsetAsync(deg, 0, (size_t)N_NODES * 4, stream);
    hipMemsetAsync(pooled, 0, (size_t)NGRAPH * OUT2 * 4, stream);

    prep_kernel<<<2048, 256, 0, stream>>>(x, W1, W2, xb, W1T, W2T);
    gemm1_mfma<<<dim3(13, 391), 256, 0, stream>>>(xb, W1T, h1);
    alphas1_kernel<<<(N_NODES * H1 + 255) / 256, 256, 0, stream>>>(h1, a_src1, a_dst1, as1, ad1);
    hist_kernel<<<(ETOT + 255) / 256, 256, 0, stream>>>(ei, deg);
    scan1_kernel<<<196, 256, 0, stream>>>(deg, row_ptr, bsum);
    scan2_kernel<<<1, 256, 0, stream>>>(bsum, boff);
    scan3_kernel<<<196, 256, 0, stream>>>(row_ptr, boff, cursor);
    scatter_kernel<<<(ETOT + 255) / 256, 256, 0, stream>>>(ei, cursor, eid_arr);
    agg1_kernel<<<N_NODES / 4, 256, 0, stream>>>(ei, row_ptr, eid_arr, as1, ad1,
                                                 (const uint32*)h1, b1, (uint32*)out1);
    gemm2_mfma<<<391, 256, 0, stream>>>(out1, W2T, h2);
    alphas2_kernel<<<N_NODES, 128, 0, stream>>>(h2, a_src2, a_dst2, as2, ad2);
    agg2_kernel<<<N_NODES / 4, 256, 0, stream>>>(ei, row_ptr, eid_arr, as2, ad2,
                                                 (const uint32*)h2, b2, batch, pooled);
    fc_kernel<<<NGRAPH, 128, 0, stream>>>(pooled, fcW, fcb, out);
}

// Round 3
// 683.640 us; speedup vs baseline: 1.8042x; 1.1428x over previous
//
#include <hip/hip_runtime.h>
#include <hip/hip_bf16.h>
#include <stdint.h>

typedef unsigned int uint32;
typedef unsigned short u16;
typedef __attribute__((ext_vector_type(8))) short bf16x8;
typedef __attribute__((ext_vector_type(4))) float f32x4;

#define N_NODES 50000
#define N_EDGES 800000
#define ETOT    (N_EDGES + N_NODES)
#define F_INN   78
#define H1      10
#define D1      780
#define OUT2    128
#define NGRAPH  512
#define NEG_SLOPE 0.2f

#define NX  (N_NODES * F_INN)
#define NW1 (D1 * F_INN)
#define NW2 (OUT2 * D1)

__device__ __forceinline__ float lrelu(float v) { return v > 0.f ? v : NEG_SLOPE * v; }
__device__ __forceinline__ float bl(uint32 u) { return __uint_as_float(u << 16); }
__device__ __forceinline__ float bh(uint32 u) { return __uint_as_float(u & 0xffff0000u); }
__device__ __forceinline__ u16 f2bfbits(float f) {
    return __bfloat16_as_ushort(__float2bfloat16(f));
}
__device__ __forceinline__ uint32 packbf(float lo, float hi) {
    return (uint32)f2bfbits(lo) | ((uint32)f2bfbits(hi) << 16);
}
__device__ __forceinline__ int esrc(const int* ei, int e) { return e < N_EDGES ? ei[e] : e - N_EDGES; }
__device__ __forceinline__ int edst(const int* ei, int e) { return e < N_EDGES ? ei[N_EDGES + e] : e - N_EDGES; }

// ---------------- prep: x->bf16, W1->W1T bf16 [n][k], W2->W2T bf16 [n][k] ----------------
__global__ __launch_bounds__(256) void prep_kernel(const float* __restrict__ x,
                                                   const float* __restrict__ W1,
                                                   const float* __restrict__ W2,
                                                   u16* __restrict__ xb,
                                                   u16* __restrict__ W1T,
                                                   u16* __restrict__ W2T) {
    const int total = NX + NW1 + NW2;
    for (int id = blockIdx.x * 256 + threadIdx.x; id < total; id += gridDim.x * 256) {
        if (id < NX) {
            xb[id] = f2bfbits(x[id]);
        } else if (id < NX + NW1) {
            int t = id - NX;
            int n = t / F_INN, k = t - n * F_INN;
            W1T[t] = f2bfbits(W1[k * D1 + n]);
        } else {
            int t = id - NX - NW1;
            int n = t / D1, k = t - n * D1;
            W2T[t] = f2bfbits(W2[k * OUT2 + n]);
        }
    }
}

// ---------------- prep2: fold attention vectors through weights ----------------
// VAT[j][k] (32 x 78 bf16): j<10 -> W1 head-slice @ a_src1[h], j in 10..19 -> a_dst1, else 0
// w2a4[u] (390 float4): (src[2u], dst[2u], src[2u+1], dst[2u+1]) of W2 @ a_{src,dst}2
__global__ __launch_bounds__(256) void prep2_kernel(const float* __restrict__ W1,
                                                    const float* __restrict__ a_src1,
                                                    const float* __restrict__ a_dst1,
                                                    const float* __restrict__ W2,
                                                    const float* __restrict__ a_src2,
                                                    const float* __restrict__ a_dst2,
                                                    u16* __restrict__ VAT,
                                                    float4* __restrict__ w2a4) {
    int tid = threadIdx.x;
    for (int idx = tid; idx < 32 * F_INN; idx += 256) {
        int j = idx / F_INN, k = idx - j * F_INN;
        float s = 0.f;
        if (j < 20) {
            int h = (j < 10) ? j : j - 10;
            const float* vec = ((j < 10) ? a_src1 : a_dst1) + h * F_INN;
            const float* wrow = W1 + k * D1 + h * F_INN;
            for (int f = 0; f < F_INN; ++f) s = fmaf(wrow[f], vec[f], s);
        }
        VAT[j * F_INN + k] = f2bfbits(s);
    }
    for (int u = tid; u < 390; u += 256) {
        const float* r0 = W2 + (size_t)(2 * u) * OUT2;
        const float* r1 = r0 + OUT2;
        float s0 = 0.f, d0 = 0.f, s1 = 0.f, d1 = 0.f;
        for (int j = 0; j < OUT2; ++j) {
            float a2s = a_src2[j], a2d = a_dst2[j];
            s0 = fmaf(r0[j], a2s, s0);
            d0 = fmaf(r0[j], a2d, d0);
            s1 = fmaf(r1[j], a2s, s1);
            d1 = fmaf(r1[j], a2d, d1);
        }
        w2a4[u] = make_float4(s0, d0, s1, d1);
    }
}

// ---------------- GEMM1 (MFMA): xb[50000x78] @ W1[78x780] -> h1 bf16 ----------------
#define G1S 52
__global__ __launch_bounds__(256) void gemm1_mfma(const u16* __restrict__ xb,
                                                  const u16* __restrict__ W1T,
                                                  u16* __restrict__ h1) {
    __shared__ uint32 As[128 * G1S];
    __shared__ uint32 Bs[64 * G1S];
    int tid = threadIdx.x;
    int col0 = blockIdx.x * 64, row0 = blockIdx.y * 128;
    const uint32* xbu = (const uint32*)xb;
    const uint32* w1u = (const uint32*)W1T;

    for (int idx = tid; idx < 128 * 39; idx += 256) {
        int r = idx / 39, c = idx - r * 39;
        int gr = row0 + r;
        As[r * G1S + c] = (gr < N_NODES) ? xbu[gr * 39 + c] : 0u;
    }
    for (int idx = tid; idx < 128 * 9; idx += 256) {
        int r = idx / 9, c = 39 + (idx - r * 9);
        As[r * G1S + c] = 0u;
    }
    for (int idx = tid; idx < 64 * 39; idx += 256) {
        int n = idx / 39, c = idx - n * 39;
        int gn = col0 + n;
        Bs[n * G1S + c] = (gn < D1) ? w1u[gn * 39 + c] : 0u;
    }
    for (int idx = tid; idx < 64 * 9; idx += 256) {
        int n = idx / 9, c = 39 + (idx - n * 9);
        Bs[n * G1S + c] = 0u;
    }
    __syncthreads();

    int lane = tid & 63, wv = tid >> 6;
    int wm = wv >> 1, wn = wv & 1;
    int l15 = lane & 15, quad = lane >> 4;
    const u16* Asu = (const u16*)As;
    const u16* Bsu = (const u16*)Bs;

    f32x4 acc[4][2];
#pragma unroll
    for (int mi = 0; mi < 4; ++mi)
#pragma unroll
        for (int nj = 0; nj < 2; ++nj) acc[mi][nj] = (f32x4){0.f, 0.f, 0.f, 0.f};

    int abase[4], bbase[2];
#pragma unroll
    for (int mi = 0; mi < 4; ++mi) abase[mi] = (wm * 64 + mi * 16 + l15) * 104 + quad * 8;
#pragma unroll
    for (int nj = 0; nj < 2; ++nj) bbase[nj] = (wn * 32 + nj * 16 + l15) * 104 + quad * 8;

#pragma unroll
    for (int ks = 0; ks < 96; ks += 32) {
        bf16x8 a[4], b[2];
#pragma unroll
        for (int mi = 0; mi < 4; ++mi) a[mi] = *(const bf16x8*)(Asu + abase[mi] + ks);
#pragma unroll
        for (int nj = 0; nj < 2; ++nj) b[nj] = *(const bf16x8*)(Bsu + bbase[nj] + ks);
#pragma unroll
        for (int mi = 0; mi < 4; ++mi)
#pragma unroll
            for (int nj = 0; nj < 2; ++nj)
                acc[mi][nj] = __builtin_amdgcn_mfma_f32_16x16x32_bf16(a[mi], b[nj], acc[mi][nj], 0, 0, 0);
    }

#pragma unroll
    for (int mi = 0; mi < 4; ++mi)
#pragma unroll
        for (int nj = 0; nj < 2; ++nj)
#pragma unroll
            for (int reg = 0; reg < 4; ++reg) {
                int row = row0 + wm * 64 + mi * 16 + quad * 4 + reg;
                int col = col0 + wn * 32 + nj * 16 + l15;
                if (row < N_NODES && col < D1)
                    h1[(size_t)row * D1 + col] = f2bfbits(acc[mi][nj][reg]);
            }
}

// ---------------- alphas1 via folded vectors: xb[50000x78] @ VAT^T[78x32] ----------------
__global__ __launch_bounds__(256) void alphas1x_kernel(const u16* __restrict__ xb,
                                                       const u16* __restrict__ VAT,
                                                       float* __restrict__ as1,
                                                       float* __restrict__ ad1) {
    __shared__ uint32 As[128 * G1S];
    __shared__ uint32 Bs[32 * G1S];
    int tid = threadIdx.x;
    int row0 = blockIdx.x * 128;
    const uint32* xbu = (const uint32*)xb;
    const uint32* vau = (const uint32*)VAT;

    for (int idx = tid; idx < 128 * 39; idx += 256) {
        int r = idx / 39, c = idx - r * 39;
        int gr = row0 + r;
        As[r * G1S + c] = (gr < N_NODES) ? xbu[gr * 39 + c] : 0u;
    }
    for (int idx = tid; idx < 128 * 9; idx += 256) {
        int r = idx / 9, c = 39 + (idx - r * 9);
        As[r * G1S + c] = 0u;
    }
    for (int idx = tid; idx < 32 * 39; idx += 256) {
        int n = idx / 39, c = idx - n * 39;
        Bs[n * G1S + c] = vau[n * 39 + c];
    }
    for (int idx = tid; idx < 32 * 9; idx += 256) {
        int n = idx / 9, c = 39 + (idx - n * 9);
        Bs[n * G1S + c] = 0u;
    }
    __syncthreads();

    int lane = tid & 63, wv = tid >> 6;
    int wm = wv >> 1, wn = wv & 1;
    int l15 = lane & 15, quad = lane >> 4;
    const u16* Asu = (const u16*)As;
    const u16* Bsu = (const u16*)Bs;

    f32x4 acc[4];
#pragma unroll
    for (int mi = 0; mi < 4; ++mi) acc[mi] = (f32x4){0.f, 0.f, 0.f, 0.f};

    int abase[4];
#pragma unroll
    for (int mi = 0; mi < 4; ++mi) abase[mi] = (wm * 64 + mi * 16 + l15) * 104 + quad * 8;
    int bbase = (wn * 16 + l15) * 104 + quad * 8;

#pragma unroll
    for (int ks = 0; ks < 96; ks += 32) {
        bf16x8 b = *(const bf16x8*)(Bsu + bbase + ks);
#pragma unroll
        for (int mi = 0; mi < 4; ++mi) {
            bf16x8 a = *(const bf16x8*)(Asu + abase[mi] + ks);
            acc[mi] = __builtin_amdgcn_mfma_f32_16x16x32_bf16(a, b, acc[mi], 0, 0, 0);
        }
    }

    int col = wn * 16 + l15;
#pragma unroll
    for (int mi = 0; mi < 4; ++mi)
#pragma unroll
        for (int reg = 0; reg < 4; ++reg) {
            int row = row0 + wm * 64 + mi * 16 + quad * 4 + reg;
            if (row < N_NODES) {
                if (col < 10) as1[row * H1 + col] = acc[mi][reg];
                else if (col < 20) ad1[row * H1 + col - 10] = acc[mi][reg];
            }
        }
}

// ---------------- GEMM2 (MFMA): out1[50000x780] bf16 @ W2[780x128] -> h2 bf16 ----------------
#define G2S 36
__global__ __launch_bounds__(256) void gemm2_mfma(const u16* __restrict__ out1,
                                                  const u16* __restrict__ W2T,
                                                  u16* __restrict__ h2) {
    __shared__ uint32 As[64 * G2S];
    __shared__ uint32 Bs[128 * G2S];
    int tid = threadIdx.x;
    int row0 = blockIdx.x * 64;
    const uint32* o1u = (const uint32*)out1;
    const uint32* w2u = (const uint32*)W2T;

    int lane = tid & 63, wv = tid >> 6;
    int wm = wv >> 1, wn = wv & 1;
    int l15 = lane & 15, quad = lane >> 4;
    const u16* Asu = (const u16*)As;
    const u16* Bsu = (const u16*)Bs;

    f32x4 acc[2][4];
#pragma unroll
    for (int mi = 0; mi < 2; ++mi)
#pragma unroll
        for (int nj = 0; nj < 4; ++nj) acc[mi][nj] = (f32x4){0.f, 0.f, 0.f, 0.f};

    int abase[2], bbase[4];
#pragma unroll
    for (int mi = 0; mi < 2; ++mi) abase[mi] = (wm * 32 + mi * 16 + l15) * 72 + quad * 8;
#pragma unroll
    for (int nj = 0; nj < 4; ++nj) bbase[nj] = (wn * 64 + nj * 16 + l15) * 72 + quad * 8;

    for (int s = 0; s < 13; ++s) {
        int k0h = s * 32;
        for (int idx = tid; idx < 64 * 32; idx += 256) {
            int r = idx >> 5, c = idx & 31;
            int gr = row0 + r;
            As[r * G2S + c] = (gr < N_NODES && (k0h + c) < 390) ? o1u[(size_t)gr * 390 + k0h + c] : 0u;
        }
        for (int idx = tid; idx < 128 * 32; idx += 256) {
            int n = idx >> 5, c = idx & 31;
            Bs[n * G2S + c] = ((k0h + c) < 390) ? w2u[(size_t)n * 390 + k0h + c] : 0u;
        }
        __syncthreads();
#pragma unroll
        for (int ks = 0; ks < 64; ks += 32) {
            bf16x8 a[2], b[4];
#pragma unroll
            for (int mi = 0; mi < 2; ++mi) a[mi] = *(const bf16x8*)(Asu + abase[mi] + ks);
#pragma unroll
            for (int nj = 0; nj < 4; ++nj) b[nj] = *(const bf16x8*)(Bsu + bbase[nj] + ks);
#pragma unroll
            for (int mi = 0; mi < 2; ++mi)
#pragma unroll
                for (int nj = 0; nj < 4; ++nj)
                    acc[mi][nj] = __builtin_amdgcn_mfma_f32_16x16x32_bf16(a[mi], b[nj], acc[mi][nj], 0, 0, 0);
        }
        __syncthreads();
    }

#pragma unroll
    for (int mi = 0; mi < 2; ++mi)
#pragma unroll
        for (int nj = 0; nj < 4; ++nj)
#pragma unroll
            for (int reg = 0; reg < 4; ++reg) {
                int row = row0 + wm * 32 + mi * 16 + quad * 4 + reg;
                int col = wn * 64 + nj * 16 + l15;
                if (row < N_NODES)
                    h2[(size_t)row * OUT2 + col] = f2bfbits(acc[mi][nj][reg]);
            }
}

// ---------------- CSR build ----------------
__global__ void hist_kernel(const int* __restrict__ ei, int* __restrict__ deg) {
    int e = blockIdx.x * 256 + threadIdx.x;
    if (e < ETOT) atomicAdd(&deg[edst(ei, e)], 1);
}

__global__ __launch_bounds__(256) void scan1_kernel(const int* __restrict__ deg,
                                                    int* __restrict__ row_ptr,
                                                    int* __restrict__ bsum) {
    __shared__ int buf[256];
    int tid = threadIdx.x;
    int i = blockIdx.x * 256 + tid;
    int v = (i < N_NODES) ? deg[i] : 0;
    buf[tid] = v;
    __syncthreads();
    for (int off = 1; off < 256; off <<= 1) {
        int t = (tid >= off) ? buf[tid - off] : 0;
        __syncthreads();
        buf[tid] += t;
        __syncthreads();
    }
    if (i < N_NODES) row_ptr[i] = buf[tid] - v;
    if (tid == 255) bsum[blockIdx.x] = buf[255];
}

__global__ __launch_bounds__(256) void scan2_kernel(const int* __restrict__ bsum,
                                                    int* __restrict__ boff) {
    __shared__ int buf[256];
    int tid = threadIdx.x;
    int v = (tid < 196) ? bsum[tid] : 0;
    buf[tid] = v;
    __syncthreads();
    for (int off = 1; off < 256; off <<= 1) {
        int t = (tid >= off) ? buf[tid - off] : 0;
        __syncthreads();
        buf[tid] += t;
        __syncthreads();
    }
    if (tid < 196) boff[tid] = buf[tid] - v;
}

__global__ __launch_bounds__(256) void scan3_kernel(int* __restrict__ row_ptr,
                                                    const int* __restrict__ boff,
                                                    int* __restrict__ cursor) {
    int i = blockIdx.x * 256 + threadIdx.x;
    if (i < N_NODES) {
        int r = row_ptr[i] + boff[blockIdx.x];
        row_ptr[i] = r;
        cursor[i] = r;
    }
    if (i == 0) row_ptr[N_NODES] = ETOT;
}

__global__ void scatter_kernel(const int* __restrict__ ei, int* __restrict__ cursor,
                               int* __restrict__ src_arr) {
    int e = blockIdx.x * 256 + threadIdx.x;
    if (e < ETOT) {
        int pos = atomicAdd(&cursor[edst(ei, e)], 1);
        src_arr[pos] = esrc(ei, e);
    }
}

// ---------------- layer-1 aggregation: 2 waves per node (5 heads each) ----------------
// Also fuses layer-2 alpha projections: as2/ad2 += out1_row . w2a
__global__ __launch_bounds__(256) void agg1_kernel(const int* __restrict__ row_ptr,
                                                   const int* __restrict__ src_arr,
                                                   const float* __restrict__ as1,
                                                   const float* __restrict__ ad1,
                                                   const uint32* __restrict__ h1u,
                                                   const float* __restrict__ b1,
                                                   const float4* __restrict__ w2a4,
                                                   uint32* __restrict__ out1u,
                                                   float* __restrict__ as2,
                                                   float* __restrict__ ad2) {
    __shared__ float w_sh[4][64 * 5];
    __shared__ int src_sh[4][64];
    int tid = threadIdx.x, lane = tid & 63, wv = tid >> 6;
    int i = blockIdx.x * 2 + (wv >> 1);
    int half = wv & 1, h0 = half * 5;
    int rs = row_ptr[i], deg = row_ptr[i + 1] - rs;

    float adst[5];
#pragma unroll
    for (int k = 0; k < 5; ++k) adst[k] = ad1[i * H1 + h0 + k];

    // online softmax over this wave's 5 heads
    float m[5], ss[5];
#pragma unroll
    for (int k = 0; k < 5; ++k) { m[k] = -1e30f; ss[k] = 0.f; }
    for (int eix = lane; eix < deg; eix += 64) {
        int sn = src_arr[rs + eix];
        const float* ap = as1 + sn * H1 + h0;
#pragma unroll
        for (int k = 0; k < 5; ++k) {
            float v = lrelu(ap[k] + adst[k]);
            float nm = fmaxf(m[k], v);
            ss[k] = ss[k] * __expf(m[k] - nm) + __expf(v - nm);
            m[k] = nm;
        }
    }
#pragma unroll
    for (int off = 1; off < 64; off <<= 1) {
#pragma unroll
        for (int k = 0; k < 5; ++k) {
            float mo = __shfl_xor(m[k], off, 64);
            float so = __shfl_xor(ss[k], off, 64);
            float nm = fmaxf(m[k], mo);
            ss[k] = ss[k] * __expf(m[k] - nm) + so * __expf(mo - nm);
            m[k] = nm;
        }
    }
    float rden[5];
#pragma unroll
    for (int k = 0; k < 5; ++k) rden[k] = 1.f / (ss[k] + 1e-16f);

    // gather over half-row: 195 uints; lane covers u=lane+64q (q<3) + tail lanes 0..2
    float acc[8];
#pragma unroll
    for (int q = 0; q < 8; ++q) acc[q] = 0.f;
    int hq[3];
#pragma unroll
    for (int q = 0; q < 3; ++q) hq[q] = (lane + 64 * q) / 39;
    bool tail = lane < 3;
    size_t hbase = (size_t)half * 195;

    for (int base = 0; base < deg; base += 64) {
        int cnt = min(deg - base, 64);
        if (lane < cnt) {
            int sn = src_arr[rs + base + lane];
            src_sh[wv][lane] = sn;
            const float* ap = as1 + sn * H1 + h0;
#pragma unroll
            for (int k = 0; k < 5; ++k)
                w_sh[wv][lane * 5 + k] = __expf(lrelu(ap[k] + adst[k]) - m[k]) * rden[k];
        }
        __builtin_amdgcn_wave_barrier();
        int eix = 0;
        for (; eix + 1 < cnt; eix += 2) {
            int s0 = src_sh[wv][eix], s1 = src_sh[wv][eix + 1];
            const uint32* r0 = h1u + (size_t)s0 * 390 + hbase;
            const uint32* r1 = h1u + (size_t)s1 * 390 + hbase;
            const float* w0 = &w_sh[wv][eix * 5];
            const float* w1 = &w_sh[wv][(eix + 1) * 5];
            uint32 uv0[3], uv1[3], t0 = 0, t1 = 0;
#pragma unroll
            for (int q = 0; q < 3; ++q) { uv0[q] = r0[lane + 64 * q]; uv1[q] = r1[lane + 64 * q]; }
            if (tail) { t0 = r0[192 + lane]; t1 = r1[192 + lane]; }
#pragma unroll
            for (int q = 0; q < 3; ++q) {
                float wa = w0[hq[q]], wb = w1[hq[q]];
                acc[2 * q]     = fmaf(wa, bl(uv0[q]), fmaf(wb, bl(uv1[q]), acc[2 * q]));
                acc[2 * q + 1] = fmaf(wa, bh(uv0[q]), fmaf(wb, bh(uv1[q]), acc[2 * q + 1]));
            }
            if (tail) {
                float wa = w0[4], wb = w1[4];
                acc[6] = fmaf(wa, bl(t0), fmaf(wb, bl(t1), acc[6]));
                acc[7] = fmaf(wa, bh(t0), fmaf(wb, bh(t1), acc[7]));
            }
        }
        if (eix < cnt) {
            int s0 = src_sh[wv][eix];
            const uint32* r0 = h1u + (size_t)s0 * 390 + hbase;
            const float* w0 = &w_sh[wv][eix * 5];
#pragma unroll
            for (int q = 0; q < 3; ++q) {
                uint32 uv = r0[lane + 64 * q];
                float wa = w0[hq[q]];
                acc[2 * q]     = fmaf(wa, bl(uv), acc[2 * q]);
                acc[2 * q + 1] = fmaf(wa, bh(uv), acc[2 * q + 1]);
            }
            if (tail) {
                uint32 uv = r0[192 + lane];
                float wa = w0[4];
                acc[6] = fmaf(wa, bl(uv), acc[6]);
                acc[7] = fmaf(wa, bh(uv), acc[7]);
            }
        }
        __builtin_amdgcn_wave_barrier();
    }

    // epilogue: bias + relu + pack + store; fused layer-2 alpha dots
    uint32* orow = out1u + (size_t)i * 390;
    const float2* bp = (const float2*)b1;
    float s2 = 0.f, d2 = 0.f;
#pragma unroll
    for (int q = 0; q < 3; ++q) {
        int ug = (int)hbase + lane + 64 * q;
        float2 bv = bp[ug];
        float v0 = fmaxf(acc[2 * q] + bv.x, 0.f);
        float v1 = fmaxf(acc[2 * q + 1] + bv.y, 0.f);
        orow[ug] = packbf(v0, v1);
        float4 w = w2a4[ug];
        s2 = fmaf(v0, w.x, fmaf(v1, w.z, s2));
        d2 = fmaf(v0, w.y, fmaf(v1, w.w, d2));
    }
    if (tail) {
        int ug = (int)hbase + 192 + lane;
        float2 bv = bp[ug];
        float v0 = fmaxf(acc[6] + bv.x, 0.f);
        float v1 = fmaxf(acc[7] + bv.y, 0.f);
        orow[ug] = packbf(v0, v1);
        float4 w = w2a4[ug];
        s2 = fmaf(v0, w.x, fmaf(v1, w.z, s2));
        d2 = fmaf(v0, w.y, fmaf(v1, w.w, d2));
    }
#pragma unroll
    for (int off = 32; off; off >>= 1) {
        s2 += __shfl_xor(s2, off, 64);
        d2 += __shfl_xor(d2, off, 64);
    }
    if (lane == 0) {
        atomicAdd(&as2[i], s2);
        atomicAdd(&ad2[i], d2);
    }
}

// ---------------- layer-2 aggregation + pool: one wave per node ----------------
__global__ __launch_bounds__(256) void agg2_kernel(const int* __restrict__ row_ptr,
                                                   const int* __restrict__ src_arr,
                                                   const float* __restrict__ as2,
                                                   const float* __restrict__ ad2,
                                                   const uint32* __restrict__ h2u,
                                                   const float* __restrict__ b2,
                                                   const int* __restrict__ batch,
                                                   float* __restrict__ pooled) {
    __shared__ float w_sh[4][64];
    __shared__ int src_sh[4][64];
    int tid = threadIdx.x, lane = tid & 63, wv = tid >> 6;
    int i = blockIdx.x * 4 + wv;
    int rs = row_ptr[i], deg = row_ptr[i + 1] - rs;
    float adst = ad2[i];

    float m = -1e30f, ss = 0.f;
    for (int eix = lane; eix < deg; eix += 64) {
        int sn = src_arr[rs + eix];
        float v = lrelu(as2[sn] + adst);
        float nm = fmaxf(m, v);
        ss = ss * __expf(m - nm) + __expf(v - nm);
        m = nm;
    }
#pragma unroll
    for (int off = 1; off < 64; off <<= 1) {
        float mo = __shfl_xor(m, off, 64);
        float so = __shfl_xor(ss, off, 64);
        float nm = fmaxf(m, mo);
        ss = ss * __expf(m - nm) + so * __expf(mo - nm);
        m = nm;
    }
    float rden = 1.f / (ss + 1e-16f);

    float a0 = 0.f, a1 = 0.f;
    for (int base = 0; base < deg; base += 64) {
        int cnt = min(deg - base, 64);
        if (lane < cnt) {
            int sn = src_arr[rs + base + lane];
            src_sh[wv][lane] = sn;
            w_sh[wv][lane] = __expf(lrelu(as2[sn] + adst) - m) * rden;
        }
        __builtin_amdgcn_wave_barrier();
        int eix = 0;
        for (; eix + 1 < cnt; eix += 2) {
            int s0 = src_sh[wv][eix], s1 = src_sh[wv][eix + 1];
            float w0 = w_sh[wv][eix], w1 = w_sh[wv][eix + 1];
            uint32 u0 = h2u[(size_t)s0 * 64 + lane];
            uint32 u1 = h2u[(size_t)s1 * 64 + lane];
            a0 = fmaf(w0, bl(u0), fmaf(w1, bl(u1), a0));
            a1 = fmaf(w0, bh(u0), fmaf(w1, bh(u1), a1));
        }
        if (eix < cnt) {
            int s0 = src_sh[wv][eix];
            float w0 = w_sh[wv][eix];
            uint32 u0 = h2u[(size_t)s0 * 64 + lane];
            a0 = fmaf(w0, bl(u0), a0);
            a1 = fmaf(w0, bh(u0), a1);
        }
        __builtin_amdgcn_wave_barrier();
    }
    float2 bv = ((const float2*)b2)[lane];
    float v0 = fmaxf(a0 + bv.x, 0.f);
    float v1 = fmaxf(a1 + bv.y, 0.f);
    int g = batch[i];
    atomicMax((int*)&pooled[g * OUT2 + 2 * lane], __float_as_int(v0));
    atomicMax((int*)&pooled[g * OUT2 + 2 * lane + 1], __float_as_int(v1));
}

// ---------------- final FC + relu ----------------
__global__ __launch_bounds__(128) void fc_kernel(const float* __restrict__ pooled,
                                                 const float* __restrict__ fcW,
                                                 const float* __restrict__ fcb,
                                                 float* __restrict__ out) {
    int g = blockIdx.x, tid = threadIdx.x;
    __shared__ float p[128];
    p[tid] = pooled[g * OUT2 + tid];
    __syncthreads();
    float acc = fcb[tid];
    for (int k = 0; k < 128; ++k) acc = fmaf(p[k], fcW[k * OUT2 + tid], acc);
    out[g * OUT2 + tid] = fmaxf(acc, 0.f);
}

extern "C" void kernel_launch(void* const* d_in, const int* in_sizes, int n_in,
                              void* d_out, int out_size, void* d_ws, size_t ws_size,
                              hipStream_t stream) {
    const float* x      = (const float*)d_in[0];
    const int*   ei     = (const int*)d_in[1];
    const int*   batch  = (const int*)d_in[2];
    const float* W1     = (const float*)d_in[4];
    const float* a_src1 = (const float*)d_in[5];
    const float* a_dst1 = (const float*)d_in[6];
    const float* b1     = (const float*)d_in[7];
    const float* W2     = (const float*)d_in[8];
    const float* a_src2 = (const float*)d_in[9];
    const float* a_dst2 = (const float*)d_in[10];
    const float* b2     = (const float*)d_in[11];
    const float* fcW    = (const float*)d_in[12];
    const float* fcb    = (const float*)d_in[13];
    float* out = (float*)d_out;

    size_t off = 0;
    char* base = (char*)d_ws;
    auto alloc = [&](size_t bytes) -> void* {
        void* p = base + off;
        off += (bytes + 255) & ~(size_t)255;
        return p;
    };
    u16* h1     = (u16*)alloc((size_t)N_NODES * D1 * 2);
    u16* out1   = (u16*)alloc((size_t)N_NODES * D1 * 2);
    u16* h2     = (u16*)alloc((size_t)N_NODES * OUT2 * 2);  // also hosts xb early
    u16* xb     = h2;   // xb dead before gemm2 writes h2
    float* as1  = (float*)alloc((size_t)N_NODES * H1 * 4);
    float* ad1  = (float*)alloc((size_t)N_NODES * H1 * 4);
    float* as2  = (float*)alloc((size_t)N_NODES * 4);
    float* ad2  = (float*)alloc((size_t)N_NODES * 4);
    u16* W1T    = (u16*)alloc((size_t)NW1 * 2);
    u16* W2T    = (u16*)alloc((size_t)NW2 * 2);
    u16* VAT    = (u16*)alloc((size_t)32 * F_INN * 2);
    float4* w2a4 = (float4*)alloc((size_t)390 * 16);
    float* pooled = (float*)alloc((size_t)NGRAPH * OUT2 * 4);
    int* deg     = (int*)alloc((size_t)N_NODES * 4);
    int* row_ptr = (int*)alloc((size_t)(N_NODES + 1) * 4);
    int* cursor  = (int*)alloc((size_t)N_NODES * 4);
    int* src_arr = (int*)alloc((size_t)ETOT * 4);
    int* bsum    = (int*)alloc(196 * 4);
    int* boff    = (int*)alloc(196 * 4);

    hipMemsetAsync(deg, 0, (size_t)N_NODES * 4, stream);
    hipMemsetAsync(pooled, 0, (size_t)NGRAPH * OUT2 * 4, stream);
    hipMemsetAsync(as2, 0, (size_t)N_NODES * 4, stream);
    hipMemsetAsync(ad2, 0, (size_t)N_NODES * 4, stream);

    prep_kernel<<<2048, 256, 0, stream>>>(x, W1, W2, xb, W1T, W2T);
    prep2_kernel<<<1, 256, 0, stream>>>(W1, a_src1, a_dst1, W2, a_src2, a_dst2, VAT, w2a4);
    alphas1x_kernel<<<391, 256, 0, stream>>>(xb, VAT, as1, ad1);
    gemm1_mfma<<<dim3(13, 391), 256, 0, stream>>>(xb, W1T, h1);
    hist_kernel<<<(ETOT + 255) / 256, 256, 0, stream>>>(ei, deg);
    scan1_kernel<<<196, 256, 0, stream>>>(deg, row_ptr, bsum);
    scan2_kernel<<<1, 256, 0, stream>>>(bsum, boff);
    scan3_kernel<<<196, 256, 0, stream>>>(row_ptr, boff, cursor);
    scatter_kernel<<<(ETOT + 255) / 256, 256, 0, stream>>>(ei, cursor, src_arr);
    agg1_kernel<<<N_NODES / 2, 256, 0, stream>>>(row_ptr, src_arr, as1, ad1,
                                                 (const uint32*)h1, b1, w2a4,
                                                 (uint32*)out1, as2, ad2);
    gemm2_mfma<<<782, 256, 0, stream>>>(out1, W2T, h2);
    agg2_kernel<<<N_NODES / 4, 256, 0, stream>>>(row_ptr, src_arr, as2, ad2,
                                                 (const uint32*)h2, b2, batch, pooled);
    fc_kernel<<<NGRAPH, 128, 0, stream>>>(pooled, fcW, fcb, out);
}

// Round 4
// 659.334 us; speedup vs baseline: 1.8707x; 1.0369x over previous
//
#include <hip/hip_runtime.h>
#include <hip/hip_bf16.h>
#include <stdint.h>

typedef unsigned int uint32;
typedef unsigned short u16;
typedef __attribute__((ext_vector_type(8))) short bf16x8;
typedef __attribute__((ext_vector_type(4))) float f32x4;
typedef __attribute__((ext_vector_type(2))) float f32x2;
typedef uint32 u32x3 __attribute__((ext_vector_type(3)));
typedef u32x3 u32x3a __attribute__((aligned(4)));   // 4B-aligned dwordx3 load

#define N_NODES 50000
#define N_EDGES 800000
#define ETOT    (N_EDGES + N_NODES)
#define F_INN   78
#define H1      10
#define D1      780
#define OUT2    128
#define NGRAPH  512
#define NEG_SLOPE 0.2f

#define NX  (N_NODES * F_INN)
#define NW1 (D1 * F_INN)
#define NW2 (OUT2 * D1)

__device__ __forceinline__ float lrelu(float v) { return v > 0.f ? v : NEG_SLOPE * v; }
__device__ __forceinline__ float bl(uint32 u) { return __uint_as_float(u << 16); }
__device__ __forceinline__ float bh(uint32 u) { return __uint_as_float(u & 0xffff0000u); }
__device__ __forceinline__ u16 f2bfbits(float f) {
    return __bfloat16_as_ushort(__float2bfloat16(f));
}
__device__ __forceinline__ uint32 packbf(float lo, float hi) {
    return (uint32)f2bfbits(lo) | ((uint32)f2bfbits(hi) << 16);
}
// bf16-pair -> float2 (native cvt on gfx950; falls back to shifts)
__device__ __forceinline__ f32x2 bf2(uint32 u) {
    __hip_bfloat162 b = *reinterpret_cast<__hip_bfloat162*>(&u);
    float2 t = __bfloat1622float2(b);
    return (f32x2){t.x, t.y};
}
__device__ __forceinline__ int esrc(const int* ei, int e) { return e < N_EDGES ? ei[e] : e - N_EDGES; }
__device__ __forceinline__ int edst(const int* ei, int e) { return e < N_EDGES ? ei[N_EDGES + e] : e - N_EDGES; }

// ---------------- prep: x->bf16, W1->W1T bf16 [n][k], W2->W2T bf16 [n][k] ----------------
__global__ __launch_bounds__(256) void prep_kernel(const float* __restrict__ x,
                                                   const float* __restrict__ W1,
                                                   const float* __restrict__ W2,
                                                   u16* __restrict__ xb,
                                                   u16* __restrict__ W1T,
                                                   u16* __restrict__ W2T) {
    const int total = NX + NW1 + NW2;
    for (int id = blockIdx.x * 256 + threadIdx.x; id < total; id += gridDim.x * 256) {
        if (id < NX) {
            xb[id] = f2bfbits(x[id]);
        } else if (id < NX + NW1) {
            int t = id - NX;
            int n = t / F_INN, k = t - n * F_INN;
            W1T[t] = f2bfbits(W1[k * D1 + n]);
        } else {
            int t = id - NX - NW1;
            int n = t / D1, k = t - n * D1;
            W2T[t] = f2bfbits(W2[k * OUT2 + n]);
        }
    }
}

// ---------------- prep2: fold attention vectors through weights ----------------
__global__ __launch_bounds__(256) void prep2_kernel(const float* __restrict__ W1,
                                                    const float* __restrict__ a_src1,
                                                    const float* __restrict__ a_dst1,
                                                    const float* __restrict__ W2,
                                                    const float* __restrict__ a_src2,
                                                    const float* __restrict__ a_dst2,
                                                    u16* __restrict__ VAT,
                                                    float4* __restrict__ w2a4) {
    int gid = blockIdx.x * 256 + threadIdx.x;
    int gs = gridDim.x * 256;
    for (int idx = gid; idx < 32 * F_INN; idx += gs) {
        int j = idx / F_INN, k = idx - j * F_INN;
        float s = 0.f;
        if (j < 20) {
            int h = (j < 10) ? j : j - 10;
            const float* vec = ((j < 10) ? a_src1 : a_dst1) + h * F_INN;
            const float* wrow = W1 + k * D1 + h * F_INN;
            for (int f = 0; f < F_INN; ++f) s = fmaf(wrow[f], vec[f], s);
        }
        VAT[j * F_INN + k] = f2bfbits(s);
    }
    for (int u = gid; u < 390; u += gs) {
        const float* r0 = W2 + (size_t)(2 * u) * OUT2;
        const float* r1 = r0 + OUT2;
        float s0 = 0.f, d0 = 0.f, s1 = 0.f, d1 = 0.f;
        for (int j = 0; j < OUT2; ++j) {
            float a2s = a_src2[j], a2d = a_dst2[j];
            s0 = fmaf(r0[j], a2s, s0);
            d0 = fmaf(r0[j], a2d, d0);
            s1 = fmaf(r1[j], a2s, s1);
            d1 = fmaf(r1[j], a2d, d1);
        }
        w2a4[u] = make_float4(s0, d0, s1, d1);
    }
}

// ---------------- GEMM1 (MFMA): xb[50000x78] @ W1[78x780] -> h1 bf16 ----------------
#define G1S 52
__global__ __launch_bounds__(256) void gemm1_mfma(const u16* __restrict__ xb,
                                                  const u16* __restrict__ W1T,
                                                  u16* __restrict__ h1) {
    __shared__ uint32 As[128 * G1S];
    __shared__ uint32 Bs[64 * G1S];
    int tid = threadIdx.x;
    int col0 = blockIdx.x * 64, row0 = blockIdx.y * 128;
    const uint32* xbu = (const uint32*)xb;
    const uint32* w1u = (const uint32*)W1T;

    for (int idx = tid; idx < 128 * 39; idx += 256) {
        int r = idx / 39, c = idx - r * 39;
        int gr = row0 + r;
        As[r * G1S + c] = (gr < N_NODES) ? xbu[gr * 39 + c] : 0u;
    }
    for (int idx = tid; idx < 128 * 9; idx += 256) {
        int r = idx / 9, c = 39 + (idx - r * 9);
        As[r * G1S + c] = 0u;
    }
    for (int idx = tid; idx < 64 * 39; idx += 256) {
        int n = idx / 39, c = idx - n * 39;
        int gn = col0 + n;
        Bs[n * G1S + c] = (gn < D1) ? w1u[gn * 39 + c] : 0u;
    }
    for (int idx = tid; idx < 64 * 9; idx += 256) {
        int n = idx / 9, c = 39 + (idx - n * 9);
        Bs[n * G1S + c] = 0u;
    }
    __syncthreads();

    int lane = tid & 63, wv = tid >> 6;
    int wm = wv >> 1, wn = wv & 1;
    int l15 = lane & 15, quad = lane >> 4;
    const u16* Asu = (const u16*)As;
    const u16* Bsu = (const u16*)Bs;

    f32x4 acc[4][2];
#pragma unroll
    for (int mi = 0; mi < 4; ++mi)
#pragma unroll
        for (int nj = 0; nj < 2; ++nj) acc[mi][nj] = (f32x4){0.f, 0.f, 0.f, 0.f};

    int abase[4], bbase[2];
#pragma unroll
    for (int mi = 0; mi < 4; ++mi) abase[mi] = (wm * 64 + mi * 16 + l15) * 104 + quad * 8;
#pragma unroll
    for (int nj = 0; nj < 2; ++nj) bbase[nj] = (wn * 32 + nj * 16 + l15) * 104 + quad * 8;

#pragma unroll
    for (int ks = 0; ks < 96; ks += 32) {
        bf16x8 a[4], b[2];
#pragma unroll
        for (int mi = 0; mi < 4; ++mi) a[mi] = *(const bf16x8*)(Asu + abase[mi] + ks);
#pragma unroll
        for (int nj = 0; nj < 2; ++nj) b[nj] = *(const bf16x8*)(Bsu + bbase[nj] + ks);
#pragma unroll
        for (int mi = 0; mi < 4; ++mi)
#pragma unroll
            for (int nj = 0; nj < 2; ++nj)
                acc[mi][nj] = __builtin_amdgcn_mfma_f32_16x16x32_bf16(a[mi], b[nj], acc[mi][nj], 0, 0, 0);
    }

#pragma unroll
    for (int mi = 0; mi < 4; ++mi)
#pragma unroll
        for (int nj = 0; nj < 2; ++nj)
#pragma unroll
            for (int reg = 0; reg < 4; ++reg) {
                int row = row0 + wm * 64 + mi * 16 + quad * 4 + reg;
                int col = col0 + wn * 32 + nj * 16 + l15;
                if (row < N_NODES && col < D1)
                    h1[(size_t)row * D1 + col] = f2bfbits(acc[mi][nj][reg]);
            }
}

// ---------------- alphas1 via folded vectors: xb[50000x78] @ VAT^T[78x32] ----------------
__global__ __launch_bounds__(256) void alphas1x_kernel(const u16* __restrict__ xb,
                                                       const u16* __restrict__ VAT,
                                                       float* __restrict__ as1,
                                                       float* __restrict__ ad1) {
    __shared__ uint32 As[128 * G1S];
    __shared__ uint32 Bs[32 * G1S];
    int tid = threadIdx.x;
    int row0 = blockIdx.x * 128;
    const uint32* xbu = (const uint32*)xb;
    const uint32* vau = (const uint32*)VAT;

    for (int idx = tid; idx < 128 * 39; idx += 256) {
        int r = idx / 39, c = idx - r * 39;
        int gr = row0 + r;
        As[r * G1S + c] = (gr < N_NODES) ? xbu[gr * 39 + c] : 0u;
    }
    for (int idx = tid; idx < 128 * 9; idx += 256) {
        int r = idx / 9, c = 39 + (idx - r * 9);
        As[r * G1S + c] = 0u;
    }
    for (int idx = tid; idx < 32 * 39; idx += 256) {
        int n = idx / 39, c = idx - n * 39;
        Bs[n * G1S + c] = vau[n * 39 + c];
    }
    for (int idx = tid; idx < 32 * 9; idx += 256) {
        int n = idx / 9, c = 39 + (idx - n * 9);
        Bs[n * G1S + c] = 0u;
    }
    __syncthreads();

    int lane = tid & 63, wv = tid >> 6;
    int wm = wv >> 1, wn = wv & 1;
    int l15 = lane & 15, quad = lane >> 4;
    const u16* Asu = (const u16*)As;
    const u16* Bsu = (const u16*)Bs;

    f32x4 acc[4];
#pragma unroll
    for (int mi = 0; mi < 4; ++mi) acc[mi] = (f32x4){0.f, 0.f, 0.f, 0.f};

    int abase[4];
#pragma unroll
    for (int mi = 0; mi < 4; ++mi) abase[mi] = (wm * 64 + mi * 16 + l15) * 104 + quad * 8;
    int bbase = (wn * 16 + l15) * 104 + quad * 8;

#pragma unroll
    for (int ks = 0; ks < 96; ks += 32) {
        bf16x8 b = *(const bf16x8*)(Bsu + bbase + ks);
#pragma unroll
        for (int mi = 0; mi < 4; ++mi) {
            bf16x8 a = *(const bf16x8*)(Asu + abase[mi] + ks);
            acc[mi] = __builtin_amdgcn_mfma_f32_16x16x32_bf16(a, b, acc[mi], 0, 0, 0);
        }
    }

    int col = wn * 16 + l15;
#pragma unroll
    for (int mi = 0; mi < 4; ++mi)
#pragma unroll
        for (int reg = 0; reg < 4; ++reg) {
            int row = row0 + wm * 64 + mi * 16 + quad * 4 + reg;
            if (row < N_NODES) {
                if (col < 10) as1[row * H1 + col] = acc[mi][reg];
                else if (col < 20) ad1[row * H1 + col - 10] = acc[mi][reg];
            }
        }
}

// ---------------- GEMM2 (MFMA): out1[50000x780] bf16 @ W2[780x128] -> h2 bf16 ----------------
#define G2S 36
__global__ __launch_bounds__(256) void gemm2_mfma(const u16* __restrict__ out1,
                                                  const u16* __restrict__ W2T,
                                                  u16* __restrict__ h2) {
    __shared__ uint32 As[64 * G2S];
    __shared__ uint32 Bs[128 * G2S];
    int tid = threadIdx.x;
    int row0 = blockIdx.x * 64;
    const uint32* o1u = (const uint32*)out1;
    const uint32* w2u = (const uint32*)W2T;

    int lane = tid & 63, wv = tid >> 6;
    int wm = wv >> 1, wn = wv & 1;
    int l15 = lane & 15, quad = lane >> 4;
    const u16* Asu = (const u16*)As;
    const u16* Bsu = (const u16*)Bs;

    f32x4 acc[2][4];
#pragma unroll
    for (int mi = 0; mi < 2; ++mi)
#pragma unroll
        for (int nj = 0; nj < 4; ++nj) acc[mi][nj] = (f32x4){0.f, 0.f, 0.f, 0.f};

    int abase[2], bbase[4];
#pragma unroll
    for (int mi = 0; mi < 2; ++mi) abase[mi] = (wm * 32 + mi * 16 + l15) * 72 + quad * 8;
#pragma unroll
    for (int nj = 0; nj < 4; ++nj) bbase[nj] = (wn * 64 + nj * 16 + l15) * 72 + quad * 8;

    for (int s = 0; s < 13; ++s) {
        int k0h = s * 32;
        for (int idx = tid; idx < 64 * 32; idx += 256) {
            int r = idx >> 5, c = idx & 31;
            int gr = row0 + r;
            As[r * G2S + c] = (gr < N_NODES && (k0h + c) < 390) ? o1u[(size_t)gr * 390 + k0h + c] : 0u;
        }
        for (int idx = tid; idx < 128 * 32; idx += 256) {
            int n = idx >> 5, c = idx & 31;
            Bs[n * G2S + c] = ((k0h + c) < 390) ? w2u[(size_t)n * 390 + k0h + c] : 0u;
        }
        __syncthreads();
#pragma unroll
        for (int ks = 0; ks < 64; ks += 32) {
            bf16x8 a[2], b[4];
#pragma unroll
            for (int mi = 0; mi < 2; ++mi) a[mi] = *(const bf16x8*)(Asu + abase[mi] + ks);
#pragma unroll
            for (int nj = 0; nj < 4; ++nj) b[nj] = *(const bf16x8*)(Bsu + bbase[nj] + ks);
#pragma unroll
            for (int mi = 0; mi < 2; ++mi)
#pragma unroll
                for (int nj = 0; nj < 4; ++nj)
                    acc[mi][nj] = __builtin_amdgcn_mfma_f32_16x16x32_bf16(a[mi], b[nj], acc[mi][nj], 0, 0, 0);
        }
        __syncthreads();
    }

#pragma unroll
    for (int mi = 0; mi < 2; ++mi)
#pragma unroll
        for (int nj = 0; nj < 4; ++nj)
#pragma unroll
            for (int reg = 0; reg < 4; ++reg) {
                int row = row0 + wm * 32 + mi * 16 + quad * 4 + reg;
                int col = wn * 64 + nj * 16 + l15;
                if (row < N_NODES)
                    h2[(size_t)row * OUT2 + col] = f2bfbits(acc[mi][nj][reg]);
            }
}

// ---------------- CSR build ----------------
__global__ void hist_kernel(const int* __restrict__ ei, int* __restrict__ deg) {
    int e = blockIdx.x * 256 + threadIdx.x;
    if (e < ETOT) atomicAdd(&deg[edst(ei, e)], 1);
}

__global__ __launch_bounds__(256) void scan1_kernel(const int* __restrict__ deg,
                                                    int* __restrict__ row_ptr,
                                                    int* __restrict__ bsum) {
    __shared__ int buf[256];
    int tid = threadIdx.x;
    int i = blockIdx.x * 256 + tid;
    int v = (i < N_NODES) ? deg[i] : 0;
    buf[tid] = v;
    __syncthreads();
    for (int off = 1; off < 256; off <<= 1) {
        int t = (tid >= off) ? buf[tid - off] : 0;
        __syncthreads();
        buf[tid] += t;
        __syncthreads();
    }
    if (i < N_NODES) row_ptr[i] = buf[tid] - v;
    if (tid == 255) bsum[blockIdx.x] = buf[255];
}

__global__ __launch_bounds__(256) void scan2_kernel(const int* __restrict__ bsum,
                                                    int* __restrict__ boff) {
    __shared__ int buf[256];
    int tid = threadIdx.x;
    int v = (tid < 196) ? bsum[tid] : 0;
    buf[tid] = v;
    __syncthreads();
    for (int off = 1; off < 256; off <<= 1) {
        int t = (tid >= off) ? buf[tid - off] : 0;
        __syncthreads();
        buf[tid] += t;
        __syncthreads();
    }
    if (tid < 196) boff[tid] = buf[tid] - v;
}

__global__ __launch_bounds__(256) void scan3_kernel(int* __restrict__ row_ptr,
                                                    const int* __restrict__ boff,
                                                    int* __restrict__ cursor) {
    int i = blockIdx.x * 256 + threadIdx.x;
    if (i < N_NODES) {
        int r = row_ptr[i] + boff[blockIdx.x];
        row_ptr[i] = r;
        cursor[i] = r;
    }
    if (i == 0) row_ptr[N_NODES] = ETOT;
}

__global__ void scatter_kernel(const int* __restrict__ ei, int* __restrict__ cursor,
                               int* __restrict__ src_arr) {
    int e = blockIdx.x * 256 + threadIdx.x;
    if (e < ETOT) {
        int pos = atomicAdd(&cursor[edst(ei, e)], 1);
        src_arr[pos] = esrc(ei, e);
    }
}

// ---------------- layer-1 aggregation: 2 waves per node (5 heads each) ----------------
// lane covers uints {3*lane..3*lane+2} of the 195-uint half-row (one dwordx3 load);
// a lane's 3 uints never straddle a 39-uint head boundary -> ONE weight per lane.
__global__ __launch_bounds__(256) void agg1_kernel(const int* __restrict__ row_ptr,
                                                   const int* __restrict__ src_arr,
                                                   const float* __restrict__ as1,
                                                   const float* __restrict__ ad1,
                                                   const uint32* __restrict__ h1u,
                                                   const float* __restrict__ b1,
                                                   const float4* __restrict__ w2a4,
                                                   uint32* __restrict__ out1u,
                                                   float* __restrict__ as2,
                                                   float* __restrict__ ad2) {
    __shared__ float w_sh[4][64 * 5];
    __shared__ int src_sh[4][64];
    int tid = threadIdx.x, lane = tid & 63, wv = tid >> 6;
    int i = blockIdx.x * 2 + (wv >> 1);
    int half = wv & 1, h0 = half * 5;
    int rs = row_ptr[i], deg = row_ptr[i + 1] - rs;

    float adst[5];
#pragma unroll
    for (int k = 0; k < 5; ++k) adst[k] = ad1[i * H1 + h0 + k];

    // online softmax over this wave's 5 heads
    float m[5], ss[5];
#pragma unroll
    for (int k = 0; k < 5; ++k) { m[k] = -1e30f; ss[k] = 0.f; }
    for (int eix = lane; eix < deg; eix += 64) {
        int sn = src_arr[rs + eix];
        const float* ap = as1 + sn * H1 + h0;
#pragma unroll
        for (int k = 0; k < 5; ++k) {
            float v = lrelu(ap[k] + adst[k]);
            float nm = fmaxf(m[k], v);
            ss[k] = ss[k] * __expf(m[k] - nm) + __expf(v - nm);
            m[k] = nm;
        }
    }
#pragma unroll
    for (int off = 1; off < 64; off <<= 1) {
#pragma unroll
        for (int k = 0; k < 5; ++k) {
            float mo = __shfl_xor(m[k], off, 64);
            float so = __shfl_xor(ss[k], off, 64);
            float nm = fmaxf(m[k], mo);
            ss[k] = ss[k] * __expf(m[k] - nm) + so * __expf(mo - nm);
            m[k] = nm;
        }
    }
    float rden[5];
#pragma unroll
    for (int k = 0; k < 5; ++k) rden[k] = 1.f / (ss[k] + 1e-16f);

    // gather
    int hq = lane / 13;            // head index (0..4) for all 3 uints of this lane
    int ubase = 3 * lane;          // uints 0..191
    bool tail = lane < 3;          // uints 192..194, head 4
    size_t hbase = (size_t)half * 195;
    f32x2 acc0 = {0.f, 0.f}, acc1 = {0.f, 0.f}, acc2 = {0.f, 0.f}, acct = {0.f, 0.f};

    for (int base = 0; base < deg; base += 64) {
        int cnt = min(deg - base, 64);
        if (lane < cnt) {
            int sn = src_arr[rs + base + lane];
            src_sh[wv][lane] = sn;
            const float* ap = as1 + sn * H1 + h0;
#pragma unroll
            for (int k = 0; k < 5; ++k)
                w_sh[wv][lane * 5 + k] = __expf(lrelu(ap[k] + adst[k]) - m[k]) * rden[k];
        }
        __builtin_amdgcn_wave_barrier();
        int eix = 0;
        for (; eix + 1 < cnt; eix += 2) {
            int s0 = src_sh[wv][eix], s1 = src_sh[wv][eix + 1];
            const uint32* r0 = h1u + (size_t)s0 * 390 + hbase;
            const uint32* r1 = h1u + (size_t)s1 * 390 + hbase;
            u32x3 A = *(const u32x3a*)(r0 + ubase);
            u32x3 B = *(const u32x3a*)(r1 + ubase);
            float wa = w_sh[wv][eix * 5 + hq];
            float wb = w_sh[wv][(eix + 1) * 5 + hq];
            acc0 = wa * bf2(A.x) + acc0;  acc0 = wb * bf2(B.x) + acc0;
            acc1 = wa * bf2(A.y) + acc1;  acc1 = wb * bf2(B.y) + acc1;
            acc2 = wa * bf2(A.z) + acc2;  acc2 = wb * bf2(B.z) + acc2;
            if (tail) {
                uint32 ta = r0[192 + lane], tb = r1[192 + lane];
                float w4a = w_sh[wv][eix * 5 + 4];
                float w4b = w_sh[wv][(eix + 1) * 5 + 4];
                acct = w4a * bf2(ta) + acct;  acct = w4b * bf2(tb) + acct;
            }
        }
        if (eix < cnt) {
            int s0 = src_sh[wv][eix];
            const uint32* r0 = h1u + (size_t)s0 * 390 + hbase;
            u32x3 A = *(const u32x3a*)(r0 + ubase);
            float wa = w_sh[wv][eix * 5 + hq];
            acc0 = wa * bf2(A.x) + acc0;
            acc1 = wa * bf2(A.y) + acc1;
            acc2 = wa * bf2(A.z) + acc2;
            if (tail) {
                uint32 ta = r0[192 + lane];
                float w4a = w_sh[wv][eix * 5 + 4];
                acct = w4a * bf2(ta) + acct;
            }
        }
        __builtin_amdgcn_wave_barrier();
    }

    // epilogue: bias + relu + pack + store; fused layer-2 alpha dots
    uint32* orow = out1u + (size_t)i * 390;
    const float2* bp = (const float2*)b1;
    float s2 = 0.f, d2 = 0.f;
    f32x2 accs[3] = {acc0, acc1, acc2};
#pragma unroll
    for (int q = 0; q < 3; ++q) {
        int ug = (int)hbase + ubase + q;
        float2 bv = bp[ug];
        float v0 = fmaxf(accs[q].x + bv.x, 0.f);
        float v1 = fmaxf(accs[q].y + bv.y, 0.f);
        orow[ug] = packbf(v0, v1);
        float4 w = w2a4[ug];
        s2 = fmaf(v0, w.x, fmaf(v1, w.z, s2));
        d2 = fmaf(v0, w.y, fmaf(v1, w.w, d2));
    }
    if (tail) {
        int ug = (int)hbase + 192 + lane;
        float2 bv = bp[ug];
        float v0 = fmaxf(acct.x + bv.x, 0.f);
        float v1 = fmaxf(acct.y + bv.y, 0.f);
        orow[ug] = packbf(v0, v1);
        float4 w = w2a4[ug];
        s2 = fmaf(v0, w.x, fmaf(v1, w.z, s2));
        d2 = fmaf(v0, w.y, fmaf(v1, w.w, d2));
    }
#pragma unroll
    for (int off = 32; off; off >>= 1) {
        s2 += __shfl_xor(s2, off, 64);
        d2 += __shfl_xor(d2, off, 64);
    }
    if (lane == 0) {
        atomicAdd(&as2[i], s2);
        atomicAdd(&ad2[i], d2);
    }
}

// ---------------- layer-2 aggregation + pool: one wave per node ----------------
__global__ __launch_bounds__(256) void agg2_kernel(const int* __restrict__ row_ptr,
                                                   const int* __restrict__ src_arr,
                                                   const float* __restrict__ as2,
                                                   const float* __restrict__ ad2,
                                                   const uint32* __restrict__ h2u,
                                                   const float* __restrict__ b2,
                                                   const int* __restrict__ batch,
                                                   float* __restrict__ pooled) {
    __shared__ float w_sh[4][64];
    __shared__ int src_sh[4][64];
    int tid = threadIdx.x, lane = tid & 63, wv = tid >> 6;
    int i = blockIdx.x * 4 + wv;
    int rs = row_ptr[i], deg = row_ptr[i + 1] - rs;
    float adst = ad2[i];

    float m = -1e30f, ss = 0.f;
    for (int eix = lane; eix < deg; eix += 64) {
        int sn = src_arr[rs + eix];
        float v = lrelu(as2[sn] + adst);
        float nm = fmaxf(m, v);
        ss = ss * __expf(m - nm) + __expf(v - nm);
        m = nm;
    }
#pragma unroll
    for (int off = 1; off < 64; off <<= 1) {
        float mo = __shfl_xor(m, off, 64);
        float so = __shfl_xor(ss, off, 64);
        float nm = fmaxf(m, mo);
        ss = ss * __expf(m - nm) + so * __expf(mo - nm);
        m = nm;
    }
    float rden = 1.f / (ss + 1e-16f);

    f32x2 acc = {0.f, 0.f};
    for (int base = 0; base < deg; base += 64) {
        int cnt = min(deg - base, 64);
        if (lane < cnt) {
            int sn = src_arr[rs + base + lane];
            src_sh[wv][lane] = sn;
            w_sh[wv][lane] = __expf(lrelu(as2[sn] + adst) - m) * rden;
        }
        __builtin_amdgcn_wave_barrier();
        int eix = 0;
        for (; eix + 1 < cnt; eix += 2) {
            int s0 = src_sh[wv][eix], s1 = src_sh[wv][eix + 1];
            float w0 = w_sh[wv][eix], w1 = w_sh[wv][eix + 1];
            uint32 u0 = h2u[(size_t)s0 * 64 + lane];
            uint32 u1 = h2u[(size_t)s1 * 64 + lane];
            acc = w0 * bf2(u0) + acc;
            acc = w1 * bf2(u1) + acc;
        }
        if (eix < cnt) {
            int s0 = src_sh[wv][eix];
            float w0 = w_sh[wv][eix];
            uint32 u0 = h2u[(size_t)s0 * 64 + lane];
            acc = w0 * bf2(u0) + acc;
        }
        __builtin_amdgcn_wave_barrier();
    }
    float2 bv = ((const float2*)b2)[lane];
    float v0 = fmaxf(acc.x + bv.x, 0.f);
    float v1 = fmaxf(acc.y + bv.y, 0.f);
    int g = batch[i];
    atomicMax((int*)&pooled[g * OUT2 + 2 * lane], __float_as_int(v0));
    atomicMax((int*)&pooled[g * OUT2 + 2 * lane + 1], __float_as_int(v1));
}

// ---------------- final FC + relu ----------------
__global__ __launch_bounds__(128) void fc_kernel(const float* __restrict__ pooled,
                                                 const float* __restrict__ fcW,
                                                 const float* __restrict__ fcb,
                                                 float* __restrict__ out) {
    int g = blockIdx.x, tid = threadIdx.x;
    __shared__ float p[128];
    p[tid] = pooled[g * OUT2 + tid];
    __syncthreads();
    float acc = fcb[tid];
    for (int k = 0; k < 128; ++k) acc = fmaf(p[k], fcW[k * OUT2 + tid], acc);
    out[g * OUT2 + tid] = fmaxf(acc, 0.f);
}

extern "C" void kernel_launch(void* const* d_in, const int* in_sizes, int n_in,
                              void* d_out, int out_size, void* d_ws, size_t ws_size,
                              hipStream_t stream) {
    const float* x      = (const float*)d_in[0];
    const int*   ei     = (const int*)d_in[1];
    const int*   batch  = (const int*)d_in[2];
    const float* W1     = (const float*)d_in[4];
    const float* a_src1 = (const float*)d_in[5];
    const float* a_dst1 = (const float*)d_in[6];
    const float* b1     = (const float*)d_in[7];
    const float* W2     = (const float*)d_in[8];
    const float* a_src2 = (const float*)d_in[9];
    const float* a_dst2 = (const float*)d_in[10];
    const float* b2     = (const float*)d_in[11];
    const float* fcW    = (const float*)d_in[12];
    const float* fcb    = (const float*)d_in[13];
    float* out = (float*)d_out;

    size_t off = 0;
    char* base = (char*)d_ws;
    auto alloc = [&](size_t bytes) -> void* {
        void* p = base + off;
        off += (bytes + 255) & ~(size_t)255;
        return p;
    };
    u16* h1     = (u16*)alloc((size_t)N_NODES * D1 * 2);
    u16* out1   = (u16*)alloc((size_t)N_NODES * D1 * 2);
    u16* h2     = (u16*)alloc((size_t)N_NODES * OUT2 * 2);  // also hosts xb early
    u16* xb     = h2;   // xb dead before gemm2 writes h2
    float* as1  = (float*)alloc((size_t)N_NODES * H1 * 4);
    float* ad1  = (float*)alloc((size_t)N_NODES * H1 * 4);
    float* as2  = (float*)alloc((size_t)N_NODES * 4);
    float* ad2  = (float*)alloc((size_t)N_NODES * 4);
    u16* W1T    = (u16*)alloc((size_t)NW1 * 2);
    u16* W2T    = (u16*)alloc((size_t)NW2 * 2);
    u16* VAT    = (u16*)alloc((size_t)32 * F_INN * 2);
    float4* w2a4 = (float4*)alloc((size_t)390 * 16);
    float* pooled = (float*)alloc((size_t)NGRAPH * OUT2 * 4);
    int* deg     = (int*)alloc((size_t)N_NODES * 4);
    int* row_ptr = (int*)alloc((size_t)(N_NODES + 1) * 4);
    int* cursor  = (int*)alloc((size_t)N_NODES * 4);
    int* src_arr = (int*)alloc((size_t)ETOT * 4);
    int* bsum    = (int*)alloc(196 * 4);
    int* boff    = (int*)alloc(196 * 4);

    hipMemsetAsync(deg, 0, (size_t)N_NODES * 4, stream);
    hipMemsetAsync(pooled, 0, (size_t)NGRAPH * OUT2 * 4, stream);
    hipMemsetAsync(as2, 0, (size_t)N_NODES * 4, stream);
    hipMemsetAsync(ad2, 0, (size_t)N_NODES * 4, stream);

    prep_kernel<<<2048, 256, 0, stream>>>(x, W1, W2, xb, W1T, W2T);
    prep2_kernel<<<8, 256, 0, stream>>>(W1, a_src1, a_dst1, W2, a_src2, a_dst2, VAT, w2a4);
    alphas1x_kernel<<<391, 256, 0, stream>>>(xb, VAT, as1, ad1);
    gemm1_mfma<<<dim3(13, 391), 256, 0, stream>>>(xb, W1T, h1);
    hist_kernel<<<(ETOT + 255) / 256, 256, 0, stream>>>(ei, deg);
    scan1_kernel<<<196, 256, 0, stream>>>(deg, row_ptr, bsum);
    scan2_kernel<<<1, 256, 0, stream>>>(bsum, boff);
    scan3_kernel<<<196, 256, 0, stream>>>(row_ptr, boff, cursor);
    scatter_kernel<<<(ETOT + 255) / 256, 256, 0, stream>>>(ei, cursor, src_arr);
    agg1_kernel<<<N_NODES / 2, 256, 0, stream>>>(row_ptr, src_arr, as1, ad1,
                                                 (const uint32*)h1, b1, w2a4,
                                                 (uint32*)out1, as2, ad2);
    gemm2_mfma<<<782, 256, 0, stream>>>(out1, W2T, h2);
    agg2_kernel<<<N_NODES / 4, 256, 0, stream>>>(row_ptr, src_arr, as2, ad2,
                                                 (const uint32*)h2, b2, batch, pooled);
    fc_kernel<<<NGRAPH, 128, 0, stream>>>(pooled, fcW, fcb, out);
}

// Round 5
// 643.713 us; speedup vs baseline: 1.9161x; 1.0243x over previous
//
#include <hip/hip_runtime.h>
#include <hip/hip_bf16.h>
#include <stdint.h>

typedef unsigned int uint32;
typedef unsigned short u16;
typedef __attribute__((ext_vector_type(8))) short bf16x8;
typedef __attribute__((ext_vector_type(4))) float f32x4;
typedef __attribute__((ext_vector_type(2))) float f32x2;
typedef uint32 u32x3 __attribute__((ext_vector_type(3)));
typedef u32x3 u32x3a __attribute__((aligned(4)));

#define N_NODES 50000
#define N_EDGES 800000
#define ETOT    (N_EDGES + N_NODES)
#define F_INN   78
#define H1      10
#define D1      780
#define OUT2    128
#define NGRAPH  512
#define NEG_SLOPE 0.2f

#define NX  (N_NODES * F_INN)
#define NW1 (D1 * F_INN)
#define NW2 (OUT2 * D1)

__device__ __forceinline__ float lrelu(float v) { return v > 0.f ? v : NEG_SLOPE * v; }
__device__ __forceinline__ float bl(uint32 u) { return __uint_as_float(u << 16); }
__device__ __forceinline__ float bf1(u16 u) { return __uint_as_float(((uint32)u) << 16); }
__device__ __forceinline__ u16 f2bfbits(float f) {
    return __bfloat16_as_ushort(__float2bfloat16(f));
}
__device__ __forceinline__ uint32 packbf(float lo, float hi) {
    return (uint32)f2bfbits(lo) | ((uint32)f2bfbits(hi) << 16);
}
__device__ __forceinline__ f32x2 bf2(uint32 u) {
    __hip_bfloat162 b = *reinterpret_cast<__hip_bfloat162*>(&u);
    float2 t = __bfloat1622float2(b);
    return (f32x2){t.x, t.y};
}
__device__ __forceinline__ int esrc(const int* ei, int e) { return e < N_EDGES ? ei[e] : e - N_EDGES; }
__device__ __forceinline__ int edst(const int* ei, int e) { return e < N_EDGES ? ei[N_EDGES + e] : e - N_EDGES; }

// ---------------- prep: x->bf16, W1->W1X[0:780] bf16 [n][k], W2->W2T bf16 [n][k] ----------------
__global__ __launch_bounds__(256) void prep_kernel(const float* __restrict__ x,
                                                   const float* __restrict__ W1,
                                                   const float* __restrict__ W2,
                                                   u16* __restrict__ xb,
                                                   u16* __restrict__ W1X,
                                                   u16* __restrict__ W2T) {
    const int total = NX + NW1 + NW2;
    for (int id = blockIdx.x * 256 + threadIdx.x; id < total; id += gridDim.x * 256) {
        if (id < NX) {
            xb[id] = f2bfbits(x[id]);
        } else if (id < NX + NW1) {
            int t = id - NX;
            int n = t / F_INN, k = t - n * F_INN;
            W1X[t] = f2bfbits(W1[k * D1 + n]);
        } else {
            int t = id - NX - NW1;
            int n = t / D1, k = t - n * D1;
            W2T[t] = f2bfbits(W2[k * OUT2 + n]);
        }
    }
}

// ---------------- prep2: folded attention vectors appended to W1X (cols 780..811) + w2a4 ----------------
__global__ __launch_bounds__(256) void prep2_kernel(const float* __restrict__ W1,
                                                    const float* __restrict__ a_src1,
                                                    const float* __restrict__ a_dst1,
                                                    const float* __restrict__ W2,
                                                    const float* __restrict__ a_src2,
                                                    const float* __restrict__ a_dst2,
                                                    u16* __restrict__ VAT,   // = W1X + NW1
                                                    float4* __restrict__ w2a4) {
    int gid = blockIdx.x * 256 + threadIdx.x;
    int gs = gridDim.x * 256;
    for (int idx = gid; idx < 32 * F_INN; idx += gs) {
        int j = idx / F_INN, k = idx - j * F_INN;
        float s = 0.f;
        if (j < 20) {
            int h = (j < 10) ? j : j - 10;
            const float* vec = ((j < 10) ? a_src1 : a_dst1) + h * F_INN;
            const float* wrow = W1 + k * D1 + h * F_INN;
            for (int f = 0; f < F_INN; ++f) s = fmaf(wrow[f], vec[f], s);
        }
        VAT[j * F_INN + k] = f2bfbits(s);
    }
    for (int u = gid; u < 390; u += gs) {
        const float* r0 = W2 + (size_t)(2 * u) * OUT2;
        const float* r1 = r0 + OUT2;
        float s0 = 0.f, d0 = 0.f, s1 = 0.f, d1 = 0.f;
        for (int j = 0; j < OUT2; ++j) {
            float a2s = a_src2[j], a2d = a_dst2[j];
            s0 = fmaf(r0[j], a2s, s0);
            d0 = fmaf(r0[j], a2d, d0);
            s1 = fmaf(r1[j], a2s, s1);
            d1 = fmaf(r1[j], a2d, d1);
        }
        w2a4[u] = make_float4(s0, d0, s1, d1);
    }
}

// ---------------- GEMM1 (MFMA): xb[50000x78] @ W1X[78x812] -> h1 bf16 + asd1 f32 ----------------
#define G1S 52
__global__ __launch_bounds__(256) void gemm1_mfma(const u16* __restrict__ xb,
                                                  const u16* __restrict__ W1X,
                                                  u16* __restrict__ h1,
                                                  float* __restrict__ asd1) {
    __shared__ uint32 As[128 * G1S];
    __shared__ uint32 Bs[64 * G1S];
    int tid = threadIdx.x;
    int col0 = blockIdx.x * 64, row0 = blockIdx.y * 128;
    const uint32* xbu = (const uint32*)xb;
    const uint32* w1u = (const uint32*)W1X;

    for (int idx = tid; idx < 128 * 39; idx += 256) {
        int r = idx / 39, c = idx - r * 39;
        int gr = row0 + r;
        As[r * G1S + c] = (gr < N_NODES) ? xbu[gr * 39 + c] : 0u;
    }
    for (int idx = tid; idx < 128 * 9; idx += 256) {
        int r = idx / 9, c = 39 + (idx - r * 9);
        As[r * G1S + c] = 0u;
    }
    for (int idx = tid; idx < 64 * 39; idx += 256) {
        int n = idx / 39, c = idx - n * 39;
        int gn = col0 + n;
        Bs[n * G1S + c] = (gn < 812) ? w1u[gn * 39 + c] : 0u;
    }
    for (int idx = tid; idx < 64 * 9; idx += 256) {
        int n = idx / 9, c = 39 + (idx - n * 9);
        Bs[n * G1S + c] = 0u;
    }
    __syncthreads();

    int lane = tid & 63, wv = tid >> 6;
    int wm = wv >> 1, wn = wv & 1;
    int l15 = lane & 15, quad = lane >> 4;
    const u16* Asu = (const u16*)As;
    const u16* Bsu = (const u16*)Bs;

    f32x4 acc[4][2];
#pragma unroll
    for (int mi = 0; mi < 4; ++mi)
#pragma unroll
        for (int nj = 0; nj < 2; ++nj) acc[mi][nj] = (f32x4){0.f, 0.f, 0.f, 0.f};

    int abase[4], bbase[2];
#pragma unroll
    for (int mi = 0; mi < 4; ++mi) abase[mi] = (wm * 64 + mi * 16 + l15) * 104 + quad * 8;
#pragma unroll
    for (int nj = 0; nj < 2; ++nj) bbase[nj] = (wn * 32 + nj * 16 + l15) * 104 + quad * 8;

#pragma unroll
    for (int ks = 0; ks < 96; ks += 32) {
        bf16x8 a[4], b[2];
#pragma unroll
        for (int mi = 0; mi < 4; ++mi) a[mi] = *(const bf16x8*)(Asu + abase[mi] + ks);
#pragma unroll
        for (int nj = 0; nj < 2; ++nj) b[nj] = *(const bf16x8*)(Bsu + bbase[nj] + ks);
#pragma unroll
        for (int mi = 0; mi < 4; ++mi)
#pragma unroll
            for (int nj = 0; nj < 2; ++nj)
                acc[mi][nj] = __builtin_amdgcn_mfma_f32_16x16x32_bf16(a[mi], b[nj], acc[mi][nj], 0, 0, 0);
    }

#pragma unroll
    for (int mi = 0; mi < 4; ++mi)
#pragma unroll
        for (int nj = 0; nj < 2; ++nj)
#pragma unroll
            for (int reg = 0; reg < 4; ++reg) {
                int row = row0 + wm * 64 + mi * 16 + quad * 4 + reg;
                int col = col0 + wn * 32 + nj * 16 + l15;
                if (row < N_NODES) {
                    if (col < D1) {
                        h1[(size_t)row * D1 + col] = f2bfbits(acc[mi][nj][reg]);
                    } else {
                        int c = col - D1;
                        if (c < 20) asd1[(size_t)row * 20 + c] = acc[mi][nj][reg];
                    }
                }
            }
}

// ---------------- GEMM2 (MFMA): out1[50000x780] bf16 @ W2[780x128] -> h2 bf16 ----------------
#define G2S 36
__global__ __launch_bounds__(256) void gemm2_mfma(const u16* __restrict__ out1,
                                                  const u16* __restrict__ W2T,
                                                  u16* __restrict__ h2) {
    __shared__ uint32 As[64 * G2S];
    __shared__ uint32 Bs[128 * G2S];
    int tid = threadIdx.x;
    int row0 = blockIdx.x * 64;
    const uint32* o1u = (const uint32*)out1;
    const uint32* w2u = (const uint32*)W2T;

    int lane = tid & 63, wv = tid >> 6;
    int wm = wv >> 1, wn = wv & 1;
    int l15 = lane & 15, quad = lane >> 4;
    const u16* Asu = (const u16*)As;
    const u16* Bsu = (const u16*)Bs;

    f32x4 acc[2][4];
#pragma unroll
    for (int mi = 0; mi < 2; ++mi)
#pragma unroll
        for (int nj = 0; nj < 4; ++nj) acc[mi][nj] = (f32x4){0.f, 0.f, 0.f, 0.f};

    int abase[2], bbase[4];
#pragma unroll
    for (int mi = 0; mi < 2; ++mi) abase[mi] = (wm * 32 + mi * 16 + l15) * 72 + quad * 8;
#pragma unroll
    for (int nj = 0; nj < 4; ++nj) bbase[nj] = (wn * 64 + nj * 16 + l15) * 72 + quad * 8;

    for (int s = 0; s < 13; ++s) {
        int k0h = s * 32;
        for (int idx = tid; idx < 64 * 32; idx += 256) {
            int r = idx >> 5, c = idx & 31;
            int gr = row0 + r;
            As[r * G2S + c] = (gr < N_NODES && (k0h + c) < 390) ? o1u[(size_t)gr * 390 + k0h + c] : 0u;
        }
        for (int idx = tid; idx < 128 * 32; idx += 256) {
            int n = idx >> 5, c = idx & 31;
            Bs[n * G2S + c] = ((k0h + c) < 390) ? w2u[(size_t)n * 390 + k0h + c] : 0u;
        }
        __syncthreads();
#pragma unroll
        for (int ks = 0; ks < 64; ks += 32) {
            bf16x8 a[2], b[4];
#pragma unroll
            for (int mi = 0; mi < 2; ++mi) a[mi] = *(const bf16x8*)(Asu + abase[mi] + ks);
#pragma unroll
            for (int nj = 0; nj < 4; ++nj) b[nj] = *(const bf16x8*)(Bsu + bbase[nj] + ks);
#pragma unroll
            for (int mi = 0; mi < 2; ++mi)
#pragma unroll
                for (int nj = 0; nj < 4; ++nj)
                    acc[mi][nj] = __builtin_amdgcn_mfma_f32_16x16x32_bf16(a[mi], b[nj], acc[mi][nj], 0, 0, 0);
        }
        __syncthreads();
    }

#pragma unroll
    for (int mi = 0; mi < 2; ++mi)
#pragma unroll
        for (int nj = 0; nj < 4; ++nj)
#pragma unroll
            for (int reg = 0; reg < 4; ++reg) {
                int row = row0 + wm * 32 + mi * 16 + quad * 4 + reg;
                int col = wn * 64 + nj * 16 + l15;
                if (row < N_NODES)
                    h2[(size_t)row * OUT2 + col] = f2bfbits(acc[mi][nj][reg]);
            }
}

// ---------------- CSR build ----------------
__global__ void hist_kernel(const int* __restrict__ ei, int* __restrict__ deg) {
    int e = blockIdx.x * 256 + threadIdx.x;
    if (e < ETOT) atomicAdd(&deg[edst(ei, e)], 1);
}

__global__ __launch_bounds__(256) void scan1_kernel(const int* __restrict__ deg,
                                                    int* __restrict__ row_ptr,
                                                    int* __restrict__ bsum) {
    __shared__ int buf[256];
    int tid = threadIdx.x;
    int i = blockIdx.x * 256 + tid;
    int v = (i < N_NODES) ? deg[i] : 0;
    buf[tid] = v;
    __syncthreads();
    for (int off = 1; off < 256; off <<= 1) {
        int t = (tid >= off) ? buf[tid - off] : 0;
        __syncthreads();
        buf[tid] += t;
        __syncthreads();
    }
    if (i < N_NODES) row_ptr[i] = buf[tid] - v;
    if (tid == 255) bsum[blockIdx.x] = buf[255];
}

__global__ __launch_bounds__(256) void scan2_kernel(const int* __restrict__ bsum,
                                                    int* __restrict__ boff) {
    __shared__ int buf[256];
    int tid = threadIdx.x;
    int v = (tid < 196) ? bsum[tid] : 0;
    buf[tid] = v;
    __syncthreads();
    for (int off = 1; off < 256; off <<= 1) {
        int t = (tid >= off) ? buf[tid - off] : 0;
        __syncthreads();
        buf[tid] += t;
        __syncthreads();
    }
    if (tid < 196) boff[tid] = buf[tid] - v;
}

__global__ __launch_bounds__(256) void scan3_kernel(int* __restrict__ row_ptr,
                                                    const int* __restrict__ boff,
                                                    int* __restrict__ cursor) {
    int i = blockIdx.x * 256 + threadIdx.x;
    if (i < N_NODES) {
        int r = row_ptr[i] + boff[blockIdx.x];
        row_ptr[i] = r;
        cursor[i] = r;
    }
    if (i == 0) row_ptr[N_NODES] = ETOT;
}

__global__ void scatter_kernel(const int* __restrict__ ei, int* __restrict__ cursor,
                               int* __restrict__ src_arr, int* __restrict__ dst_arr) {
    int e = blockIdx.x * 256 + threadIdx.x;
    if (e < ETOT) {
        int d = edst(ei, e);
        int pos = atomicAdd(&cursor[d], 1);
        src_arr[pos] = esrc(ei, e);
        dst_arr[pos] = d;
    }
}

// ---------------- edge-parallel exp weights, layer 1 (no max-subtraction) ----------------
__global__ __launch_bounds__(256) void expw_kernel(const int* __restrict__ src_arr,
                                                   const int* __restrict__ dst_arr,
                                                   const float* __restrict__ asd1,
                                                   u16* __restrict__ expw) {
    int p = blockIdx.x * 256 + threadIdx.x;
    if (p >= ETOT) return;
    int s = src_arr[p], d = dst_arr[p];
    const float4* sp = (const float4*)(asd1 + (size_t)s * 20);
    float4 s01 = sp[0], s02 = sp[1];
    float2 s03 = ((const float2*)sp)[4];
    const float* dp = asd1 + (size_t)d * 20 + 10;
    float2 d01 = *(const float2*)dp;
    float4 d02 = *(const float4*)(dp + 2);
    float4 d03 = *(const float4*)(dp + 6);
    float sv[10] = {s01.x, s01.y, s01.z, s01.w, s02.x, s02.y, s02.z, s02.w, s03.x, s03.y};
    float dv[10] = {d01.x, d01.y, d02.x, d02.y, d02.z, d02.w, d03.x, d03.y, d03.z, d03.w};
#pragma unroll
    for (int h = 0; h < 10; ++h) {
        float v = lrelu(sv[h] + dv[h]);
        expw[(size_t)h * ETOT + p] = f2bfbits(__expf(v));
    }
}

// ---------------- edge-parallel exp weights, layer 2 ----------------
__global__ __launch_bounds__(256) void expw2_kernel(const int* __restrict__ src_arr,
                                                    const int* __restrict__ dst_arr,
                                                    const float* __restrict__ as2,
                                                    const float* __restrict__ ad2,
                                                    float* __restrict__ w2) {
    int p = blockIdx.x * 256 + threadIdx.x;
    if (p >= ETOT) return;
    w2[p] = __expf(lrelu(as2[src_arr[p]] + ad2[dst_arr[p]]));
}

// ---------------- layer-1 aggregation: 2 waves per node, weights precomputed ----------------
__global__ __launch_bounds__(256) void agg1_kernel(const int* __restrict__ row_ptr,
                                                   const int* __restrict__ src_arr,
                                                   const u16* __restrict__ expw,
                                                   const uint32* __restrict__ h1u,
                                                   const float* __restrict__ b1,
                                                   const float4* __restrict__ w2a4,
                                                   uint32* __restrict__ out1u,
                                                   float* __restrict__ as2,
                                                   float* __restrict__ ad2) {
    __shared__ float w_sh[4][5 * 72];
    __shared__ int src_sh[4][64];
    int tid = threadIdx.x, lane = tid & 63, wv = tid >> 6;
    int i = blockIdx.x * 2 + (wv >> 1);
    int half = wv & 1, h0 = half * 5;
    int rs = row_ptr[i], deg = row_ptr[i + 1] - rs;

    int hq = lane / 13;
    int ubase = 3 * lane;
    bool tail = lane < 3;
    size_t hbase = (size_t)half * 195;
    f32x2 acc0 = {0.f, 0.f}, acc1 = {0.f, 0.f}, acc2 = {0.f, 0.f}, acct = {0.f, 0.f};
    float den[5] = {0.f, 0.f, 0.f, 0.f, 0.f};
    float rden[5];

    if (deg <= 64) {
        // single-chunk fast path: stage + den in one sweep
        if (lane < deg) {
            src_sh[wv][lane] = src_arr[rs + lane];
#pragma unroll
            for (int k = 0; k < 5; ++k) {
                float w = bf1(expw[(size_t)(h0 + k) * ETOT + rs + lane]);
                den[k] = w;
                w_sh[wv][k * 72 + lane] = w;
            }
        }
        __builtin_amdgcn_wave_barrier();
#pragma unroll
        for (int off = 1; off < 64; off <<= 1)
#pragma unroll
            for (int k = 0; k < 5; ++k) den[k] += __shfl_xor(den[k], off, 64);
#pragma unroll
        for (int k = 0; k < 5; ++k) rden[k] = __builtin_amdgcn_rcpf(den[k]);

        int cnt = deg;
        int eix = 0;
        for (; eix + 1 < cnt; eix += 2) {
            int s0 = src_sh[wv][eix], s1 = src_sh[wv][eix + 1];
            const uint32* r0 = h1u + (size_t)s0 * 390 + hbase;
            const uint32* r1 = h1u + (size_t)s1 * 390 + hbase;
            u32x3 A = *(const u32x3a*)(r0 + ubase);
            u32x3 B = *(const u32x3a*)(r1 + ubase);
            float wa = w_sh[wv][hq * 72 + eix];
            float wb = w_sh[wv][hq * 72 + eix + 1];
            acc0 = wa * bf2(A.x) + acc0;  acc0 = wb * bf2(B.x) + acc0;
            acc1 = wa * bf2(A.y) + acc1;  acc1 = wb * bf2(B.y) + acc1;
            acc2 = wa * bf2(A.z) + acc2;  acc2 = wb * bf2(B.z) + acc2;
            if (tail) {
                uint32 ta = r0[192 + lane], tb = r1[192 + lane];
                float w4a = w_sh[wv][4 * 72 + eix];
                float w4b = w_sh[wv][4 * 72 + eix + 1];
                acct = w4a * bf2(ta) + acct;  acct = w4b * bf2(tb) + acct;
            }
        }
        if (eix < cnt) {
            int s0 = src_sh[wv][eix];
            const uint32* r0 = h1u + (size_t)s0 * 390 + hbase;
            u32x3 A = *(const u32x3a*)(r0 + ubase);
            float wa = w_sh[wv][hq * 72 + eix];
            acc0 = wa * bf2(A.x) + acc0;
            acc1 = wa * bf2(A.y) + acc1;
            acc2 = wa * bf2(A.z) + acc2;
            if (tail) {
                uint32 ta = r0[192 + lane];
                float w4a = w_sh[wv][4 * 72 + eix];
                acct = w4a * bf2(ta) + acct;
            }
        }
    } else {
        // general path: pass 1 den, pass 2 chunked gather
        for (int eix = lane; eix < deg; eix += 64)
#pragma unroll
            for (int k = 0; k < 5; ++k)
                den[k] += bf1(expw[(size_t)(h0 + k) * ETOT + rs + eix]);
#pragma unroll
        for (int off = 1; off < 64; off <<= 1)
#pragma unroll
            for (int k = 0; k < 5; ++k) den[k] += __shfl_xor(den[k], off, 64);
#pragma unroll
        for (int k = 0; k < 5; ++k) rden[k] = __builtin_amdgcn_rcpf(den[k]);

        for (int base = 0; base < deg; base += 64) {
            int cnt = min(deg - base, 64);
            if (lane < cnt) {
                src_sh[wv][lane] = src_arr[rs + base + lane];
#pragma unroll
                for (int k = 0; k < 5; ++k)
                    w_sh[wv][k * 72 + lane] = bf1(expw[(size_t)(h0 + k) * ETOT + rs + base + lane]);
            }
            __builtin_amdgcn_wave_barrier();
            int eix = 0;
            for (; eix + 1 < cnt; eix += 2) {
                int s0 = src_sh[wv][eix], s1 = src_sh[wv][eix + 1];
                const uint32* r0 = h1u + (size_t)s0 * 390 + hbase;
                const uint32* r1 = h1u + (size_t)s1 * 390 + hbase;
                u32x3 A = *(const u32x3a*)(r0 + ubase);
                u32x3 B = *(const u32x3a*)(r1 + ubase);
                float wa = w_sh[wv][hq * 72 + eix];
                float wb = w_sh[wv][hq * 72 + eix + 1];
                acc0 = wa * bf2(A.x) + acc0;  acc0 = wb * bf2(B.x) + acc0;
                acc1 = wa * bf2(A.y) + acc1;  acc1 = wb * bf2(B.y) + acc1;
                acc2 = wa * bf2(A.z) + acc2;  acc2 = wb * bf2(B.z) + acc2;
                if (tail) {
                    uint32 ta = r0[192 + lane], tb = r1[192 + lane];
                    float w4a = w_sh[wv][4 * 72 + eix];
                    float w4b = w_sh[wv][4 * 72 + eix + 1];
                    acct = w4a * bf2(ta) + acct;  acct = w4b * bf2(tb) + acct;
                }
            }
            if (eix < cnt) {
                int s0 = src_sh[wv][eix];
                const uint32* r0 = h1u + (size_t)s0 * 390 + hbase;
                u32x3 A = *(const u32x3a*)(r0 + ubase);
                float wa = w_sh[wv][hq * 72 + eix];
                acc0 = wa * bf2(A.x) + acc0;
                acc1 = wa * bf2(A.y) + acc1;
                acc2 = wa * bf2(A.z) + acc2;
                if (tail) {
                    uint32 ta = r0[192 + lane];
                    float w4a = w_sh[wv][4 * 72 + eix];
                    acct = w4a * bf2(ta) + acct;
                }
            }
            __builtin_amdgcn_wave_barrier();
        }
    }

    // epilogue: scale by rden, bias + relu + pack + store; fused layer-2 alpha dots
    float rq = rden[hq];
    acc0 *= rq; acc1 *= rq; acc2 *= rq;
    acct *= rden[4];
    uint32* orow = out1u + (size_t)i * 390;
    const float2* bp = (const float2*)b1;
    float s2 = 0.f, d2 = 0.f;
    f32x2 accs[3] = {acc0, acc1, acc2};
#pragma unroll
    for (int q = 0; q < 3; ++q) {
        int ug = (int)hbase + ubase + q;
        float2 bv = bp[ug];
        float v0 = fmaxf(accs[q].x + bv.x, 0.f);
        float v1 = fmaxf(accs[q].y + bv.y, 0.f);
        orow[ug] = packbf(v0, v1);
        float4 w = w2a4[ug];
        s2 = fmaf(v0, w.x, fmaf(v1, w.z, s2));
        d2 = fmaf(v0, w.y, fmaf(v1, w.w, d2));
    }
    if (tail) {
        int ug = (int)hbase + 192 + lane;
        float2 bv = bp[ug];
        float v0 = fmaxf(acct.x + bv.x, 0.f);
        float v1 = fmaxf(acct.y + bv.y, 0.f);
        orow[ug] = packbf(v0, v1);
        float4 w = w2a4[ug];
        s2 = fmaf(v0, w.x, fmaf(v1, w.z, s2));
        d2 = fmaf(v0, w.y, fmaf(v1, w.w, d2));
    }
#pragma unroll
    for (int off = 32; off; off >>= 1) {
        s2 += __shfl_xor(s2, off, 64);
        d2 += __shfl_xor(d2, off, 64);
    }
    if (lane == 0) {
        atomicAdd(&as2[i], s2);
        atomicAdd(&ad2[i], d2);
    }
}

// ---------------- layer-2 aggregation + pool: one wave per node, weights precomputed ----------------
__global__ __launch_bounds__(256) void agg2_kernel(const int* __restrict__ row_ptr,
                                                   const int* __restrict__ src_arr,
                                                   const float* __restrict__ w2,
                                                   const uint32* __restrict__ h2u,
                                                   const float* __restrict__ b2,
                                                   const int* __restrict__ batch,
                                                   float* __restrict__ pooled) {
    __shared__ float w_sh[4][64];
    __shared__ int src_sh[4][64];
    int tid = threadIdx.x, lane = tid & 63, wv = tid >> 6;
    int i = blockIdx.x * 4 + wv;
    int rs = row_ptr[i], deg = row_ptr[i + 1] - rs;

    f32x2 acc = {0.f, 0.f};
    float den = 0.f;
    if (deg <= 64) {
        if (lane < deg) {
            float w = w2[rs + lane];
            den = w;
            w_sh[wv][lane] = w;
            src_sh[wv][lane] = src_arr[rs + lane];
        }
        __builtin_amdgcn_wave_barrier();
#pragma unroll
        for (int off = 1; off < 64; off <<= 1) den += __shfl_xor(den, off, 64);
        float rden = __builtin_amdgcn_rcpf(den);
        int cnt = deg, eix = 0;
        for (; eix + 1 < cnt; eix += 2) {
            int s0 = src_sh[wv][eix], s1 = src_sh[wv][eix + 1];
            float w0 = w_sh[wv][eix], w1 = w_sh[wv][eix + 1];
            uint32 u0 = h2u[(size_t)s0 * 64 + lane];
            uint32 u1 = h2u[(size_t)s1 * 64 + lane];
            acc = w0 * bf2(u0) + acc;
            acc = w1 * bf2(u1) + acc;
        }
        if (eix < cnt) {
            int s0 = src_sh[wv][eix];
            float w0 = w_sh[wv][eix];
            uint32 u0 = h2u[(size_t)s0 * 64 + lane];
            acc = w0 * bf2(u0) + acc;
        }
        acc *= rden;
    } else {
        for (int eix = lane; eix < deg; eix += 64) den += w2[rs + eix];
#pragma unroll
        for (int off = 1; off < 64; off <<= 1) den += __shfl_xor(den, off, 64);
        float rden = __builtin_amdgcn_rcpf(den);
        for (int base = 0; base < deg; base += 64) {
            int cnt = min(deg - base, 64);
            if (lane < cnt) {
                w_sh[wv][lane] = w2[rs + base + lane];
                src_sh[wv][lane] = src_arr[rs + base + lane];
            }
            __builtin_amdgcn_wave_barrier();
            int eix = 0;
            for (; eix + 1 < cnt; eix += 2) {
                int s0 = src_sh[wv][eix], s1 = src_sh[wv][eix + 1];
                float w0 = w_sh[wv][eix], w1 = w_sh[wv][eix + 1];
                uint32 u0 = h2u[(size_t)s0 * 64 + lane];
                uint32 u1 = h2u[(size_t)s1 * 64 + lane];
                acc = w0 * bf2(u0) + acc;
                acc = w1 * bf2(u1) + acc;
            }
            if (eix < cnt) {
                int s0 = src_sh[wv][eix];
                float w0 = w_sh[wv][eix];
                uint32 u0 = h2u[(size_t)s0 * 64 + lane];
                acc = w0 * bf2(u0) + acc;
            }
            __builtin_amdgcn_wave_barrier();
        }
        acc *= rden;
    }
    float2 bv = ((const float2*)b2)[lane];
    float v0 = fmaxf(acc.x + bv.x, 0.f);
    float v1 = fmaxf(acc.y + bv.y, 0.f);
    int g = batch[i];
    atomicMax((int*)&pooled[g * OUT2 + 2 * lane], __float_as_int(v0));
    atomicMax((int*)&pooled[g * OUT2 + 2 * lane + 1], __float_as_int(v1));
}

// ---------------- final FC + relu ----------------
__global__ __launch_bounds__(128) void fc_kernel(const float* __restrict__ pooled,
                                                 const float* __restrict__ fcW,
                                                 const float* __restrict__ fcb,
                                                 float* __restrict__ out) {
    int g = blockIdx.x, tid = threadIdx.x;
    __shared__ float p[128];
    p[tid] = pooled[g * OUT2 + tid];
    __syncthreads();
    float acc = fcb[tid];
    for (int k = 0; k < 128; ++k) acc = fmaf(p[k], fcW[k * OUT2 + tid], acc);
    out[g * OUT2 + tid] = fmaxf(acc, 0.f);
}

extern "C" void kernel_launch(void* const* d_in, const int* in_sizes, int n_in,
                              void* d_out, int out_size, void* d_ws, size_t ws_size,
                              hipStream_t stream) {
    const float* x      = (const float*)d_in[0];
    const int*   ei     = (const int*)d_in[1];
    const int*   batch  = (const int*)d_in[2];
    const float* W1     = (const float*)d_in[4];
    const float* a_src1 = (const float*)d_in[5];
    const float* a_dst1 = (const float*)d_in[6];
    const float* b1     = (const float*)d_in[7];
    const float* W2     = (const float*)d_in[8];
    const float* a_src2 = (const float*)d_in[9];
    const float* a_dst2 = (const float*)d_in[10];
    const float* b2     = (const float*)d_in[11];
    const float* fcW    = (const float*)d_in[12];
    const float* fcb    = (const float*)d_in[13];
    float* out = (float*)d_out;

    size_t off = 0;
    char* base = (char*)d_ws;
    auto alloc = [&](size_t bytes) -> void* {
        void* p = base + off;
        off += (bytes + 255) & ~(size_t)255;
        return p;
    };
    u16* h1     = (u16*)alloc((size_t)N_NODES * D1 * 2);
    u16* out1   = (u16*)alloc((size_t)N_NODES * D1 * 2);
    u16* h2     = (u16*)alloc((size_t)N_NODES * OUT2 * 2);  // also hosts xb early
    u16* xb     = h2;   // xb dead before gemm2 writes h2
    float* asd1 = (float*)alloc((size_t)N_NODES * 20 * 4);
    float* as2  = (float*)alloc((size_t)N_NODES * 4);
    float* ad2  = (float*)alloc((size_t)N_NODES * 4);
    u16* W1X    = (u16*)alloc((size_t)(NW1 + 32 * F_INN) * 2);  // W1T + VAT appended
    u16* W2T    = (u16*)alloc((size_t)NW2 * 2);
    float4* w2a4 = (float4*)alloc((size_t)390 * 16);
    float* pooled = (float*)alloc((size_t)NGRAPH * OUT2 * 4);
    int* deg     = (int*)alloc((size_t)N_NODES * 4);
    int* row_ptr = (int*)alloc((size_t)(N_NODES + 1) * 4);
    int* cursor  = (int*)alloc((size_t)N_NODES * 4);
    int* src_arr = (int*)alloc((size_t)ETOT * 4);
    int* dst_arr = (int*)alloc((size_t)ETOT * 4);
    u16* expw    = (u16*)alloc((size_t)10 * ETOT * 2);
    float* w2e   = (float*)alloc((size_t)ETOT * 4);
    int* bsum    = (int*)alloc(196 * 4);
    int* boff    = (int*)alloc(196 * 4);

    hipMemsetAsync(deg, 0, (size_t)N_NODES * 4, stream);
    hipMemsetAsync(pooled, 0, (size_t)NGRAPH * OUT2 * 4, stream);
    hipMemsetAsync(as2, 0, (size_t)N_NODES * 4, stream);
    hipMemsetAsync(ad2, 0, (size_t)N_NODES * 4, stream);

    prep_kernel<<<2048, 256, 0, stream>>>(x, W1, W2, xb, W1X, W2T);
    prep2_kernel<<<8, 256, 0, stream>>>(W1, a_src1, a_dst1, W2, a_src2, a_dst2,
                                        W1X + NW1, w2a4);
    gemm1_mfma<<<dim3(13, 391), 256, 0, stream>>>(xb, W1X, h1, asd1);
    hist_kernel<<<(ETOT + 255) / 256, 256, 0, stream>>>(ei, deg);
    scan1_kernel<<<196, 256, 0, stream>>>(deg, row_ptr, bsum);
    scan2_kernel<<<1, 256, 0, stream>>>(bsum, boff);
    scan3_kernel<<<196, 256, 0, stream>>>(row_ptr, boff, cursor);
    scatter_kernel<<<(ETOT + 255) / 256, 256, 0, stream>>>(ei, cursor, src_arr, dst_arr);
    expw_kernel<<<(ETOT + 255) / 256, 256, 0, stream>>>(src_arr, dst_arr, asd1, expw);
    agg1_kernel<<<N_NODES / 2, 256, 0, stream>>>(row_ptr, src_arr, expw,
                                                 (const uint32*)h1, b1, w2a4,
                                                 (uint32*)out1, as2, ad2);
    gemm2_mfma<<<782, 256, 0, stream>>>(out1, W2T, h2);
    expw2_kernel<<<(ETOT + 255) / 256, 256, 0, stream>>>(src_arr, dst_arr, as2, ad2, w2e);
    agg2_kernel<<<N_NODES / 4, 256, 0, stream>>>(row_ptr, src_arr, w2e,
                                                 (const uint32*)h2, b2, batch, pooled);
    fc_kernel<<<NGRAPH, 128, 0, stream>>>(pooled, fcW, fcb, out);
}

// Round 6
// 590.591 us; speedup vs baseline: 2.0884x; 1.0899x over previous
//
#include <hip/hip_runtime.h>
#include <hip/hip_bf16.h>
#include <stdint.h>

typedef unsigned int uint32;
typedef unsigned short u16;
typedef __attribute__((ext_vector_type(8))) short bf16x8;
typedef __attribute__((ext_vector_type(4))) float f32x4;
typedef __attribute__((ext_vector_type(2))) float f32x2;
typedef uint32 u32x4 __attribute__((ext_vector_type(4)));   // align 16 (LDS)
typedef u32x4 u32x4a __attribute__((aligned(4)));           // 4B-aligned global loads

#define N_NODES 50000
#define N_EDGES 800000
#define ETOT    (N_EDGES + N_NODES)
#define F_INN   78
#define H1      10
#define D1      780
#define OUT2    128
#define NGRAPH  512
#define NEG_SLOPE 0.2f

#define NX  (N_NODES * F_INN)
#define NW1 (D1 * F_INN)
#define NW2 (OUT2 * D1)

__device__ __forceinline__ float lrelu(float v) { return v > 0.f ? v : NEG_SLOPE * v; }
__device__ __forceinline__ u16 f2bfbits(float f) {
    return __bfloat16_as_ushort(__float2bfloat16(f));
}
__device__ __forceinline__ uint32 packbf(float lo, float hi) {
    return (uint32)f2bfbits(lo) | ((uint32)f2bfbits(hi) << 16);
}
__device__ __forceinline__ f32x2 bf2(uint32 u) {
    __hip_bfloat162 b = *reinterpret_cast<__hip_bfloat162*>(&u);
    float2 t = __bfloat1622float2(b);
    return (f32x2){t.x, t.y};
}
__device__ __forceinline__ int esrc(const int* ei, int e) { return e < N_EDGES ? ei[e] : e - N_EDGES; }
__device__ __forceinline__ int edst(const int* ei, int e) { return e < N_EDGES ? ei[N_EDGES + e] : e - N_EDGES; }

// ---------------- prep: x->bf16, W1->W1X bf16 [n][k], W2->W2T bf16 [n][k] ----------------
__global__ __launch_bounds__(256) void prep_kernel(const float* __restrict__ x,
                                                   const float* __restrict__ W1,
                                                   const float* __restrict__ W2,
                                                   u16* __restrict__ xb,
                                                   u16* __restrict__ W1X,
                                                   u16* __restrict__ W2T) {
    const int total = NX + NW1 + NW2;
    for (int id = blockIdx.x * 256 + threadIdx.x; id < total; id += gridDim.x * 256) {
        if (id < NX) {
            xb[id] = f2bfbits(x[id]);
        } else if (id < NX + NW1) {
            int t = id - NX;
            int n = t / F_INN, k = t - n * F_INN;
            W1X[t] = f2bfbits(W1[k * D1 + n]);
        } else {
            int t = id - NX - NW1;
            int n = t / D1, k = t - n * D1;
            W2T[t] = f2bfbits(W2[k * OUT2 + n]);
        }
    }
}

// ---------------- prep2: VAT (32x78 bf16) + w2as/w2ad (780 f32 each) ----------------
__global__ __launch_bounds__(256) void prep2_kernel(const float* __restrict__ W1,
                                                    const float* __restrict__ a_src1,
                                                    const float* __restrict__ a_dst1,
                                                    const float* __restrict__ W2,
                                                    const float* __restrict__ a_src2,
                                                    const float* __restrict__ a_dst2,
                                                    u16* __restrict__ VAT,
                                                    float* __restrict__ w2as,
                                                    float* __restrict__ w2ad) {
    int gid = blockIdx.x * 256 + threadIdx.x;
    int gs = gridDim.x * 256;
    for (int idx = gid; idx < 32 * F_INN; idx += gs) {
        int j = idx / F_INN, k = idx - j * F_INN;
        float s = 0.f;
        if (j < 20) {
            int h = (j < 10) ? j : j - 10;
            const float* vec = ((j < 10) ? a_src1 : a_dst1) + h * F_INN;
            const float* wrow = W1 + k * D1 + h * F_INN;
            for (int f = 0; f < F_INN; ++f) s = fmaf(wrow[f], vec[f], s);
        }
        VAT[j * F_INN + k] = f2bfbits(s);
    }
    for (int c = gid; c < D1; c += gs) {
        const float* r0 = W2 + (size_t)c * OUT2;
        float s = 0.f, d = 0.f;
        for (int j = 0; j < OUT2; ++j) {
            s = fmaf(r0[j], a_src2[j], s);
            d = fmaf(r0[j], a_dst2[j], d);
        }
        w2as[c] = s;
        w2ad[c] = d;
    }
}

// ---------------- alphas1x (MFMA): xb[50000x78] @ VAT^T[78x32] -> asd1[50000x20] ----------------
#define G1S 52
__global__ __launch_bounds__(256) void alphas1x_kernel(const u16* __restrict__ xb,
                                                       const u16* __restrict__ VAT,
                                                       float* __restrict__ asd1) {
    __shared__ uint32 As[128 * G1S];
    __shared__ uint32 Bs[32 * G1S];
    int tid = threadIdx.x;
    int row0 = blockIdx.x * 128;
    const uint32* xbu = (const uint32*)xb;
    const uint32* vau = (const uint32*)VAT;

    for (int idx = tid; idx < 128 * 39; idx += 256) {
        int r = idx / 39, c = idx - r * 39;
        int gr = row0 + r;
        As[r * G1S + c] = (gr < N_NODES) ? xbu[gr * 39 + c] : 0u;
    }
    for (int idx = tid; idx < 128 * 13; idx += 256) {
        int r = idx / 13, c = 39 + (idx - r * 13);
        As[r * G1S + c] = 0u;
    }
    for (int idx = tid; idx < 32 * 39; idx += 256) {
        int n = idx / 39, c = idx - n * 39;
        Bs[n * G1S + c] = vau[n * 39 + c];
    }
    for (int idx = tid; idx < 32 * 13; idx += 256) {
        int n = idx / 13, c = 39 + (idx - n * 13);
        Bs[n * G1S + c] = 0u;
    }
    __syncthreads();

    int lane = tid & 63, wv = tid >> 6;
    int wm = wv >> 1, wn = wv & 1;
    int l15 = lane & 15, quad = lane >> 4;
    const u16* Asu = (const u16*)As;
    const u16* Bsu = (const u16*)Bs;

    f32x4 acc[4];
#pragma unroll
    for (int mi = 0; mi < 4; ++mi) acc[mi] = (f32x4){0.f, 0.f, 0.f, 0.f};

    int abase[4];
#pragma unroll
    for (int mi = 0; mi < 4; ++mi) abase[mi] = (wm * 64 + mi * 16 + l15) * 104 + quad * 8;
    int bbase = (wn * 16 + l15) * 104 + quad * 8;

#pragma unroll
    for (int ks = 0; ks < 96; ks += 32) {
        bf16x8 b = *(const bf16x8*)(Bsu + bbase + ks);
#pragma unroll
        for (int mi = 0; mi < 4; ++mi) {
            bf16x8 a = *(const bf16x8*)(Asu + abase[mi] + ks);
            acc[mi] = __builtin_amdgcn_mfma_f32_16x16x32_bf16(a, b, acc[mi], 0, 0, 0);
        }
    }

    int col = wn * 16 + l15;
#pragma unroll
    for (int mi = 0; mi < 4; ++mi)
#pragma unroll
        for (int reg = 0; reg < 4; ++reg) {
            int row = row0 + wm * 64 + mi * 16 + quad * 4 + reg;
            if (row < N_NODES && col < 20) asd1[(size_t)row * 20 + col] = acc[mi][reg];
        }
}

// ---------------- CSR build ----------------
__global__ void hist_kernel(const int* __restrict__ ei, int* __restrict__ deg) {
    int e = blockIdx.x * 256 + threadIdx.x;
    if (e < ETOT) atomicAdd(&deg[edst(ei, e)], 1);
}

__global__ __launch_bounds__(256) void scan1_kernel(const int* __restrict__ deg,
                                                    int* __restrict__ row_ptr,
                                                    int* __restrict__ bsum) {
    __shared__ int buf[256];
    int tid = threadIdx.x;
    int i = blockIdx.x * 256 + tid;
    int v = (i < N_NODES) ? deg[i] : 0;
    buf[tid] = v;
    __syncthreads();
    for (int off = 1; off < 256; off <<= 1) {
        int t = (tid >= off) ? buf[tid - off] : 0;
        __syncthreads();
        buf[tid] += t;
        __syncthreads();
    }
    if (i < N_NODES) row_ptr[i] = buf[tid] - v;
    if (tid == 255) bsum[blockIdx.x] = buf[255];
}

__global__ __launch_bounds__(256) void scan2_kernel(const int* __restrict__ bsum,
                                                    int* __restrict__ boff) {
    __shared__ int buf[256];
    int tid = threadIdx.x;
    int v = (tid < 196) ? bsum[tid] : 0;
    buf[tid] = v;
    __syncthreads();
    for (int off = 1; off < 256; off <<= 1) {
        int t = (tid >= off) ? buf[tid - off] : 0;
        __syncthreads();
        buf[tid] += t;
        __syncthreads();
    }
    if (tid < 196) boff[tid] = buf[tid] - v;
}

__global__ __launch_bounds__(256) void scan3_kernel(int* __restrict__ row_ptr,
                                                    const int* __restrict__ boff,
                                                    int* __restrict__ cursor) {
    int i = blockIdx.x * 256 + threadIdx.x;
    if (i < N_NODES) {
        int r = row_ptr[i] + boff[blockIdx.x];
        row_ptr[i] = r;
        cursor[i] = r;
    }
    if (i == 0) row_ptr[N_NODES] = ETOT;
}

__global__ void scatter_kernel(const int* __restrict__ ei, int* __restrict__ cursor,
                               int* __restrict__ src_arr, int* __restrict__ dst_arr) {
    int e = blockIdx.x * 256 + threadIdx.x;
    if (e < ETOT) {
        int d = edst(ei, e);
        int pos = atomicAdd(&cursor[d], 1);
        src_arr[pos] = esrc(ei, e);
        dst_arr[pos] = d;
    }
}

// ---------------- edge-parallel exp weights, layer 1: AoS [pos][10 bf16] (5 uints) ----------------
__global__ __launch_bounds__(256) void expw_kernel(const int* __restrict__ src_arr,
                                                   const int* __restrict__ dst_arr,
                                                   const float* __restrict__ asd1,
                                                   uint32* __restrict__ expw5) {
    int p = blockIdx.x * 256 + threadIdx.x;
    if (p >= ETOT) return;
    int s = src_arr[p], d = dst_arr[p];
    const float4* sp = (const float4*)(asd1 + (size_t)s * 20);
    float4 s01 = sp[0], s02 = sp[1];
    float2 s03 = ((const float2*)sp)[4];
    const float* dp = asd1 + (size_t)d * 20 + 10;
    float2 d01 = *(const float2*)dp;
    float4 d02 = *(const float4*)(dp + 2);
    float4 d03 = *(const float4*)(dp + 6);
    float sv[10] = {s01.x, s01.y, s01.z, s01.w, s02.x, s02.y, s02.z, s02.w, s03.x, s03.y};
    float dv[10] = {d01.x, d01.y, d02.x, d02.y, d02.z, d02.w, d03.x, d03.y, d03.z, d03.w};
    uint32 o[5];
#pragma unroll
    for (int k = 0; k < 5; ++k) {
        float w0 = __expf(lrelu(sv[2 * k] + dv[2 * k]));
        float w1 = __expf(lrelu(sv[2 * k + 1] + dv[2 * k + 1]));
        o[k] = packbf(w0, w1);
    }
#pragma unroll
    for (int k = 0; k < 5; ++k) expw5[(size_t)p * 5 + k] = o[k];
}

// ---------------- edge-parallel exp weights, layer 2 ----------------
__global__ __launch_bounds__(256) void expw2_kernel(const int* __restrict__ src_arr,
                                                    const int* __restrict__ dst_arr,
                                                    const float* __restrict__ as2,
                                                    const float* __restrict__ ad2,
                                                    float* __restrict__ w2) {
    int p = blockIdx.x * 256 + threadIdx.x;
    if (p >= ETOT) return;
    w2[p] = __expf(lrelu(as2[src_arr[p]] + ad2[dst_arr[p]]));
}

// ---------------- agg1x: Agg[n,h,f] = (1/den_h) sum_e w_eh * xb[src_e, f], one wave/node ----------------
// lane owns uints u = 6*lane+q (q<6) of the 390-uint (head-major) row; tail u=384+lane (lane<6).
__global__ __launch_bounds__(256) void agg1x_kernel(const int* __restrict__ row_ptr,
                                                    const int* __restrict__ src_arr,
                                                    const uint32* __restrict__ expw5,
                                                    const uint32* __restrict__ xbu,
                                                    uint32* __restrict__ aggb) {
    __shared__ uint32 rows_sh[4][32 * 40];
    __shared__ float wts_sh[4][32 * 12 + 16];
    int tid = threadIdx.x, lane = tid & 63, wv = tid >> 6;
    int i = blockIdx.x * 4 + wv;
    int rs = row_ptr[i], deg = row_ptr[i + 1] - rs;
    uint32* rows = rows_sh[wv];
    float* wts = wts_sh[wv];
    float* dsh = wts + 32 * 12;

    // per-lane constants
    int hA = (6 * lane) / 39;
    int hB = (6 * lane + 5) / 39;
    int j[6];
    bool sel[6];
#pragma unroll
    for (int q = 0; q < 6; ++q) {
        int u = 6 * lane + q;
        int h = u / 39;
        j[q] = u - 39 * h;
        sel[q] = (h != hA);
    }
    bool tl = lane < 6;
    int jT = 33 + lane;

    f32x2 acc[6];
#pragma unroll
    for (int q = 0; q < 6; ++q) acc[q] = (f32x2){0.f, 0.f};
    f32x2 accT = {0.f, 0.f};
    float den[10];
#pragma unroll
    for (int h = 0; h < 10; ++h) den[h] = 0.f;

    for (int base = 0; base < deg; base += 32) {
        int cnt = min(deg - base, 32);
        int e = lane >> 1, half = lane & 1;
        if (e < cnt) {
            int sn = src_arr[rs + base + e];
            const uint32* rp = xbu + (size_t)sn * 39 + half * 20;
            uint32* lp = rows + e * 40 + half * 20;
            if (half == 0) {
#pragma unroll
                for (int t = 0; t < 5; ++t)
                    *(u32x4*)(lp + 4 * t) = *(const u32x4a*)(rp + 4 * t);
                // weights for this edge
                const uint32* wp = expw5 + (size_t)(rs + base + e) * 5;
#pragma unroll
                for (int k = 0; k < 5; ++k) {
                    f32x2 w2v = bf2(wp[k]);
                    den[2 * k] += w2v.x;
                    den[2 * k + 1] += w2v.y;
                    *(f32x2*)(wts + e * 12 + 2 * k) = w2v;
                }
            } else {
#pragma unroll
                for (int t = 0; t < 4; ++t)
                    *(u32x4*)(lp + 4 * t) = *(const u32x4a*)(rp + 4 * t);
                lp[16] = rp[16];
                lp[17] = rp[17];
                lp[18] = rp[18];
            }
        }
        __builtin_amdgcn_wave_barrier();
        for (int e2 = 0; e2 < cnt; ++e2) {
            const uint32* rb = rows + e2 * 40;
            const float* wb = wts + e2 * 12;
            float wA = wb[hA], wBv = wb[hB];
#pragma unroll
            for (int q = 0; q < 6; ++q) {
                uint32 v = rb[j[q]];
                float w = sel[q] ? wBv : wA;
                acc[q] = w * bf2(v) + acc[q];
            }
            if (tl) {
                uint32 v = rb[jT];
                accT = wb[9] * bf2(v) + accT;
            }
        }
        __builtin_amdgcn_wave_barrier();
    }

    // den reduce across lanes
#pragma unroll
    for (int off = 1; off < 64; off <<= 1)
#pragma unroll
        for (int h = 0; h < 10; ++h) den[h] += __shfl_xor(den[h], off, 64);
    if (lane < 10) dsh[lane] = den[lane];
    __builtin_amdgcn_wave_barrier();
    float rA = __builtin_amdgcn_rcpf(dsh[hA]);
    float rB = __builtin_amdgcn_rcpf(dsh[hB]);
    float r9 = __builtin_amdgcn_rcpf(dsh[9]);

    uint32* orow = aggb + (size_t)i * 390;
#pragma unroll
    for (int q = 0; q < 6; ++q) {
        f32x2 a = acc[q] * (sel[q] ? rB : rA);
        orow[6 * lane + q] = packbf(a.x, a.y);
    }
    if (tl) {
        f32x2 a = accT * r9;
        orow[384 + lane] = packbf(a.x, a.y);
    }
}

// ---------------- gemm1b: out1[64 rows x 780] = per-head Agg @ W1_h + bias, relu; emits as2/ad2 ----------------
__global__ __launch_bounds__(256) void gemm1b_kernel(const uint32* __restrict__ aggb,
                                                     const uint32* __restrict__ w1u,
                                                     const float* __restrict__ b1,
                                                     const float* __restrict__ w2as,
                                                     const float* __restrict__ w2ad,
                                                     u16* __restrict__ out1,
                                                     float* __restrict__ as2,
                                                     float* __restrict__ ad2) {
    __shared__ uint32 As[64 * 48];
    __shared__ uint32 Bs[80 * 48];
    int tid = threadIdx.x;
    int row0 = blockIdx.x * 64;
    int lane = tid & 63, wv = tid >> 6;
    int l15 = lane & 15, quad = lane >> 4;
    const u16* Asu = (const u16*)As;
    const u16* Bsu = (const u16*)Bs;

    float s2p[4] = {0.f, 0.f, 0.f, 0.f};
    float d2p[4] = {0.f, 0.f, 0.f, 0.f};

    for (int h = 0; h < 10; ++h) {
        for (int idx = tid; idx < 64 * 48; idx += 256) {
            int r = idx / 48, c = idx - r * 48;
            int gr = row0 + r;
            As[idx] = (c < 39 && gr < N_NODES) ? aggb[(size_t)gr * 390 + h * 39 + c] : 0u;
        }
        for (int idx = tid; idx < 80 * 48; idx += 256) {
            int n = idx / 48, c = idx - n * 48;
            Bs[idx] = (c < 39 && n < 78) ? w1u[(size_t)(h * 78 + n) * 39 + c] : 0u;
        }
        __syncthreads();

        f32x4 acc[5];
#pragma unroll
        for (int nj = 0; nj < 5; ++nj) acc[nj] = (f32x4){0.f, 0.f, 0.f, 0.f};
        int arow = (wv * 16 + l15) * 96 + quad * 8;
#pragma unroll
        for (int ks = 0; ks < 96; ks += 32) {
            bf16x8 a = *(const bf16x8*)(Asu + arow + ks);
#pragma unroll
            for (int nj = 0; nj < 5; ++nj) {
                bf16x8 b = *(const bf16x8*)(Bsu + (nj * 16 + l15) * 96 + quad * 8 + ks);
                acc[nj] = __builtin_amdgcn_mfma_f32_16x16x32_bf16(a, b, acc[nj], 0, 0, 0);
            }
        }
        __syncthreads();

        int row = row0 + wv * 16 + quad * 4;
#pragma unroll
        for (int nj = 0; nj < 5; ++nj) {
            int col = nj * 16 + l15;
            if (col < 78) {
                int gc = h * 78 + col;
                float bia = b1[gc], was = w2as[gc], wad = w2ad[gc];
#pragma unroll
                for (int reg = 0; reg < 4; ++reg) {
                    int r = row + reg;
                    if (r < N_NODES) {
                        float v = fmaxf(acc[nj][reg] + bia, 0.f);
                        out1[(size_t)r * 780 + gc] = f2bfbits(v);
                        s2p[reg] = fmaf(v, was, s2p[reg]);
                        d2p[reg] = fmaf(v, wad, d2p[reg]);
                    }
                }
            }
        }
    }

    // reduce across l15 lanes (cols) -> per-row alpha projections
#pragma unroll
    for (int off = 1; off < 16; off <<= 1)
#pragma unroll
        for (int reg = 0; reg < 4; ++reg) {
            s2p[reg] += __shfl_xor(s2p[reg], off, 64);
            d2p[reg] += __shfl_xor(d2p[reg], off, 64);
        }
    if (l15 == 0) {
        int row = row0 + wv * 16 + quad * 4;
#pragma unroll
        for (int reg = 0; reg < 4; ++reg) {
            int r = row + reg;
            if (r < N_NODES) {
                as2[r] = s2p[reg];
                ad2[r] = d2p[reg];
            }
        }
    }
}

// ---------------- GEMM2 (MFMA): out1[50000x780] bf16 @ W2[780x128] -> h2 bf16 ----------------
#define G2S 36
__global__ __launch_bounds__(256) void gemm2_mfma(const u16* __restrict__ out1,
                                                  const u16* __restrict__ W2T,
                                                  u16* __restrict__ h2) {
    __shared__ uint32 As[64 * G2S];
    __shared__ uint32 Bs[128 * G2S];
    int tid = threadIdx.x;
    int row0 = blockIdx.x * 64;
    const uint32* o1u = (const uint32*)out1;
    const uint32* w2u = (const uint32*)W2T;

    int lane = tid & 63, wv = tid >> 6;
    int wm = wv >> 1, wn = wv & 1;
    int l15 = lane & 15, quad = lane >> 4;
    const u16* Asu = (const u16*)As;
    const u16* Bsu = (const u16*)Bs;

    f32x4 acc[2][4];
#pragma unroll
    for (int mi = 0; mi < 2; ++mi)
#pragma unroll
        for (int nj = 0; nj < 4; ++nj) acc[mi][nj] = (f32x4){0.f, 0.f, 0.f, 0.f};

    int abase[2], bbase[4];
#pragma unroll
    for (int mi = 0; mi < 2; ++mi) abase[mi] = (wm * 32 + mi * 16 + l15) * 72 + quad * 8;
#pragma unroll
    for (int nj = 0; nj < 4; ++nj) bbase[nj] = (wn * 64 + nj * 16 + l15) * 72 + quad * 8;

    for (int s = 0; s < 13; ++s) {
        int k0h = s * 32;
        for (int idx = tid; idx < 64 * 32; idx += 256) {
            int r = idx >> 5, c = idx & 31;
            int gr = row0 + r;
            As[r * G2S + c] = (gr < N_NODES && (k0h + c) < 390) ? o1u[(size_t)gr * 390 + k0h + c] : 0u;
        }
        for (int idx = tid; idx < 128 * 32; idx += 256) {
            int n = idx >> 5, c = idx & 31;
            Bs[n * G2S + c] = ((k0h + c) < 390) ? w2u[(size_t)n * 390 + k0h + c] : 0u;
        }
        __syncthreads();
#pragma unroll
        for (int ks = 0; ks < 64; ks += 32) {
            bf16x8 a[2], b[4];
#pragma unroll
            for (int mi = 0; mi < 2; ++mi) a[mi] = *(const bf16x8*)(Asu + abase[mi] + ks);
#pragma unroll
            for (int nj = 0; nj < 4; ++nj) b[nj] = *(const bf16x8*)(Bsu + bbase[nj] + ks);
#pragma unroll
            for (int mi = 0; mi < 2; ++mi)
#pragma unroll
                for (int nj = 0; nj < 4; ++nj)
                    acc[mi][nj] = __builtin_amdgcn_mfma_f32_16x16x32_bf16(a[mi], b[nj], acc[mi][nj], 0, 0, 0);
        }
        __syncthreads();
    }

#pragma unroll
    for (int mi = 0; mi < 2; ++mi)
#pragma unroll
        for (int nj = 0; nj < 4; ++nj)
#pragma unroll
            for (int reg = 0; reg < 4; ++reg) {
                int row = row0 + wm * 32 + mi * 16 + quad * 4 + reg;
                int col = wn * 64 + nj * 16 + l15;
                if (row < N_NODES)
                    h2[(size_t)row * OUT2 + col] = f2bfbits(acc[mi][nj][reg]);
            }
}

// ---------------- layer-2 aggregation + pool: one wave per node ----------------
__global__ __launch_bounds__(256) void agg2_kernel(const int* __restrict__ row_ptr,
                                                   const int* __restrict__ src_arr,
                                                   const float* __restrict__ w2,
                                                   const uint32* __restrict__ h2u,
                                                   const float* __restrict__ b2,
                                                   const int* __restrict__ batch,
                                                   float* __restrict__ pooled) {
    __shared__ float w_sh[4][64];
    __shared__ int src_sh[4][64];
    int tid = threadIdx.x, lane = tid & 63, wv = tid >> 6;
    int i = blockIdx.x * 4 + wv;
    int rs = row_ptr[i], deg = row_ptr[i + 1] - rs;

    f32x2 acc = {0.f, 0.f};
    float den = 0.f;
    if (deg <= 64) {
        if (lane < deg) {
            float w = w2[rs + lane];
            den = w;
            w_sh[wv][lane] = w;
            src_sh[wv][lane] = src_arr[rs + lane];
        }
        __builtin_amdgcn_wave_barrier();
#pragma unroll
        for (int off = 1; off < 64; off <<= 1) den += __shfl_xor(den, off, 64);
        float rden = __builtin_amdgcn_rcpf(den);
        int cnt = deg, eix = 0;
        for (; eix + 1 < cnt; eix += 2) {
            int s0 = src_sh[wv][eix], s1 = src_sh[wv][eix + 1];
            float w0 = w_sh[wv][eix], w1 = w_sh[wv][eix + 1];
            uint32 u0 = h2u[(size_t)s0 * 64 + lane];
            uint32 u1 = h2u[(size_t)s1 * 64 + lane];
            acc = w0 * bf2(u0) + acc;
            acc = w1 * bf2(u1) + acc;
        }
        if (eix < cnt) {
            int s0 = src_sh[wv][eix];
            float w0 = w_sh[wv][eix];
            uint32 u0 = h2u[(size_t)s0 * 64 + lane];
            acc = w0 * bf2(u0) + acc;
        }
        acc *= rden;
    } else {
        for (int eix = lane; eix < deg; eix += 64) den += w2[rs + eix];
#pragma unroll
        for (int off = 1; off < 64; off <<= 1) den += __shfl_xor(den, off, 64);
        float rden = __builtin_amdgcn_rcpf(den);
        for (int base = 0; base < deg; base += 64) {
            int cnt = min(deg - base, 64);
            if (lane < cnt) {
                w_sh[wv][lane] = w2[rs + base + lane];
                src_sh[wv][lane] = src_arr[rs + base + lane];
            }
            __builtin_amdgcn_wave_barrier();
            int eix = 0;
            for (; eix + 1 < cnt; eix += 2) {
                int s0 = src_sh[wv][eix], s1 = src_sh[wv][eix + 1];
                float w0 = w_sh[wv][eix], w1 = w_sh[wv][eix + 1];
                uint32 u0 = h2u[(size_t)s0 * 64 + lane];
                uint32 u1 = h2u[(size_t)s1 * 64 + lane];
                acc = w0 * bf2(u0) + acc;
                acc = w1 * bf2(u1) + acc;
            }
            if (eix < cnt) {
                int s0 = src_sh[wv][eix];
                float w0 = w_sh[wv][eix];
                uint32 u0 = h2u[(size_t)s0 * 64 + lane];
                acc = w0 * bf2(u0) + acc;
            }
            __builtin_amdgcn_wave_barrier();
        }
        acc *= rden;
    }
    float2 bv = ((const float2*)b2)[lane];
    float v0 = fmaxf(acc.x + bv.x, 0.f);
    float v1 = fmaxf(acc.y + bv.y, 0.f);
    int g = batch[i];
    atomicMax((int*)&pooled[g * OUT2 + 2 * lane], __float_as_int(v0));
    atomicMax((int*)&pooled[g * OUT2 + 2 * lane + 1], __float_as_int(v1));
}

// ---------------- final FC + relu ----------------
__global__ __launch_bounds__(128) void fc_kernel(const float* __restrict__ pooled,
                                                 const float* __restrict__ fcW,
                                                 const float* __restrict__ fcb,
                                                 float* __restrict__ out) {
    int g = blockIdx.x, tid = threadIdx.x;
    __shared__ float p[128];
    p[tid] = pooled[g * OUT2 + tid];
    __syncthreads();
    float acc = fcb[tid];
    for (int k = 0; k < 128; ++k) acc = fmaf(p[k], fcW[k * OUT2 + tid], acc);
    out[g * OUT2 + tid] = fmaxf(acc, 0.f);
}

extern "C" void kernel_launch(void* const* d_in, const int* in_sizes, int n_in,
                              void* d_out, int out_size, void* d_ws, size_t ws_size,
                              hipStream_t stream) {
    const float* x      = (const float*)d_in[0];
    const int*   ei     = (const int*)d_in[1];
    const int*   batch  = (const int*)d_in[2];
    const float* W1     = (const float*)d_in[4];
    const float* a_src1 = (const float*)d_in[5];
    const float* a_dst1 = (const float*)d_in[6];
    const float* b1     = (const float*)d_in[7];
    const float* W2     = (const float*)d_in[8];
    const float* a_src2 = (const float*)d_in[9];
    const float* a_dst2 = (const float*)d_in[10];
    const float* b2     = (const float*)d_in[11];
    const float* fcW    = (const float*)d_in[12];
    const float* fcb    = (const float*)d_in[13];
    float* out = (float*)d_out;

    size_t off = 0;
    char* base = (char*)d_ws;
    auto alloc = [&](size_t bytes) -> void* {
        void* p = base + off;
        off += (bytes + 255) & ~(size_t)255;
        return p;
    };
    uint32* aggb = (uint32*)alloc((size_t)N_NODES * 390 * 4);   // Agg normalized, bf16 pairs
    u16* out1   = (u16*)alloc((size_t)N_NODES * D1 * 2);
    u16* h2     = (u16*)alloc((size_t)N_NODES * OUT2 * 2);      // also hosts xb early
    u16* xb     = h2;   // xb dead before gemm2 writes h2
    float* asd1 = (float*)alloc((size_t)N_NODES * 20 * 4);
    float* as2  = (float*)alloc((size_t)N_NODES * 4);
    float* ad2  = (float*)alloc((size_t)N_NODES * 4);
    u16* W1X    = (u16*)alloc((size_t)NW1 * 2);
    u16* W2T    = (u16*)alloc((size_t)NW2 * 2);
    u16* VAT    = (u16*)alloc((size_t)32 * F_INN * 2);
    float* w2as = (float*)alloc((size_t)D1 * 4);
    float* w2ad = (float*)alloc((size_t)D1 * 4);
    float* pooled = (float*)alloc((size_t)NGRAPH * OUT2 * 4);
    int* deg     = (int*)alloc((size_t)N_NODES * 4);
    int* row_ptr = (int*)alloc((size_t)(N_NODES + 1) * 4);
    int* cursor  = (int*)alloc((size_t)N_NODES * 4);
    int* src_arr = (int*)alloc((size_t)ETOT * 4);
    int* dst_arr = (int*)alloc((size_t)ETOT * 4);
    uint32* expw5 = (uint32*)alloc((size_t)ETOT * 5 * 4);
    float* w2e   = (float*)alloc((size_t)ETOT * 4);
    int* bsum    = (int*)alloc(196 * 4);
    int* boff    = (int*)alloc(196 * 4);

    hipMemsetAsync(deg, 0, (size_t)N_NODES * 4, stream);
    hipMemsetAsync(pooled, 0, (size_t)NGRAPH * OUT2 * 4, stream);

    prep_kernel<<<2048, 256, 0, stream>>>(x, W1, W2, xb, W1X, W2T);
    prep2_kernel<<<8, 256, 0, stream>>>(W1, a_src1, a_dst1, W2, a_src2, a_dst2,
                                        VAT, w2as, w2ad);
    alphas1x_kernel<<<391, 256, 0, stream>>>(xb, VAT, asd1);
    hist_kernel<<<(ETOT + 255) / 256, 256, 0, stream>>>(ei, deg);
    scan1_kernel<<<196, 256, 0, stream>>>(deg, row_ptr, bsum);
    scan2_kernel<<<1, 256, 0, stream>>>(bsum, boff);
    scan3_kernel<<<196, 256, 0, stream>>>(row_ptr, boff, cursor);
    scatter_kernel<<<(ETOT + 255) / 256, 256, 0, stream>>>(ei, cursor, src_arr, dst_arr);
    expw_kernel<<<(ETOT + 255) / 256, 256, 0, stream>>>(src_arr, dst_arr, asd1, expw5);
    agg1x_kernel<<<N_NODES / 4, 256, 0, stream>>>(row_ptr, src_arr, expw5,
                                                  (const uint32*)xb, aggb);
    gemm1b_kernel<<<(N_NODES + 63) / 64, 256, 0, stream>>>(aggb, (const uint32*)W1X,
                                                           b1, w2as, w2ad,
                                                           out1, as2, ad2);
    gemm2_mfma<<<782, 256, 0, stream>>>(out1, W2T, h2);
    expw2_kernel<<<(ETOT + 255) / 256, 256, 0, stream>>>(src_arr, dst_arr, as2, ad2, w2e);
    agg2_kernel<<<N_NODES / 4, 256, 0, stream>>>(row_ptr, src_arr, w2e,
                                                 (const uint32*)h2, b2, batch, pooled);
    fc_kernel<<<NGRAPH, 128, 0, stream>>>(pooled, fcW, fcb, out);
}

// Round 7
// 589.067 us; speedup vs baseline: 2.0938x; 1.0026x over previous
//
#include <hip/hip_runtime.h>
#include <hip/hip_bf16.h>
#include <stdint.h>

typedef unsigned int uint32;
typedef unsigned short u16;
typedef __attribute__((ext_vector_type(8))) short bf16x8;
typedef __attribute__((ext_vector_type(4))) float f32x4;
typedef __attribute__((ext_vector_type(2))) float f32x2;
typedef uint32 u32x4 __attribute__((ext_vector_type(4)));   // align 16 (LDS)
typedef u32x4 u32x4a __attribute__((aligned(4)));           // 4B-aligned global loads

#define N_NODES 50000
#define N_EDGES 800000
#define ETOT    (N_EDGES + N_NODES)
#define F_INN   78
#define H1      10
#define D1      780
#define OUT2    128
#define NGRAPH  512
#define NEG_SLOPE 0.2f

#define NX  (N_NODES * F_INN)
#define NW1 (D1 * F_INN)
#define NW2 (OUT2 * D1)

__device__ __forceinline__ float lrelu(float v) { return v > 0.f ? v : NEG_SLOPE * v; }
__device__ __forceinline__ u16 f2bfbits(float f) {
    return __bfloat16_as_ushort(__float2bfloat16(f));
}
__device__ __forceinline__ uint32 packbf(float lo, float hi) {
    return (uint32)f2bfbits(lo) | ((uint32)f2bfbits(hi) << 16);
}
__device__ __forceinline__ f32x2 bf2(uint32 u) {
    __hip_bfloat162 b = *reinterpret_cast<__hip_bfloat162*>(&u);
    float2 t = __bfloat1622float2(b);
    return (f32x2){t.x, t.y};
}
__device__ __forceinline__ int esrc(const int* ei, int e) { return e < N_EDGES ? ei[e] : e - N_EDGES; }
__device__ __forceinline__ int edst(const int* ei, int e) { return e < N_EDGES ? ei[N_EDGES + e] : e - N_EDGES; }

// ---------------- prep: x->bf16, W1->W1X bf16 [n][k], W2->W2T bf16 [n][k] ----------------
__global__ __launch_bounds__(256) void prep_kernel(const float* __restrict__ x,
                                                   const float* __restrict__ W1,
                                                   const float* __restrict__ W2,
                                                   u16* __restrict__ xb,
                                                   u16* __restrict__ W1X,
                                                   u16* __restrict__ W2T) {
    const int total = NX + NW1 + NW2;
    for (int id = blockIdx.x * 256 + threadIdx.x; id < total; id += gridDim.x * 256) {
        if (id < NX) {
            xb[id] = f2bfbits(x[id]);
        } else if (id < NX + NW1) {
            int t = id - NX;
            int n = t / F_INN, k = t - n * F_INN;
            W1X[t] = f2bfbits(W1[k * D1 + n]);
        } else {
            int t = id - NX - NW1;
            int n = t / D1, k = t - n * D1;
            W2T[t] = f2bfbits(W2[k * OUT2 + n]);
        }
    }
}

// ---------------- prep2: VAT (32x78 bf16) + w2as/w2ad (780 f32 each) ----------------
__global__ __launch_bounds__(256) void prep2_kernel(const float* __restrict__ W1,
                                                    const float* __restrict__ a_src1,
                                                    const float* __restrict__ a_dst1,
                                                    const float* __restrict__ W2,
                                                    const float* __restrict__ a_src2,
                                                    const float* __restrict__ a_dst2,
                                                    u16* __restrict__ VAT,
                                                    float* __restrict__ w2as,
                                                    float* __restrict__ w2ad) {
    int gid = blockIdx.x * 256 + threadIdx.x;
    int gs = gridDim.x * 256;
    for (int idx = gid; idx < 32 * F_INN; idx += gs) {
        int j = idx / F_INN, k = idx - j * F_INN;
        float s = 0.f;
        if (j < 20) {
            int h = (j < 10) ? j : j - 10;
            const float* vec = ((j < 10) ? a_src1 : a_dst1) + h * F_INN;
            const float* wrow = W1 + k * D1 + h * F_INN;
            for (int f = 0; f < F_INN; ++f) s = fmaf(wrow[f], vec[f], s);
        }
        VAT[j * F_INN + k] = f2bfbits(s);
    }
    for (int c = gid; c < D1; c += gs) {
        const float* r0 = W2 + (size_t)c * OUT2;
        float s = 0.f, d = 0.f;
        for (int j = 0; j < OUT2; ++j) {
            s = fmaf(r0[j], a_src2[j], s);
            d = fmaf(r0[j], a_dst2[j], d);
        }
        w2as[c] = s;
        w2ad[c] = d;
    }
}

// ---------------- alphas1x (MFMA): xb[50000x78] @ VAT^T[78x32] -> asd1[50000x20] ----------------
#define G1S 52
__global__ __launch_bounds__(256) void alphas1x_kernel(const u16* __restrict__ xb,
                                                       const u16* __restrict__ VAT,
                                                       float* __restrict__ asd1) {
    __shared__ uint32 As[128 * G1S];
    __shared__ uint32 Bs[32 * G1S];
    int tid = threadIdx.x;
    int row0 = blockIdx.x * 128;
    const uint32* xbu = (const uint32*)xb;
    const uint32* vau = (const uint32*)VAT;

    for (int idx = tid; idx < 128 * 39; idx += 256) {
        int r = idx / 39, c = idx - r * 39;
        int gr = row0 + r;
        As[r * G1S + c] = (gr < N_NODES) ? xbu[gr * 39 + c] : 0u;
    }
    for (int idx = tid; idx < 128 * 13; idx += 256) {
        int r = idx / 13, c = 39 + (idx - r * 13);
        As[r * G1S + c] = 0u;
    }
    for (int idx = tid; idx < 32 * 39; idx += 256) {
        int n = idx / 39, c = idx - n * 39;
        Bs[n * G1S + c] = vau[n * 39 + c];
    }
    for (int idx = tid; idx < 32 * 13; idx += 256) {
        int n = idx / 13, c = 39 + (idx - n * 13);
        Bs[n * G1S + c] = 0u;
    }
    __syncthreads();

    int lane = tid & 63, wv = tid >> 6;
    int wm = wv >> 1, wn = wv & 1;
    int l15 = lane & 15, quad = lane >> 4;
    const u16* Asu = (const u16*)As;
    const u16* Bsu = (const u16*)Bs;

    f32x4 acc[4];
#pragma unroll
    for (int mi = 0; mi < 4; ++mi) acc[mi] = (f32x4){0.f, 0.f, 0.f, 0.f};

    int abase[4];
#pragma unroll
    for (int mi = 0; mi < 4; ++mi) abase[mi] = (wm * 64 + mi * 16 + l15) * 104 + quad * 8;
    int bbase = (wn * 16 + l15) * 104 + quad * 8;

#pragma unroll
    for (int ks = 0; ks < 96; ks += 32) {
        bf16x8 b = *(const bf16x8*)(Bsu + bbase + ks);
#pragma unroll
        for (int mi = 0; mi < 4; ++mi) {
            bf16x8 a = *(const bf16x8*)(Asu + abase[mi] + ks);
            acc[mi] = __builtin_amdgcn_mfma_f32_16x16x32_bf16(a, b, acc[mi], 0, 0, 0);
        }
    }

    int col = wn * 16 + l15;
#pragma unroll
    for (int mi = 0; mi < 4; ++mi)
#pragma unroll
        for (int reg = 0; reg < 4; ++reg) {
            int row = row0 + wm * 64 + mi * 16 + quad * 4 + reg;
            if (row < N_NODES && col < 20) asd1[(size_t)row * 20 + col] = acc[mi][reg];
        }
}

// ---------------- CSR build ----------------
__global__ void hist_kernel(const int* __restrict__ ei, int* __restrict__ deg) {
    int e = blockIdx.x * 256 + threadIdx.x;
    if (e < ETOT) atomicAdd(&deg[edst(ei, e)], 1);
}

__global__ __launch_bounds__(256) void scan1_kernel(const int* __restrict__ deg,
                                                    int* __restrict__ row_ptr,
                                                    int* __restrict__ bsum) {
    __shared__ int buf[256];
    int tid = threadIdx.x;
    int i = blockIdx.x * 256 + tid;
    int v = (i < N_NODES) ? deg[i] : 0;
    buf[tid] = v;
    __syncthreads();
    for (int off = 1; off < 256; off <<= 1) {
        int t = (tid >= off) ? buf[tid - off] : 0;
        __syncthreads();
        buf[tid] += t;
        __syncthreads();
    }
    if (i < N_NODES) row_ptr[i] = buf[tid] - v;
    if (tid == 255) bsum[blockIdx.x] = buf[255];
}

__global__ __launch_bounds__(256) void scan2_kernel(const int* __restrict__ bsum,
                                                    int* __restrict__ boff) {
    __shared__ int buf[256];
    int tid = threadIdx.x;
    int v = (tid < 196) ? bsum[tid] : 0;
    buf[tid] = v;
    __syncthreads();
    for (int off = 1; off < 256; off <<= 1) {
        int t = (tid >= off) ? buf[tid - off] : 0;
        __syncthreads();
        buf[tid] += t;
        __syncthreads();
    }
    if (tid < 196) boff[tid] = buf[tid] - v;
}

__global__ __launch_bounds__(256) void scan3_kernel(int* __restrict__ row_ptr,
                                                    const int* __restrict__ boff,
                                                    int* __restrict__ cursor) {
    int i = blockIdx.x * 256 + threadIdx.x;
    if (i < N_NODES) {
        int r = row_ptr[i] + boff[blockIdx.x];
        row_ptr[i] = r;
        cursor[i] = r;
    }
    if (i == 0) row_ptr[N_NODES] = ETOT;
}

__global__ void scatter_kernel(const int* __restrict__ ei, int* __restrict__ cursor,
                               int* __restrict__ src_arr, int* __restrict__ dst_arr) {
    int e = blockIdx.x * 256 + threadIdx.x;
    if (e < ETOT) {
        int d = edst(ei, e);
        int pos = atomicAdd(&cursor[d], 1);
        src_arr[pos] = esrc(ei, e);
        dst_arr[pos] = d;
    }
}

// ---------------- edge-parallel exp weights, layer 1: AoS [pos][10 bf16] (5 uints) ----------------
__global__ __launch_bounds__(256) void expw_kernel(const int* __restrict__ src_arr,
                                                   const int* __restrict__ dst_arr,
                                                   const float* __restrict__ asd1,
                                                   uint32* __restrict__ expw5) {
    int p = blockIdx.x * 256 + threadIdx.x;
    if (p >= ETOT) return;
    int s = src_arr[p], d = dst_arr[p];
    const float4* sp = (const float4*)(asd1 + (size_t)s * 20);
    float4 s01 = sp[0], s02 = sp[1];
    float2 s03 = ((const float2*)sp)[4];
    const float* dp = asd1 + (size_t)d * 20 + 10;
    float2 d01 = *(const float2*)dp;
    float4 d02 = *(const float4*)(dp + 2);
    float4 d03 = *(const float4*)(dp + 6);
    float sv[10] = {s01.x, s01.y, s01.z, s01.w, s02.x, s02.y, s02.z, s02.w, s03.x, s03.y};
    float dv[10] = {d01.x, d01.y, d02.x, d02.y, d02.z, d02.w, d03.x, d03.y, d03.z, d03.w};
    uint32 o[5];
#pragma unroll
    for (int k = 0; k < 5; ++k) {
        float w0 = __expf(lrelu(sv[2 * k] + dv[2 * k]));
        float w1 = __expf(lrelu(sv[2 * k + 1] + dv[2 * k + 1]));
        o[k] = packbf(w0, w1);
    }
#pragma unroll
    for (int k = 0; k < 5; ++k) expw5[(size_t)p * 5 + k] = o[k];
}

// ---------------- edge-parallel exp weights, layer 2 ----------------
__global__ __launch_bounds__(256) void expw2_kernel(const int* __restrict__ src_arr,
                                                    const int* __restrict__ dst_arr,
                                                    const float* __restrict__ as2,
                                                    const float* __restrict__ ad2,
                                                    float* __restrict__ w2) {
    int p = blockIdx.x * 256 + threadIdx.x;
    if (p >= ETOT) return;
    w2[p] = __expf(lrelu(as2[src_arr[p]] + ad2[dst_arr[p]]));
}

// ---------------- agg1x: Agg[n,h,f] = (1/den_h) sum_e w_eh * xb[src_e, f], one wave/node ----------------
__global__ __launch_bounds__(256) void agg1x_kernel(const int* __restrict__ row_ptr,
                                                    const int* __restrict__ src_arr,
                                                    const uint32* __restrict__ expw5,
                                                    const uint32* __restrict__ xbu,
                                                    uint32* __restrict__ aggb) {
    __shared__ uint32 rows_sh[4][32 * 40];
    __shared__ float wts_sh[4][32 * 12 + 16];
    int tid = threadIdx.x, lane = tid & 63, wv = tid >> 6;
    int i = blockIdx.x * 4 + wv;
    int rs = row_ptr[i], deg = row_ptr[i + 1] - rs;
    uint32* rows = rows_sh[wv];
    float* wts = wts_sh[wv];
    float* dsh = wts + 32 * 12;

    int hA = (6 * lane) / 39;
    int hB = (6 * lane + 5) / 39;
    int j[6];
    bool sel[6];
#pragma unroll
    for (int q = 0; q < 6; ++q) {
        int u = 6 * lane + q;
        int h = u / 39;
        j[q] = u - 39 * h;
        sel[q] = (h != hA);
    }
    bool tl = lane < 6;
    int jT = 33 + lane;

    f32x2 acc[6];
#pragma unroll
    for (int q = 0; q < 6; ++q) acc[q] = (f32x2){0.f, 0.f};
    f32x2 accT = {0.f, 0.f};
    float den[10];
#pragma unroll
    for (int h = 0; h < 10; ++h) den[h] = 0.f;

    for (int base = 0; base < deg; base += 32) {
        int cnt = min(deg - base, 32);
        int e = lane >> 1, half = lane & 1;
        if (e < cnt) {
            int sn = src_arr[rs + base + e];
            const uint32* rp = xbu + (size_t)sn * 39 + half * 20;
            uint32* lp = rows + e * 40 + half * 20;
            if (half == 0) {
#pragma unroll
                for (int t = 0; t < 5; ++t)
                    *(u32x4*)(lp + 4 * t) = *(const u32x4a*)(rp + 4 * t);
                const uint32* wp = expw5 + (size_t)(rs + base + e) * 5;
#pragma unroll
                for (int k = 0; k < 5; ++k) {
                    f32x2 w2v = bf2(wp[k]);
                    den[2 * k] += w2v.x;
                    den[2 * k + 1] += w2v.y;
                    *(f32x2*)(wts + e * 12 + 2 * k) = w2v;
                }
            } else {
#pragma unroll
                for (int t = 0; t < 4; ++t)
                    *(u32x4*)(lp + 4 * t) = *(const u32x4a*)(rp + 4 * t);
                lp[16] = rp[16];
                lp[17] = rp[17];
                lp[18] = rp[18];
            }
        }
        __builtin_amdgcn_wave_barrier();
        for (int e2 = 0; e2 < cnt; ++e2) {
            const uint32* rb = rows + e2 * 40;
            const float* wb = wts + e2 * 12;
            float wA = wb[hA], wBv = wb[hB];
#pragma unroll
            for (int q = 0; q < 6; ++q) {
                uint32 v = rb[j[q]];
                float w = sel[q] ? wBv : wA;
                acc[q] = w * bf2(v) + acc[q];
            }
            if (tl) {
                uint32 v = rb[jT];
                accT = wb[9] * bf2(v) + accT;
            }
        }
        __builtin_amdgcn_wave_barrier();
    }

#pragma unroll
    for (int off = 1; off < 64; off <<= 1)
#pragma unroll
        for (int h = 0; h < 10; ++h) den[h] += __shfl_xor(den[h], off, 64);
    if (lane < 10) dsh[lane] = den[lane];
    __builtin_amdgcn_wave_barrier();
    float rA = __builtin_amdgcn_rcpf(dsh[hA]);
    float rB = __builtin_amdgcn_rcpf(dsh[hB]);
    float r9 = __builtin_amdgcn_rcpf(dsh[9]);

    uint32* orow = aggb + (size_t)i * 390;
#pragma unroll
    for (int q = 0; q < 6; ++q) {
        f32x2 a = acc[q] * (sel[q] ? rB : rA);
        orow[6 * lane + q] = packbf(a.x, a.y);
    }
    if (tl) {
        f32x2 a = accT * r9;
        orow[384 + lane] = packbf(a.x, a.y);
    }
}

// ---------------- gemm1b v2: grid (10 heads, 391 row-blocks); 128x80x96 tile ----------------
// out1[:, h*78+c] = relu(Agg_h @ W1_h + b1); as2/ad2 via l15-reduce + atomicAdd
__global__ __launch_bounds__(256) void gemm1b_kernel(const uint32* __restrict__ aggb,
                                                     const uint32* __restrict__ w1u,
                                                     const float* __restrict__ b1,
                                                     const float* __restrict__ w2as,
                                                     const float* __restrict__ w2ad,
                                                     u16* __restrict__ out1,
                                                     float* __restrict__ as2,
                                                     float* __restrict__ ad2) {
    __shared__ uint32 As[128 * G1S];
    __shared__ uint32 Bs[80 * G1S];
    int tid = threadIdx.x;
    int h = blockIdx.x;
    int row0 = blockIdx.y * 128;

    for (int idx = tid; idx < 128 * 48; idx += 256) {
        int r = idx / 48, c = idx - r * 48;
        int gr = row0 + r;
        As[r * G1S + c] = (c < 39 && gr < N_NODES) ? aggb[(size_t)gr * 390 + h * 39 + c] : 0u;
    }
    for (int idx = tid; idx < 80 * 48; idx += 256) {
        int n = idx / 48, c = idx - n * 48;
        Bs[n * G1S + c] = (c < 39 && n < 78) ? w1u[(size_t)(h * 78 + n) * 39 + c] : 0u;
    }
    __syncthreads();

    int lane = tid & 63, wv = tid >> 6;
    int l15 = lane & 15, quad = lane >> 4;
    const u16* Asu = (const u16*)As;
    const u16* Bsu = (const u16*)Bs;

    f32x4 acc[2][5];
#pragma unroll
    for (int mi = 0; mi < 2; ++mi)
#pragma unroll
        for (int nj = 0; nj < 5; ++nj) acc[mi][nj] = (f32x4){0.f, 0.f, 0.f, 0.f};

    int abase[2], bbase[5];
#pragma unroll
    for (int mi = 0; mi < 2; ++mi) abase[mi] = (wv * 32 + mi * 16 + l15) * 104 + quad * 8;
#pragma unroll
    for (int nj = 0; nj < 5; ++nj) bbase[nj] = (nj * 16 + l15) * 104 + quad * 8;

#pragma unroll
    for (int ks = 0; ks < 96; ks += 32) {
        bf16x8 a[2], b[5];
#pragma unroll
        for (int mi = 0; mi < 2; ++mi) a[mi] = *(const bf16x8*)(Asu + abase[mi] + ks);
#pragma unroll
        for (int nj = 0; nj < 5; ++nj) b[nj] = *(const bf16x8*)(Bsu + bbase[nj] + ks);
#pragma unroll
        for (int mi = 0; mi < 2; ++mi)
#pragma unroll
            for (int nj = 0; nj < 5; ++nj)
                acc[mi][nj] = __builtin_amdgcn_mfma_f32_16x16x32_bf16(a[mi], b[nj], acc[mi][nj], 0, 0, 0);
    }

    float s2p[2][4] = {}, d2p[2][4] = {};
#pragma unroll
    for (int mi = 0; mi < 2; ++mi) {
        int rowb = row0 + wv * 32 + mi * 16 + quad * 4;
#pragma unroll
        for (int nj = 0; nj < 5; ++nj) {
            int col = nj * 16 + l15;
            if (col < 78) {
                int gc = h * 78 + col;
                float bia = b1[gc], was = w2as[gc], wad = w2ad[gc];
#pragma unroll
                for (int reg = 0; reg < 4; ++reg) {
                    int r = rowb + reg;
                    if (r < N_NODES) {
                        float v = fmaxf(acc[mi][nj][reg] + bia, 0.f);
                        out1[(size_t)r * 780 + gc] = f2bfbits(v);
                        s2p[mi][reg] = fmaf(v, was, s2p[mi][reg]);
                        d2p[mi][reg] = fmaf(v, wad, d2p[mi][reg]);
                    }
                }
            }
        }
    }

#pragma unroll
    for (int off = 1; off < 16; off <<= 1)
#pragma unroll
        for (int mi = 0; mi < 2; ++mi)
#pragma unroll
            for (int reg = 0; reg < 4; ++reg) {
                s2p[mi][reg] += __shfl_xor(s2p[mi][reg], off, 64);
                d2p[mi][reg] += __shfl_xor(d2p[mi][reg], off, 64);
            }
    if (l15 == 0) {
#pragma unroll
        for (int mi = 0; mi < 2; ++mi) {
            int rowb = row0 + wv * 32 + mi * 16 + quad * 4;
#pragma unroll
            for (int reg = 0; reg < 4; ++reg) {
                int r = rowb + reg;
                if (r < N_NODES) {
                    atomicAdd(&as2[r], s2p[mi][reg]);
                    atomicAdd(&ad2[r], d2p[mi][reg]);
                }
            }
        }
    }
}

// ---------------- GEMM2 (MFMA): out1[50000x780] bf16 @ W2[780x128] -> h2 bf16 ----------------
#define G2S 36
__global__ __launch_bounds__(256) void gemm2_mfma(const u16* __restrict__ out1,
                                                  const u16* __restrict__ W2T,
                                                  u16* __restrict__ h2) {
    __shared__ uint32 As[64 * G2S];
    __shared__ uint32 Bs[128 * G2S];
    int tid = threadIdx.x;
    int row0 = blockIdx.x * 64;
    const uint32* o1u = (const uint32*)out1;
    const uint32* w2u = (const uint32*)W2T;

    int lane = tid & 63, wv = tid >> 6;
    int wm = wv >> 1, wn = wv & 1;
    int l15 = lane & 15, quad = lane >> 4;
    const u16* Asu = (const u16*)As;
    const u16* Bsu = (const u16*)Bs;

    f32x4 acc[2][4];
#pragma unroll
    for (int mi = 0; mi < 2; ++mi)
#pragma unroll
        for (int nj = 0; nj < 4; ++nj) acc[mi][nj] = (f32x4){0.f, 0.f, 0.f, 0.f};

    int abase[2], bbase[4];
#pragma unroll
    for (int mi = 0; mi < 2; ++mi) abase[mi] = (wm * 32 + mi * 16 + l15) * 72 + quad * 8;
#pragma unroll
    for (int nj = 0; nj < 4; ++nj) bbase[nj] = (wn * 64 + nj * 16 + l15) * 72 + quad * 8;

    for (int s = 0; s < 13; ++s) {
        int k0h = s * 32;
        for (int idx = tid; idx < 64 * 32; idx += 256) {
            int r = idx >> 5, c = idx & 31;
            int gr = row0 + r;
            As[r * G2S + c] = (gr < N_NODES && (k0h + c) < 390) ? o1u[(size_t)gr * 390 + k0h + c] : 0u;
        }
        for (int idx = tid; idx < 128 * 32; idx += 256) {
            int n = idx >> 5, c = idx & 31;
            Bs[n * G2S + c] = ((k0h + c) < 390) ? w2u[(size_t)n * 390 + k0h + c] : 0u;
        }
        __syncthreads();
#pragma unroll
        for (int ks = 0; ks < 64; ks += 32) {
            bf16x8 a[2], b[4];
#pragma unroll
            for (int mi = 0; mi < 2; ++mi) a[mi] = *(const bf16x8*)(Asu + abase[mi] + ks);
#pragma unroll
            for (int nj = 0; nj < 4; ++nj) b[nj] = *(const bf16x8*)(Bsu + bbase[nj] + ks);
#pragma unroll
            for (int mi = 0; mi < 2; ++mi)
#pragma unroll
                for (int nj = 0; nj < 4; ++nj)
                    acc[mi][nj] = __builtin_amdgcn_mfma_f32_16x16x32_bf16(a[mi], b[nj], acc[mi][nj], 0, 0, 0);
        }
        __syncthreads();
    }

#pragma unroll
    for (int mi = 0; mi < 2; ++mi)
#pragma unroll
        for (int nj = 0; nj < 4; ++nj)
#pragma unroll
            for (int reg = 0; reg < 4; ++reg) {
                int row = row0 + wm * 32 + mi * 16 + quad * 4 + reg;
                int col = wn * 64 + nj * 16 + l15;
                if (row < N_NODES)
                    h2[(size_t)row * OUT2 + col] = f2bfbits(acc[mi][nj][reg]);
            }
}

// ---------------- layer-2 aggregation + pool: one wave per node ----------------
__global__ __launch_bounds__(256) void agg2_kernel(const int* __restrict__ row_ptr,
                                                   const int* __restrict__ src_arr,
                                                   const float* __restrict__ w2,
                                                   const uint32* __restrict__ h2u,
                                                   const float* __restrict__ b2,
                                                   const int* __restrict__ batch,
                                                   float* __restrict__ pooled) {
    __shared__ float w_sh[4][64];
    __shared__ int src_sh[4][64];
    int tid = threadIdx.x, lane = tid & 63, wv = tid >> 6;
    int i = blockIdx.x * 4 + wv;
    int rs = row_ptr[i], deg = row_ptr[i + 1] - rs;

    f32x2 acc = {0.f, 0.f};
    float den = 0.f;
    if (deg <= 64) {
        if (lane < deg) {
            float w = w2[rs + lane];
            den = w;
            w_sh[wv][lane] = w;
            src_sh[wv][lane] = src_arr[rs + lane];
        }
        __builtin_amdgcn_wave_barrier();
#pragma unroll
        for (int off = 1; off < 64; off <<= 1) den += __shfl_xor(den, off, 64);
        float rden = __builtin_amdgcn_rcpf(den);
        int cnt = deg, eix = 0;
        for (; eix + 1 < cnt; eix += 2) {
            int s0 = src_sh[wv][eix], s1 = src_sh[wv][eix + 1];
            float w0 = w_sh[wv][eix], w1 = w_sh[wv][eix + 1];
            uint32 u0 = h2u[(size_t)s0 * 64 + lane];
            uint32 u1 = h2u[(size_t)s1 * 64 + lane];
            acc = w0 * bf2(u0) + acc;
            acc = w1 * bf2(u1) + acc;
        }
        if (eix < cnt) {
            int s0 = src_sh[wv][eix];
            float w0 = w_sh[wv][eix];
            uint32 u0 = h2u[(size_t)s0 * 64 + lane];
            acc = w0 * bf2(u0) + acc;
        }
        acc *= rden;
    } else {
        for (int eix = lane; eix < deg; eix += 64) den += w2[rs + eix];
#pragma unroll
        for (int off = 1; off < 64; off <<= 1) den += __shfl_xor(den, off, 64);
        float rden = __builtin_amdgcn_rcpf(den);
        for (int base = 0; base < deg; base += 64) {
            int cnt = min(deg - base, 64);
            if (lane < cnt) {
                w_sh[wv][lane] = w2[rs + base + lane];
                src_sh[wv][lane] = src_arr[rs + base + lane];
            }
            __builtin_amdgcn_wave_barrier();
            int eix = 0;
            for (; eix + 1 < cnt; eix += 2) {
                int s0 = src_sh[wv][eix], s1 = src_sh[wv][eix + 1];
                float w0 = w_sh[wv][eix], w1 = w_sh[wv][eix + 1];
                uint32 u0 = h2u[(size_t)s0 * 64 + lane];
                uint32 u1 = h2u[(size_t)s1 * 64 + lane];
                acc = w0 * bf2(u0) + acc;
                acc = w1 * bf2(u1) + acc;
            }
            if (eix < cnt) {
                int s0 = src_sh[wv][eix];
                float w0 = w_sh[wv][eix];
                uint32 u0 = h2u[(size_t)s0 * 64 + lane];
                acc = w0 * bf2(u0) + acc;
            }
            __builtin_amdgcn_wave_barrier();
        }
        acc *= rden;
    }
    float2 bv = ((const float2*)b2)[lane];
    float v0 = fmaxf(acc.x + bv.x, 0.f);
    float v1 = fmaxf(acc.y + bv.y, 0.f);
    int g = batch[i];
    atomicMax((int*)&pooled[g * OUT2 + 2 * lane], __float_as_int(v0));
    atomicMax((int*)&pooled[g * OUT2 + 2 * lane + 1], __float_as_int(v1));
}

// ---------------- final FC + relu ----------------
__global__ __launch_bounds__(128) void fc_kernel(const float* __restrict__ pooled,
                                                 const float* __restrict__ fcW,
                                                 const float* __restrict__ fcb,
                                                 float* __restrict__ out) {
    int g = blockIdx.x, tid = threadIdx.x;
    __shared__ float p[128];
    p[tid] = pooled[g * OUT2 + tid];
    __syncthreads();
    float acc = fcb[tid];
    for (int k = 0; k < 128; ++k) acc = fmaf(p[k], fcW[k * OUT2 + tid], acc);
    out[g * OUT2 + tid] = fmaxf(acc, 0.f);
}

extern "C" void kernel_launch(void* const* d_in, const int* in_sizes, int n_in,
                              void* d_out, int out_size, void* d_ws, size_t ws_size,
                              hipStream_t stream) {
    const float* x      = (const float*)d_in[0];
    const int*   ei     = (const int*)d_in[1];
    const int*   batch  = (const int*)d_in[2];
    const float* W1     = (const float*)d_in[4];
    const float* a_src1 = (const float*)d_in[5];
    const float* a_dst1 = (const float*)d_in[6];
    const float* b1     = (const float*)d_in[7];
    const float* W2     = (const float*)d_in[8];
    const float* a_src2 = (const float*)d_in[9];
    const float* a_dst2 = (const float*)d_in[10];
    const float* b2     = (const float*)d_in[11];
    const float* fcW    = (const float*)d_in[12];
    const float* fcb    = (const float*)d_in[13];
    float* out = (float*)d_out;

    size_t off = 0;
    char* base = (char*)d_ws;
    auto alloc = [&](size_t bytes) -> void* {
        void* p = base + off;
        off += (bytes + 255) & ~(size_t)255;
        return p;
    };
    uint32* aggb = (uint32*)alloc((size_t)N_NODES * 390 * 4);
    u16* out1   = (u16*)alloc((size_t)N_NODES * D1 * 2);
    u16* h2     = (u16*)alloc((size_t)N_NODES * OUT2 * 2);      // also hosts xb early
    u16* xb     = h2;   // xb dead before gemm2 writes h2
    float* asd1 = (float*)alloc((size_t)N_NODES * 20 * 4);
    float* as2  = (float*)alloc((size_t)N_NODES * 4);
    float* ad2  = (float*)alloc((size_t)N_NODES * 4);
    u16* W1X    = (u16*)alloc((size_t)NW1 * 2);
    u16* W2T    = (u16*)alloc((size_t)NW2 * 2);
    u16* VAT    = (u16*)alloc((size_t)32 * F_INN * 2);
    float* w2as = (float*)alloc((size_t)D1 * 4);
    float* w2ad = (float*)alloc((size_t)D1 * 4);
    float* pooled = (float*)alloc((size_t)NGRAPH * OUT2 * 4);
    int* deg     = (int*)alloc((size_t)N_NODES * 4);
    int* row_ptr = (int*)alloc((size_t)(N_NODES + 1) * 4);
    int* cursor  = (int*)alloc((size_t)N_NODES * 4);
    int* src_arr = (int*)alloc((size_t)ETOT * 4);
    int* dst_arr = (int*)alloc((size_t)ETOT * 4);
    uint32* expw5 = (uint32*)alloc((size_t)ETOT * 5 * 4);
    float* w2e   = (float*)alloc((size_t)ETOT * 4);
    int* bsum    = (int*)alloc(196 * 4);
    int* boff    = (int*)alloc(196 * 4);

    hipMemsetAsync(deg, 0, (size_t)N_NODES * 4, stream);
    hipMemsetAsync(pooled, 0, (size_t)NGRAPH * OUT2 * 4, stream);
    hipMemsetAsync(as2, 0, (size_t)N_NODES * 4, stream);
    hipMemsetAsync(ad2, 0, (size_t)N_NODES * 4, stream);

    prep_kernel<<<2048, 256, 0, stream>>>(x, W1, W2, xb, W1X, W2T);
    prep2_kernel<<<8, 256, 0, stream>>>(W1, a_src1, a_dst1, W2, a_src2, a_dst2,
                                        VAT, w2as, w2ad);
    alphas1x_kernel<<<391, 256, 0, stream>>>(xb, VAT, asd1);
    hist_kernel<<<(ETOT + 255) / 256, 256, 0, stream>>>(ei, deg);
    scan1_kernel<<<196, 256, 0, stream>>>(deg, row_ptr, bsum);
    scan2_kernel<<<1, 256, 0, stream>>>(bsum, boff);
    scan3_kernel<<<196, 256, 0, stream>>>(row_ptr, boff, cursor);
    scatter_kernel<<<(ETOT + 255) / 256, 256, 0, stream>>>(ei, cursor, src_arr, dst_arr);
    expw_kernel<<<(ETOT + 255) / 256, 256, 0, stream>>>(src_arr, dst_arr, asd1, expw5);
    agg1x_kernel<<<N_NODES / 4, 256, 0, stream>>>(row_ptr, src_arr, expw5,
                                                  (const uint32*)xb, aggb);
    gemm1b_kernel<<<dim3(10, 391), 256, 0, stream>>>(aggb, (const uint32*)W1X,
                                                     b1, w2as, w2ad,
                                                     out1, as2, ad2);
    gemm2_mfma<<<782, 256, 0, stream>>>(out1, W2T, h2);
    expw2_kernel<<<(ETOT + 255) / 256, 256, 0, stream>>>(src_arr, dst_arr, as2, ad2, w2e);
    agg2_kernel<<<N_NODES / 4, 256, 0, stream>>>(row_ptr, src_arr, w2e,
                                                 (const uint32*)h2, b2, batch, pooled);
    fc_kernel<<<NGRAPH, 128, 0, stream>>>(pooled, fcW, fcb, out);
}